// Round 5
// baseline (359.445 us; speedup 1.0000x reference)
//
#include <hip/hip_runtime.h>
#include <math.h>

#define N_NODES 50000
#define N_EDGES 800000
#define D_INPUT 256
#define HDIM 128
#define A_DIM 32
#define NEG_SLOPE 0.2f
#define BN_EPS 1e-5f
#define CAP 64        // max degree capacity; Poisson(16): P(deg>=64) ~ 1e-21
#define NB 391        // dst bins of 128 nodes (391*128 = 50048 >= 50000)
#define BIN_SHIFT 7
#define BCAP 384      // per (xcd,bin) segment capacity; lambda=256, +8 sigma
#define NXCD 8

typedef short short8 __attribute__((ext_vector_type(8)));
typedef unsigned short ushort8v __attribute__((ext_vector_type(8)));
typedef unsigned short ushort4v __attribute__((ext_vector_type(4)));
typedef float float4v __attribute__((ext_vector_type(4)));

__device__ __forceinline__ unsigned short f2bf(float f) {
  unsigned u = __float_as_uint(f);
  u += 0x7FFFu + ((u >> 16) & 1u);
  return (unsigned short)(u >> 16);
}
__device__ __forceinline__ float bf2f(unsigned short b) {
  return __uint_as_float(((unsigned)b) << 16);
}

__device__ __forceinline__ float waveReduceMax(float v) {
#pragma unroll
  for (int o = 32; o >= 1; o >>= 1) v = fmaxf(v, __shfl_xor(v, o, 64));
  return v;
}
__device__ __forceinline__ float waveReduceSum(float v) {
#pragma unroll
  for (int o = 32; o >= 1; o >>= 1) v += __shfl_xor(v, o, 64);
  return v;
}

// ---------------- prep: W -> Wt (bf16, transposed [n][k]) -------------------
__global__ __launch_bounds__(256) void k_prep(
    const float* __restrict__ W, const float* __restrict__ W1,
    const float* __restrict__ W2, unsigned short* __restrict__ Wt0,
    unsigned short* __restrict__ Wt1, unsigned short* __restrict__ Wt2)
{
  int i = blockIdx.x * 256 + threadIdx.x;
  if (i < HDIM * D_INPUT) {                 // Wt0[n][k], 128 x 256
    int n = i >> 8, k = i & 255;
    Wt0[i] = f2bf(W[(size_t)k * HDIM + n]);
  }
  if (i < HDIM * HDIM) {                    // Wt1/Wt2[n][k], 128 x 128
    int n = i >> 7, k = i & 127;
    Wt1[i] = f2bf(W1[(size_t)k * HDIM + n]);
    Wt2[i] = f2bf(W2[(size_t)k * HDIM + n]);
  }
}

// ---------------- K1: h(bf16) = x @ W, plus esrc/edst (MFMA) ----------------
__global__ __launch_bounds__(256) void k_gemm_xw_mfma(
    const float* __restrict__ x, const unsigned short* __restrict__ Wt0,
    const float* __restrict__ a_src, const float* __restrict__ a_dst,
    unsigned short* __restrict__ hbf, float* __restrict__ esrc, float* __restrict__ edst)
{
  __shared__ short As[64][72];   // [m][k] bf16
  __shared__ short Bs[128][72];  // [n][k] bf16
  __shared__ float esred[64][2], edred[64][2];

  const int t = threadIdx.x;
  const int lane = t & 63;
  const int wv = t >> 6;
  const int rh = wv >> 1;
  const int ch = wv & 1;
  const int quad = (lane >> 4) & 3;
  const int l15 = lane & 15;
  const int row0 = blockIdx.x * 64;

  float4v acc[2][4];
#pragma unroll
  for (int i = 0; i < 2; ++i)
#pragma unroll
    for (int j = 0; j < 4; ++j) acc[i][j] = (float4v){0.f, 0.f, 0.f, 0.f};

  for (int ks = 0; ks < D_INPUT / 64; ++ks) {
    const int kk0 = ks * 64;
#pragma unroll
    for (int it = 0; it < 4; ++it) {
      int idx = it * 256 + t;
      int r = idx >> 4, c4 = idx & 15;
      int rr = row0 + r; if (rr >= N_NODES) rr = N_NODES - 1;
      float4 v = *(const float4*)(x + (size_t)rr * D_INPUT + kk0 + c4 * 4);
      ushort4v b; b.x = f2bf(v.x); b.y = f2bf(v.y); b.z = f2bf(v.z); b.w = f2bf(v.w);
      *(ushort4v*)(&As[r][c4 * 4]) = b;
    }
#pragma unroll
    for (int it = 0; it < 4; ++it) {
      int idx = it * 256 + t;
      int n = idx >> 3, c8 = idx & 7;
      *(ushort8v*)(&Bs[n][c8 * 8]) = *(const ushort8v*)(Wt0 + (size_t)n * D_INPUT + kk0 + c8 * 8);
    }
    __syncthreads();
#pragma unroll
    for (int kc = 0; kc < 2; ++kc) {
      short8 af[2], bfr[4];
#pragma unroll
      for (int rt = 0; rt < 2; ++rt)
        af[rt] = *(const short8*)(&As[rh * 32 + rt * 16 + l15][kc * 32 + quad * 8]);
#pragma unroll
      for (int nt = 0; nt < 4; ++nt)
        bfr[nt] = *(const short8*)(&Bs[ch * 64 + nt * 16 + l15][kc * 32 + quad * 8]);
#pragma unroll
      for (int rt = 0; rt < 2; ++rt)
#pragma unroll
        for (int nt = 0; nt < 4; ++nt)
          acc[rt][nt] = __builtin_amdgcn_mfma_f32_16x16x32_bf16(af[rt], bfr[nt], acc[rt][nt], 0, 0, 0);
    }
    __syncthreads();
  }

  float asv[4], adv[4];
#pragma unroll
  for (int nt = 0; nt < 4; ++nt) {
    int col = ch * 64 + nt * 16 + l15;
    asv[nt] = a_src[col]; adv[nt] = a_dst[col];
  }
#pragma unroll
  for (int rt = 0; rt < 2; ++rt) {
#pragma unroll
    for (int reg = 0; reg < 4; ++reg) {
      int rloc = rh * 32 + rt * 16 + quad * 4 + reg;
      int row = row0 + rloc;
      bool valid = (row < N_NODES);
      float ps = 0.f, pd = 0.f;
#pragma unroll
      for (int nt = 0; nt < 4; ++nt) {
        float v = acc[rt][nt][reg];
        ps += v * asv[nt]; pd += v * adv[nt];
        if (valid) hbf[(size_t)row * HDIM + ch * 64 + nt * 16 + l15] = f2bf(v);
      }
#pragma unroll
      for (int o = 8; o >= 1; o >>= 1) {
        ps += __shfl_xor(ps, o, 64);
        pd += __shfl_xor(pd, o, 64);
      }
      if (l15 == 0) { esred[rloc][ch] = ps; edred[rloc][ch] = pd; }
    }
  }
  __syncthreads();
  if (t < 64) {
    int row = row0 + t;
    if (row < N_NODES) {
      esrc[row] = esred[t][0] + esred[t][1];
      edst[row] = edred[t][0] + edred[t][1];
    }
  }
}

// ---------------- phase 1: bin edges, XCD-affine segments -------------------
// payload 4B: src (16b) | d&127 (7b). xcd = blockIdx&7 is a locality
// heuristic only (round-robin dispatch); correctness independent of mapping.
__global__ __launch_bounds__(256) void k_bin(
    const int* __restrict__ srcI, const int* __restrict__ dstI,
    int* __restrict__ bcur, int* __restrict__ bbuf)
{
  int e = blockIdx.x * 256 + threadIdx.x;
  int xcd = blockIdx.x & (NXCD - 1);
  if (e < N_EDGES) {
    int s = srcI[e], d = dstI[e];
    int c = xcd * NB + (d >> BIN_SHIFT);
    int r = atomicAdd(&bcur[c], 1);
    if (r < BCAP) bbuf[(size_t)c * BCAP + r] = s | ((d & 127) << 16);
  }
}

// ---------------- phase 2: per-bin rank assignment + bucket store -----------
// one block per bin (128 dsts); LDS cursors; writes stay in a 64 KB window
__global__ __launch_bounds__(256) void k_scatter2(
    const int* __restrict__ bcur, const int* __restrict__ bbuf,
    const float* __restrict__ esrc, const float* __restrict__ edst,
    int* __restrict__ deg, int2* __restrict__ sedge)
{
  __shared__ int lcur[128];
  __shared__ float ledst[128];
  const int bin = blockIdx.x;
  const int t = threadIdx.x;
  const int d0 = bin << BIN_SHIFT;
  if (t < 128) {
    lcur[t] = 0;
    int d = d0 + t;
    ledst[t] = (d < N_NODES) ? edst[d] : 0.f;
  }
  __syncthreads();
#pragma unroll
  for (int x = 0; x < NXCD; ++x) {
    const int c = x * NB + bin;
    const int cnt = min(bcur[c], BCAP);
    const int* seg = bbuf + (size_t)c * BCAP;
    for (int i = t; i < cnt; i += 256) {
      int v = seg[i];
      int s = v & 0xFFFF;
      int dl = (v >> 16) & 127;
      float ev = esrc[s] + ledst[dl];
      ev = (ev > 0.f) ? ev : NEG_SLOPE * ev;
      int r = atomicAdd(&lcur[dl], 1);
      if (r < CAP) {
        int2 e2; e2.x = s; e2.y = __float_as_int(ev);
        sedge[(size_t)(d0 + dl) * CAP + r] = e2;
      }
    }
  }
  __syncthreads();
  if (t < 128) {
    int d = d0 + t;
    if (d < N_NODES) deg[d] = min(lcur[t], CAP);
  }
}

// ---------------- per-dst softmax + aggregation: 1 wave per node ------------
__global__ __launch_bounds__(256) void k_agg(
    const int* __restrict__ degA, const int2* __restrict__ sedge,
    const unsigned short* __restrict__ hbf,
    const float* __restrict__ b_gat, unsigned short* __restrict__ h0)
{
  const int t = threadIdx.x;
  const int lane = t & 63;
  const int node = blockIdx.x * 4 + (t >> 6);
  const int deg = degA[node];

  int2 ev; ev.x = 0; ev.y = 0;
  float val = -INFINITY;
  if (lane < deg) {
    ev = sedge[(size_t)node * CAP + lane];
    val = __int_as_float(ev.y);
  }
  const float m = waveReduceMax(val);
  const float ex = (lane < deg) ? __expf(val - m) : 0.f;
  const float s = waveReduceSum(ex);
  const float al = ex * (1.0f / fmaxf(s, 1e-16f));
  const int sr = ev.x;

  float ax = 0.f, ay = 0.f;
  int j = 0;
  for (; j + 4 <= deg; j += 4) {
    float a0 = __shfl(al, j, 64),   a1 = __shfl(al, j+1, 64);
    float a2 = __shfl(al, j+2, 64), a3 = __shfl(al, j+3, 64);
    int s0 = __shfl(sr, j, 64),   s1 = __shfl(sr, j+1, 64);
    int s2 = __shfl(sr, j+2, 64), s3 = __shfl(sr, j+3, 64);
    unsigned v0 = *(const unsigned*)(hbf + (size_t)s0 * HDIM + lane * 2);
    unsigned v1 = *(const unsigned*)(hbf + (size_t)s1 * HDIM + lane * 2);
    unsigned v2 = *(const unsigned*)(hbf + (size_t)s2 * HDIM + lane * 2);
    unsigned v3 = *(const unsigned*)(hbf + (size_t)s3 * HDIM + lane * 2);
    ax += a0 * bf2f((unsigned short)(v0 & 0xFFFFu))
        + a1 * bf2f((unsigned short)(v1 & 0xFFFFu))
        + a2 * bf2f((unsigned short)(v2 & 0xFFFFu))
        + a3 * bf2f((unsigned short)(v3 & 0xFFFFu));
    ay += a0 * bf2f((unsigned short)(v0 >> 16))
        + a1 * bf2f((unsigned short)(v1 >> 16))
        + a2 * bf2f((unsigned short)(v2 >> 16))
        + a3 * bf2f((unsigned short)(v3 >> 16));
  }
  for (; j < deg; ++j) {
    float a = __shfl(al, j, 64);
    int sj = __shfl(sr, j, 64);
    unsigned v = *(const unsigned*)(hbf + (size_t)sj * HDIM + lane * 2);
    ax += a * bf2f((unsigned short)(v & 0xFFFFu));
    ay += a * bf2f((unsigned short)(v >> 16));
  }
  float vx = fmaxf(ax + b_gat[lane * 2], 0.f);
  float vy = fmaxf(ay + b_gat[lane * 2 + 1], 0.f);
  *(unsigned*)(h0 + (size_t)node * HDIM + lane * 2) =
      (unsigned)f2bf(vx) | ((unsigned)f2bf(vy) << 16);
}

// ---------------- BN column stats (bf16 input) ------------------------------
__global__ __launch_bounds__(256) void k_bnstats(
    const unsigned short* __restrict__ src, float* __restrict__ gsum, float* __restrict__ gsq)
{
  __shared__ float ls[256], lq[256];
  const int t = threadIdx.x;
  const int c = t & 127, r2 = t >> 7;
  const int row0 = blockIdx.x * 128;
  float s = 0.f, q = 0.f;
  for (int i = 0; i < 64; ++i) {
    int row = row0 + i * 2 + r2;
    if (row < N_NODES) {
      float v = bf2f(src[(size_t)row * HDIM + c]);
      s += v; q += v * v;
    }
  }
  ls[t] = s; lq[t] = q; __syncthreads();
  if (t < 128) {
    atomicAdd(&gsum[t], ls[t] + ls[t + 128]);
    atomicAdd(&gsq[t],  lq[t] + lq[t + 128]);
  }
}

// ---------------- FC (MFMA) with inline BN-param computation ----------------
__global__ __launch_bounds__(256) void k_fc_mfma(
    const unsigned short* __restrict__ in,
    const float* __restrict__ gsumIn, const float* __restrict__ gsqIn,
    const float* __restrict__ gamma, const float* __restrict__ beta,
    const unsigned short* __restrict__ Wt,
    const float* __restrict__ bias, unsigned short* __restrict__ outp,
    float* __restrict__ gsum, float* __restrict__ gsq, int hasBN, int doStats)
{
  __shared__ short As[64][72];
  __shared__ short Bs[128][72];
  __shared__ float statS[128][2], statQ[128][2];
  __shared__ float sc[HDIM], shf[HDIM];

  const int t = threadIdx.x;
  const int lane = t & 63;
  const int wv = t >> 6;
  const int rh = wv >> 1;
  const int ch = wv & 1;
  const int quad = (lane >> 4) & 3;
  const int l15 = lane & 15;
  const int row0 = blockIdx.x * 64;

  if (hasBN && t < HDIM) {
    float mean = gsumIn[t] / (float)N_NODES;
    float var = gsqIn[t] / (float)N_NODES - mean * mean;
    float s = gamma[t] * rsqrtf(var + BN_EPS);
    sc[t] = s; shf[t] = beta[t] - mean * s;
  }
  if (hasBN) __syncthreads();

  float4v acc[2][4];
#pragma unroll
  for (int i = 0; i < 2; ++i)
#pragma unroll
    for (int j = 0; j < 4; ++j) acc[i][j] = (float4v){0.f, 0.f, 0.f, 0.f};

  for (int ks = 0; ks < HDIM / 64; ++ks) {
    const int kk0 = ks * 64;
#pragma unroll
    for (int it = 0; it < 2; ++it) {
      int idx = it * 256 + t;
      int r = idx >> 3, c8 = idx & 7;
      int rr = row0 + r; if (rr >= N_NODES) rr = N_NODES - 1;
      ushort8v v = *(const ushort8v*)(in + (size_t)rr * HDIM + kk0 + c8 * 8);
      if (hasBN) {
#pragma unroll
        for (int j = 0; j < 8; ++j) {
          int k = kk0 + c8 * 8 + j;
          v[j] = f2bf(bf2f(v[j]) * sc[k] + shf[k]);
        }
      }
      *(ushort8v*)(&As[r][c8 * 8]) = v;
    }
#pragma unroll
    for (int it = 0; it < 4; ++it) {
      int idx = it * 256 + t;
      int n = idx >> 3, c8 = idx & 7;
      *(ushort8v*)(&Bs[n][c8 * 8]) = *(const ushort8v*)(Wt + (size_t)n * HDIM + kk0 + c8 * 8);
    }
    __syncthreads();
#pragma unroll
    for (int kc = 0; kc < 2; ++kc) {
      short8 af[2], bfr[4];
#pragma unroll
      for (int rt = 0; rt < 2; ++rt)
        af[rt] = *(const short8*)(&As[rh * 32 + rt * 16 + l15][kc * 32 + quad * 8]);
#pragma unroll
      for (int nt = 0; nt < 4; ++nt)
        bfr[nt] = *(const short8*)(&Bs[ch * 64 + nt * 16 + l15][kc * 32 + quad * 8]);
#pragma unroll
      for (int rt = 0; rt < 2; ++rt)
#pragma unroll
        for (int nt = 0; nt < 4; ++nt)
          acc[rt][nt] = __builtin_amdgcn_mfma_f32_16x16x32_bf16(af[rt], bfr[nt], acc[rt][nt], 0, 0, 0);
    }
    __syncthreads();
  }

  float bv[4];
#pragma unroll
  for (int nt = 0; nt < 4; ++nt) bv[nt] = bias[ch * 64 + nt * 16 + l15];

  float pS[4] = {0.f, 0.f, 0.f, 0.f}, pQ[4] = {0.f, 0.f, 0.f, 0.f};
#pragma unroll
  for (int rt = 0; rt < 2; ++rt) {
#pragma unroll
    for (int reg = 0; reg < 4; ++reg) {
      int row = row0 + rh * 32 + rt * 16 + quad * 4 + reg;
      bool valid = (row < N_NODES);
#pragma unroll
      for (int nt = 0; nt < 4; ++nt) {
        float o = fmaxf(acc[rt][nt][reg] + bv[nt], 0.f);
        if (valid) {
          outp[(size_t)row * HDIM + ch * 64 + nt * 16 + l15] = f2bf(o);
          pS[nt] += o; pQ[nt] += o * o;
        }
      }
    }
  }
  if (doStats) {
#pragma unroll
    for (int nt = 0; nt < 4; ++nt) {
      float s = pS[nt], q = pQ[nt];
      s += __shfl_xor(s, 16, 64); s += __shfl_xor(s, 32, 64);
      q += __shfl_xor(q, 16, 64); q += __shfl_xor(q, 32, 64);
      if (lane < 16) {
        statS[ch * 64 + nt * 16 + lane][rh] = s;
        statQ[ch * 64 + nt * 16 + lane][rh] = q;
      }
    }
    __syncthreads();
    if (t < 128) {
      atomicAdd(&gsum[t], statS[t][0] + statS[t][1]);
      atomicAdd(&gsq[t],  statQ[t][0] + statQ[t][1]);
    }
  }
}

// ---------------- fc3 + row softmax (inline BN params) ----------------------
__global__ __launch_bounds__(256) void k_fc3(
    const unsigned short* __restrict__ h2,
    const float* __restrict__ gsumIn, const float* __restrict__ gsqIn,
    const float* __restrict__ gamma, const float* __restrict__ beta,
    const float* __restrict__ W3, const float* __restrict__ b3,
    float* __restrict__ out)
{
  __shared__ float w3s[HDIM * A_DIM];
  __shared__ float s2[HDIM], sh2[HDIM];
  const int t = threadIdx.x;
  for (int l = t; l < HDIM * A_DIM; l += 256) w3s[l] = W3[l];
  if (t < HDIM) {
    float mean = gsumIn[t] / (float)N_NODES;
    float var = gsqIn[t] / (float)N_NODES - mean * mean;
    float s = gamma[t] * rsqrtf(var + BN_EPS);
    s2[t] = s; sh2[t] = beta[t] - mean * s;
  }
  __syncthreads();

  const int j = t & 31;
  const int rloc = t >> 5;
  const int row = blockIdx.x * 8 + rloc;
  if (row >= N_NODES) return;

  float dotv = 0.f;
  const unsigned short* hrow = h2 + (size_t)row * HDIM;
#pragma unroll 4
  for (int k = 0; k < HDIM; ++k) {
    float hv = bf2f(hrow[k]) * s2[k] + sh2[k];
    dotv += hv * w3s[k * A_DIM + j];
  }
  float logit = dotv + b3[j];
  float mx = logit;
#pragma unroll
  for (int o = 16; o >= 1; o >>= 1) mx = fmaxf(mx, __shfl_xor(mx, o, 32));
  float ex = __expf(logit - mx);
  float sm = ex;
#pragma unroll
  for (int o = 16; o >= 1; o >>= 1) sm += __shfl_xor(sm, o, 32);
  out[(size_t)row * A_DIM + j] = ex / sm;
}

// ---------------------------------------------------------------------------
extern "C" void kernel_launch(void* const* d_in, const int* in_sizes, int n_in,
                              void* d_out, int out_size, void* d_ws, size_t ws_size,
                              hipStream_t stream) {
  const float* x     = (const float*)d_in[0];
  const int*   ei    = (const int*)d_in[1];
  const float* W     = (const float*)d_in[2];
  const float* a_src = (const float*)d_in[3];
  const float* a_dst = (const float*)d_in[4];
  const float* b_gat = (const float*)d_in[5];
  const float* g0    = (const float*)d_in[6];
  const float* beta0 = (const float*)d_in[7];
  const float* W1    = (const float*)d_in[8];
  const float* b1    = (const float*)d_in[9];
  const float* W2    = (const float*)d_in[10];
  const float* b2    = (const float*)d_in[11];
  const float* g2    = (const float*)d_in[12];
  const float* beta2 = (const float*)d_in[13];
  const float* W3    = (const float*)d_in[14];
  const float* b3    = (const float*)d_in[15];
  float* out = (float*)d_out;
  const int* srcI = ei;
  const int* dstI = ei + N_EDGES;

  char* p = (char*)d_ws;
  auto alloc = [&](size_t bytes) -> char* {
    char* q = p; p += (bytes + 255) & ~(size_t)255; return q;
  };
  unsigned short* h   = (unsigned short*)alloc(sizeof(short) * (size_t)N_NODES * HDIM);
  unsigned short* h0  = (unsigned short*)alloc(sizeof(short) * (size_t)N_NODES * HDIM);
  unsigned short* h2  = (unsigned short*)alloc(sizeof(short) * (size_t)N_NODES * HDIM);
  unsigned short* h1  = h;  // reuse
  unsigned short* Wt0 = (unsigned short*)alloc(sizeof(short) * HDIM * D_INPUT);
  unsigned short* Wt1 = (unsigned short*)alloc(sizeof(short) * HDIM * HDIM);
  unsigned short* Wt2 = (unsigned short*)alloc(sizeof(short) * HDIM * HDIM);
  int2*  sedge  = (int2*)alloc(sizeof(int2) * (size_t)N_NODES * CAP);
  int*   bbuf   = (int*)alloc(sizeof(int) * (size_t)NXCD * NB * BCAP);
  float* esrc   = (float*)alloc(sizeof(float) * N_NODES);
  float* edst   = (float*)alloc(sizeof(float) * N_NODES);
  int*   deg    = (int*)alloc(sizeof(int) * N_NODES);
  // zero-init region: bcur + stats contiguous -> one memset
  char*  zbase  = alloc(sizeof(int) * NXCD * NB + 256 + sizeof(float) * 4 * 128);
  int*   bcur   = (int*)zbase;
  float* stats  = (float*)(zbase + ((sizeof(int) * NXCD * NB + 255) & ~(size_t)255));
  float* gsum0 = stats;        float* gsq0  = stats + 128;
  float* gsum2 = stats + 256;  float* gsq2  = stats + 384;
  size_t zsize = (size_t)((char*)(stats + 512) - zbase);

  hipMemsetAsync(zbase, 0, zsize, stream);

  const int gT = (N_NODES + 63) / 64;          // 782 MFMA tiles
  const int gE = (N_EDGES + 255) / 256;        // 3125

  k_prep<<<(HDIM * D_INPUT + 255) / 256, 256, 0, stream>>>(W, W1, W2, Wt0, Wt1, Wt2);
  k_gemm_xw_mfma<<<gT, 256, 0, stream>>>(x, Wt0, a_src, a_dst, h, esrc, edst);
  k_bin<<<gE, 256, 0, stream>>>(srcI, dstI, bcur, bbuf);
  k_scatter2<<<NB, 256, 0, stream>>>(bcur, bbuf, esrc, edst, deg, sedge);
  k_agg<<<N_NODES / 4, 256, 0, stream>>>(deg, sedge, h, b_gat, h0);
  k_bnstats<<<(N_NODES + 127) / 128, 256, 0, stream>>>(h0, gsum0, gsq0);
  k_fc_mfma<<<gT, 256, 0, stream>>>(h0, gsum0, gsq0, g0, beta0, Wt1, b1, h1,
                                    nullptr, nullptr, 1, 0);
  k_fc_mfma<<<gT, 256, 0, stream>>>(h1, nullptr, nullptr, nullptr, nullptr, Wt2, b2, h2,
                                    gsum2, gsq2, 0, 1);
  k_fc3<<<(N_NODES + 7) / 8, 256, 0, stream>>>(h2, gsum2, gsq2, g2, beta2, W3, b3, out);
}

// Round 6
// 311.286 us; speedup vs baseline: 1.1547x; 1.1547x over previous
//
#include <hip/hip_runtime.h>
#include <math.h>

#define N_NODES 50000
#define N_EDGES 800000
#define D_INPUT 256
#define HDIM 128
#define A_DIM 32
#define NEG_SLOPE 0.2f
#define BN_EPS 1e-5f
#define CAP 64   // max degree capacity; Poisson(16): P(deg>=64) ~ 1e-21

typedef short short8 __attribute__((ext_vector_type(8)));
typedef unsigned short ushort8v __attribute__((ext_vector_type(8)));
typedef unsigned short ushort4v __attribute__((ext_vector_type(4)));
typedef float float4v __attribute__((ext_vector_type(4)));

__device__ __forceinline__ unsigned short f2bf(float f) {
  unsigned u = __float_as_uint(f);
  u += 0x7FFFu + ((u >> 16) & 1u);
  return (unsigned short)(u >> 16);
}
__device__ __forceinline__ float bf2f(unsigned short b) {
  return __uint_as_float(((unsigned)b) << 16);
}

__device__ __forceinline__ float waveReduceMax(float v) {
#pragma unroll
  for (int o = 32; o >= 1; o >>= 1) v = fmaxf(v, __shfl_xor(v, o, 64));
  return v;
}
__device__ __forceinline__ float waveReduceSum(float v) {
#pragma unroll
  for (int o = 32; o >= 1; o >>= 1) v += __shfl_xor(v, o, 64);
  return v;
}

// ---------------- prep: W -> Wt (bf16, transposed [n][k]) -------------------
__global__ __launch_bounds__(256) void k_prep(
    const float* __restrict__ W, const float* __restrict__ W1,
    const float* __restrict__ W2, unsigned short* __restrict__ Wt0,
    unsigned short* __restrict__ Wt1, unsigned short* __restrict__ Wt2)
{
  int i = blockIdx.x * 256 + threadIdx.x;
  if (i < HDIM * D_INPUT) {                 // Wt0[n][k], 128 x 256
    int n = i >> 8, k = i & 255;
    Wt0[i] = f2bf(W[(size_t)k * HDIM + n]);
  }
  if (i < HDIM * HDIM) {                    // Wt1/Wt2[n][k], 128 x 128
    int n = i >> 7, k = i & 127;
    Wt1[i] = f2bf(W1[(size_t)k * HDIM + n]);
    Wt2[i] = f2bf(W2[(size_t)k * HDIM + n]);
  }
}

// ---------------- K1: h(bf16) = x @ W, plus esrc/edst (MFMA) ----------------
__global__ __launch_bounds__(256) void k_gemm_xw_mfma(
    const float* __restrict__ x, const unsigned short* __restrict__ Wt0,
    const float* __restrict__ a_src, const float* __restrict__ a_dst,
    unsigned short* __restrict__ hbf, float* __restrict__ esrc, float* __restrict__ edst)
{
  __shared__ short As[64][72];   // [m][k] bf16
  __shared__ short Bs[128][72];  // [n][k] bf16
  __shared__ float esred[64][2], edred[64][2];

  const int t = threadIdx.x;
  const int lane = t & 63;
  const int wv = t >> 6;
  const int rh = wv >> 1;
  const int ch = wv & 1;
  const int quad = (lane >> 4) & 3;
  const int l15 = lane & 15;
  const int row0 = blockIdx.x * 64;

  float4v acc[2][4];
#pragma unroll
  for (int i = 0; i < 2; ++i)
#pragma unroll
    for (int j = 0; j < 4; ++j) acc[i][j] = (float4v){0.f, 0.f, 0.f, 0.f};

  for (int ks = 0; ks < D_INPUT / 64; ++ks) {
    const int kk0 = ks * 64;
#pragma unroll
    for (int it = 0; it < 4; ++it) {
      int idx = it * 256 + t;
      int r = idx >> 4, c4 = idx & 15;
      int rr = row0 + r; if (rr >= N_NODES) rr = N_NODES - 1;
      float4 v = *(const float4*)(x + (size_t)rr * D_INPUT + kk0 + c4 * 4);
      ushort4v b; b.x = f2bf(v.x); b.y = f2bf(v.y); b.z = f2bf(v.z); b.w = f2bf(v.w);
      *(ushort4v*)(&As[r][c4 * 4]) = b;
    }
#pragma unroll
    for (int it = 0; it < 4; ++it) {
      int idx = it * 256 + t;
      int n = idx >> 3, c8 = idx & 7;
      *(ushort8v*)(&Bs[n][c8 * 8]) = *(const ushort8v*)(Wt0 + (size_t)n * D_INPUT + kk0 + c8 * 8);
    }
    __syncthreads();
#pragma unroll
    for (int kc = 0; kc < 2; ++kc) {
      short8 af[2], bfr[4];
#pragma unroll
      for (int rt = 0; rt < 2; ++rt)
        af[rt] = *(const short8*)(&As[rh * 32 + rt * 16 + l15][kc * 32 + quad * 8]);
#pragma unroll
      for (int nt = 0; nt < 4; ++nt)
        bfr[nt] = *(const short8*)(&Bs[ch * 64 + nt * 16 + l15][kc * 32 + quad * 8]);
#pragma unroll
      for (int rt = 0; rt < 2; ++rt)
#pragma unroll
        for (int nt = 0; nt < 4; ++nt)
          acc[rt][nt] = __builtin_amdgcn_mfma_f32_16x16x32_bf16(af[rt], bfr[nt], acc[rt][nt], 0, 0, 0);
    }
    __syncthreads();
  }

  float asv[4], adv[4];
#pragma unroll
  for (int nt = 0; nt < 4; ++nt) {
    int col = ch * 64 + nt * 16 + l15;
    asv[nt] = a_src[col]; adv[nt] = a_dst[col];
  }
#pragma unroll
  for (int rt = 0; rt < 2; ++rt) {
#pragma unroll
    for (int reg = 0; reg < 4; ++reg) {
      int rloc = rh * 32 + rt * 16 + quad * 4 + reg;
      int row = row0 + rloc;
      bool valid = (row < N_NODES);
      float ps = 0.f, pd = 0.f;
#pragma unroll
      for (int nt = 0; nt < 4; ++nt) {
        float v = acc[rt][nt][reg];
        ps += v * asv[nt]; pd += v * adv[nt];
        if (valid) hbf[(size_t)row * HDIM + ch * 64 + nt * 16 + l15] = f2bf(v);
      }
#pragma unroll
      for (int o = 8; o >= 1; o >>= 1) {
        ps += __shfl_xor(ps, o, 64);
        pd += __shfl_xor(pd, o, 64);
      }
      if (l15 == 0) { esred[rloc][ch] = ps; edred[rloc][ch] = pd; }
    }
  }
  __syncthreads();
  if (t < 64) {
    int row = row0 + t;
    if (row < N_NODES) {
      esrc[row] = esred[t][0] + esred[t][1];
      edst[row] = edred[t][0] + edred[t][1];
    }
  }
}

// ---------------- scatter into fixed-capacity dst buckets -------------------
__global__ __launch_bounds__(256) void k_scatter(
    const int* __restrict__ srcI, const int* __restrict__ dstI,
    const float* __restrict__ esrc, const float* __restrict__ edst,
    int* __restrict__ cursor, int2* __restrict__ sedge)
{
  int e = blockIdx.x * 256 + threadIdx.x;
  if (e < N_EDGES) {
    int s = srcI[e], d = dstI[e];
    float v = esrc[s] + edst[d];
    v = (v > 0.f) ? v : NEG_SLOPE * v;
    int r = atomicAdd(&cursor[d], 1);
    if (r < CAP) {
      int2 ev; ev.x = s; ev.y = __float_as_int(v);
      sedge[(size_t)d * CAP + r] = ev;
    }
  }
}

// ---------------- per-dst softmax + aggregation: 1 wave per node ------------
__global__ __launch_bounds__(256) void k_agg(
    const int* __restrict__ cursor, const int2* __restrict__ sedge,
    const unsigned short* __restrict__ hbf,
    const float* __restrict__ b_gat, unsigned short* __restrict__ h0)
{
  const int t = threadIdx.x;
  const int lane = t & 63;
  const int node = blockIdx.x * 4 + (t >> 6);
  const int deg = min(cursor[node], CAP);

  int2 ev; ev.x = 0; ev.y = 0;
  float val = -INFINITY;
  if (lane < deg) {
    ev = sedge[(size_t)node * CAP + lane];
    val = __int_as_float(ev.y);
  }
  const float m = waveReduceMax(val);
  const float ex = (lane < deg) ? __expf(val - m) : 0.f;
  const float s = waveReduceSum(ex);
  const float al = ex * (1.0f / fmaxf(s, 1e-16f));
  const int sr = ev.x;

  float ax = 0.f, ay = 0.f;
  int j = 0;
  for (; j + 4 <= deg; j += 4) {
    float a0 = __shfl(al, j, 64),   a1 = __shfl(al, j+1, 64);
    float a2 = __shfl(al, j+2, 64), a3 = __shfl(al, j+3, 64);
    int s0 = __shfl(sr, j, 64),   s1 = __shfl(sr, j+1, 64);
    int s2 = __shfl(sr, j+2, 64), s3 = __shfl(sr, j+3, 64);
    unsigned v0 = *(const unsigned*)(hbf + (size_t)s0 * HDIM + lane * 2);
    unsigned v1 = *(const unsigned*)(hbf + (size_t)s1 * HDIM + lane * 2);
    unsigned v2 = *(const unsigned*)(hbf + (size_t)s2 * HDIM + lane * 2);
    unsigned v3 = *(const unsigned*)(hbf + (size_t)s3 * HDIM + lane * 2);
    ax += a0 * bf2f((unsigned short)(v0 & 0xFFFFu))
        + a1 * bf2f((unsigned short)(v1 & 0xFFFFu))
        + a2 * bf2f((unsigned short)(v2 & 0xFFFFu))
        + a3 * bf2f((unsigned short)(v3 & 0xFFFFu));
    ay += a0 * bf2f((unsigned short)(v0 >> 16))
        + a1 * bf2f((unsigned short)(v1 >> 16))
        + a2 * bf2f((unsigned short)(v2 >> 16))
        + a3 * bf2f((unsigned short)(v3 >> 16));
  }
  for (; j < deg; ++j) {
    float a = __shfl(al, j, 64);
    int sj = __shfl(sr, j, 64);
    unsigned v = *(const unsigned*)(hbf + (size_t)sj * HDIM + lane * 2);
    ax += a * bf2f((unsigned short)(v & 0xFFFFu));
    ay += a * bf2f((unsigned short)(v >> 16));
  }
  float vx = fmaxf(ax + b_gat[lane * 2], 0.f);
  float vy = fmaxf(ay + b_gat[lane * 2 + 1], 0.f);
  *(unsigned*)(h0 + (size_t)node * HDIM + lane * 2) =
      (unsigned)f2bf(vx) | ((unsigned)f2bf(vy) << 16);
}

// ---------------- BN column stats (bf16 input) ------------------------------
__global__ __launch_bounds__(256) void k_bnstats(
    const unsigned short* __restrict__ src, float* __restrict__ gsum, float* __restrict__ gsq)
{
  __shared__ float ls[256], lq[256];
  const int t = threadIdx.x;
  const int c = t & 127, r2 = t >> 7;
  const int row0 = blockIdx.x * 128;
  float s = 0.f, q = 0.f;
  for (int i = 0; i < 64; ++i) {
    int row = row0 + i * 2 + r2;
    if (row < N_NODES) {
      float v = bf2f(src[(size_t)row * HDIM + c]);
      s += v; q += v * v;
    }
  }
  ls[t] = s; lq[t] = q; __syncthreads();
  if (t < 128) {
    atomicAdd(&gsum[t], ls[t] + ls[t + 128]);
    atomicAdd(&gsq[t],  lq[t] + lq[t + 128]);
  }
}

// ---------------- fused FC1+FC2 (MFMA), BN0 inline, BN2 stats out -----------
// h2 = relu( relu(BN0(h0) @ W1 + b1) @ W2 + b2 ); h1 tile lives in LDS only
__global__ __launch_bounds__(256) void k_fc12(
    const unsigned short* __restrict__ in,
    const float* __restrict__ gsumIn, const float* __restrict__ gsqIn,
    const float* __restrict__ gamma, const float* __restrict__ beta,
    const unsigned short* __restrict__ Wt1, const float* __restrict__ b1,
    const unsigned short* __restrict__ Wt2, const float* __restrict__ b2,
    unsigned short* __restrict__ outp,
    float* __restrict__ gsum, float* __restrict__ gsq)
{
  __shared__ short As[64 * 72];     // A chunk [m][k], stride 72
  __shared__ short Bsh[128 * 72];   // B chunk [n][k], stride 72 (reused fc1/fc2)
  __shared__ short H1[64 * 136];    // h1 tile [m][k=128], stride 136
  __shared__ float statS[128][2], statQ[128][2];
  __shared__ float sc[HDIM], shf[HDIM];

  const int t = threadIdx.x;
  const int lane = t & 63;
  const int wv = t >> 6;
  const int rh = wv >> 1;
  const int ch = wv & 1;
  const int quad = (lane >> 4) & 3;
  const int l15 = lane & 15;
  const int row0 = blockIdx.x * 64;

  if (t < HDIM) {
    float mean = gsumIn[t] / (float)N_NODES;
    float var = gsqIn[t] / (float)N_NODES - mean * mean;
    float s = gamma[t] * rsqrtf(var + BN_EPS);
    sc[t] = s; shf[t] = beta[t] - mean * s;
  }
  __syncthreads();

  float4v acc[2][4];
#pragma unroll
  for (int i = 0; i < 2; ++i)
#pragma unroll
    for (int j = 0; j < 4; ++j) acc[i][j] = (float4v){0.f, 0.f, 0.f, 0.f};

  // ---- FC1 K-loop ----
  for (int ks = 0; ks < 2; ++ks) {
    const int kk0 = ks * 64;
#pragma unroll
    for (int it = 0; it < 2; ++it) {
      int idx = it * 256 + t;
      int r = idx >> 3, c8 = idx & 7;
      int rr = row0 + r; if (rr >= N_NODES) rr = N_NODES - 1;
      ushort8v v = *(const ushort8v*)(in + (size_t)rr * HDIM + kk0 + c8 * 8);
#pragma unroll
      for (int j = 0; j < 8; ++j) {
        int k = kk0 + c8 * 8 + j;
        v[j] = f2bf(bf2f(v[j]) * sc[k] + shf[k]);
      }
      *(ushort8v*)(&As[r * 72 + c8 * 8]) = v;
    }
#pragma unroll
    for (int it = 0; it < 4; ++it) {
      int idx = it * 256 + t;
      int n = idx >> 3, c8 = idx & 7;
      *(ushort8v*)(&Bsh[n * 72 + c8 * 8]) = *(const ushort8v*)(Wt1 + (size_t)n * HDIM + kk0 + c8 * 8);
    }
    __syncthreads();
#pragma unroll
    for (int kc = 0; kc < 2; ++kc) {
      short8 af[2], bfr[4];
#pragma unroll
      for (int rt = 0; rt < 2; ++rt)
        af[rt] = *(const short8*)(&As[(rh * 32 + rt * 16 + l15) * 72 + kc * 32 + quad * 8]);
#pragma unroll
      for (int nt = 0; nt < 4; ++nt)
        bfr[nt] = *(const short8*)(&Bsh[(ch * 64 + nt * 16 + l15) * 72 + kc * 32 + quad * 8]);
#pragma unroll
      for (int rt = 0; rt < 2; ++rt)
#pragma unroll
        for (int nt = 0; nt < 4; ++nt)
          acc[rt][nt] = __builtin_amdgcn_mfma_f32_16x16x32_bf16(af[rt], bfr[nt], acc[rt][nt], 0, 0, 0);
    }
    __syncthreads();
  }

  // ---- epilogue 1: h1 = relu(acc + b1), bf16, into LDS H1 ----
  {
    float bv[4];
#pragma unroll
    for (int nt = 0; nt < 4; ++nt) bv[nt] = b1[ch * 64 + nt * 16 + l15];
#pragma unroll
    for (int rt = 0; rt < 2; ++rt) {
#pragma unroll
      for (int reg = 0; reg < 4; ++reg) {
        int rloc = rh * 32 + rt * 16 + quad * 4 + reg;
#pragma unroll
        for (int nt = 0; nt < 4; ++nt) {
          float o = fmaxf(acc[rt][nt][reg] + bv[nt], 0.f);
          H1[rloc * 136 + ch * 64 + nt * 16 + l15] = f2bf(o);
        }
      }
    }
  }
  __syncthreads();

  // ---- FC2 K-loop (A from LDS H1) ----
#pragma unroll
  for (int i = 0; i < 2; ++i)
#pragma unroll
    for (int j = 0; j < 4; ++j) acc[i][j] = (float4v){0.f, 0.f, 0.f, 0.f};

  for (int ks = 0; ks < 2; ++ks) {
    const int kk0 = ks * 64;
#pragma unroll
    for (int it = 0; it < 4; ++it) {
      int idx = it * 256 + t;
      int n = idx >> 3, c8 = idx & 7;
      *(ushort8v*)(&Bsh[n * 72 + c8 * 8]) = *(const ushort8v*)(Wt2 + (size_t)n * HDIM + kk0 + c8 * 8);
    }
    __syncthreads();
#pragma unroll
    for (int kc = 0; kc < 2; ++kc) {
      short8 af[2], bfr[4];
#pragma unroll
      for (int rt = 0; rt < 2; ++rt)
        af[rt] = *(const short8*)(&H1[(rh * 32 + rt * 16 + l15) * 136 + kk0 + kc * 32 + quad * 8]);
#pragma unroll
      for (int nt = 0; nt < 4; ++nt)
        bfr[nt] = *(const short8*)(&Bsh[(ch * 64 + nt * 16 + l15) * 72 + kc * 32 + quad * 8]);
#pragma unroll
      for (int rt = 0; rt < 2; ++rt)
#pragma unroll
        for (int nt = 0; nt < 4; ++nt)
          acc[rt][nt] = __builtin_amdgcn_mfma_f32_16x16x32_bf16(af[rt], bfr[nt], acc[rt][nt], 0, 0, 0);
    }
    __syncthreads();
  }

  // ---- epilogue 2: h2 = relu(acc + b2), store + BN2 stats ----
  float bv[4];
#pragma unroll
  for (int nt = 0; nt < 4; ++nt) bv[nt] = b2[ch * 64 + nt * 16 + l15];

  float pS[4] = {0.f, 0.f, 0.f, 0.f}, pQ[4] = {0.f, 0.f, 0.f, 0.f};
#pragma unroll
  for (int rt = 0; rt < 2; ++rt) {
#pragma unroll
    for (int reg = 0; reg < 4; ++reg) {
      int row = row0 + rh * 32 + rt * 16 + quad * 4 + reg;
      bool valid = (row < N_NODES);
#pragma unroll
      for (int nt = 0; nt < 4; ++nt) {
        float o = fmaxf(acc[rt][nt][reg] + bv[nt], 0.f);
        if (valid) {
          outp[(size_t)row * HDIM + ch * 64 + nt * 16 + l15] = f2bf(o);
          pS[nt] += o; pQ[nt] += o * o;
        }
      }
    }
  }
#pragma unroll
  for (int nt = 0; nt < 4; ++nt) {
    float s = pS[nt], q = pQ[nt];
    s += __shfl_xor(s, 16, 64); s += __shfl_xor(s, 32, 64);
    q += __shfl_xor(q, 16, 64); q += __shfl_xor(q, 32, 64);
    if (lane < 16) {
      statS[ch * 64 + nt * 16 + lane][rh] = s;
      statQ[ch * 64 + nt * 16 + lane][rh] = q;
    }
  }
  __syncthreads();
  if (t < 128) {
    atomicAdd(&gsum[t], statS[t][0] + statS[t][1]);
    atomicAdd(&gsq[t],  statQ[t][0] + statQ[t][1]);
  }
}

// ---------------- fc3 + row softmax (inline BN params) ----------------------
__global__ __launch_bounds__(256) void k_fc3(
    const unsigned short* __restrict__ h2,
    const float* __restrict__ gsumIn, const float* __restrict__ gsqIn,
    const float* __restrict__ gamma, const float* __restrict__ beta,
    const float* __restrict__ W3, const float* __restrict__ b3,
    float* __restrict__ out)
{
  __shared__ float w3s[HDIM * A_DIM];
  __shared__ float s2[HDIM], sh2[HDIM];
  const int t = threadIdx.x;
  for (int l = t; l < HDIM * A_DIM; l += 256) w3s[l] = W3[l];
  if (t < HDIM) {
    float mean = gsumIn[t] / (float)N_NODES;
    float var = gsqIn[t] / (float)N_NODES - mean * mean;
    float s = gamma[t] * rsqrtf(var + BN_EPS);
    s2[t] = s; sh2[t] = beta[t] - mean * s;
  }
  __syncthreads();

  const int j = t & 31;
  const int rloc = t >> 5;
  const int row = blockIdx.x * 8 + rloc;
  if (row >= N_NODES) return;

  float dotv = 0.f;
  const unsigned short* hrow = h2 + (size_t)row * HDIM;
#pragma unroll 4
  for (int k = 0; k < HDIM; ++k) {
    float hv = bf2f(hrow[k]) * s2[k] + sh2[k];
    dotv += hv * w3s[k * A_DIM + j];
  }
  float logit = dotv + b3[j];
  float mx = logit;
#pragma unroll
  for (int o = 16; o >= 1; o >>= 1) mx = fmaxf(mx, __shfl_xor(mx, o, 32));
  float ex = __expf(logit - mx);
  float sm = ex;
#pragma unroll
  for (int o = 16; o >= 1; o >>= 1) sm += __shfl_xor(sm, o, 32);
  out[(size_t)row * A_DIM + j] = ex / sm;
}

// ---------------------------------------------------------------------------
extern "C" void kernel_launch(void* const* d_in, const int* in_sizes, int n_in,
                              void* d_out, int out_size, void* d_ws, size_t ws_size,
                              hipStream_t stream) {
  const float* x     = (const float*)d_in[0];
  const int*   ei    = (const int*)d_in[1];
  const float* W     = (const float*)d_in[2];
  const float* a_src = (const float*)d_in[3];
  const float* a_dst = (const float*)d_in[4];
  const float* b_gat = (const float*)d_in[5];
  const float* g0    = (const float*)d_in[6];
  const float* beta0 = (const float*)d_in[7];
  const float* W1    = (const float*)d_in[8];
  const float* b1    = (const float*)d_in[9];
  const float* W2    = (const float*)d_in[10];
  const float* b2    = (const float*)d_in[11];
  const float* g2    = (const float*)d_in[12];
  const float* beta2 = (const float*)d_in[13];
  const float* W3    = (const float*)d_in[14];
  const float* b3    = (const float*)d_in[15];
  float* out = (float*)d_out;
  const int* srcI = ei;
  const int* dstI = ei + N_EDGES;

  char* p = (char*)d_ws;
  auto alloc = [&](size_t bytes) -> char* {
    char* q = p; p += (bytes + 255) & ~(size_t)255; return q;
  };
  unsigned short* h   = (unsigned short*)alloc(sizeof(short) * (size_t)N_NODES * HDIM);
  unsigned short* h0  = (unsigned short*)alloc(sizeof(short) * (size_t)N_NODES * HDIM);
  unsigned short* h2  = (unsigned short*)alloc(sizeof(short) * (size_t)N_NODES * HDIM);
  unsigned short* Wt0 = (unsigned short*)alloc(sizeof(short) * HDIM * D_INPUT);
  unsigned short* Wt1 = (unsigned short*)alloc(sizeof(short) * HDIM * HDIM);
  unsigned short* Wt2 = (unsigned short*)alloc(sizeof(short) * HDIM * HDIM);
  int2*  sedge  = (int2*)alloc(sizeof(int2) * (size_t)N_NODES * CAP);
  float* esrc   = (float*)alloc(sizeof(float) * N_NODES);
  float* edst   = (float*)alloc(sizeof(float) * N_NODES);
  // zero-init region: cursor + stats contiguous -> one memset
  char*  zbase  = alloc(sizeof(int) * N_NODES + 256 + sizeof(float) * 4 * 128);
  int*   cursor = (int*)zbase;
  float* stats  = (float*)(zbase + ((sizeof(int) * N_NODES + 255) & ~(size_t)255));
  float* gsum0 = stats;        float* gsq0  = stats + 128;
  float* gsum2 = stats + 256;  float* gsq2  = stats + 384;
  size_t zsize = (size_t)((char*)(stats + 512) - zbase);

  hipMemsetAsync(zbase, 0, zsize, stream);

  const int gT = (N_NODES + 63) / 64;          // 782 MFMA tiles
  const int gE = (N_EDGES + 255) / 256;        // 3125

  k_prep<<<(HDIM * D_INPUT + 255) / 256, 256, 0, stream>>>(W, W1, W2, Wt0, Wt1, Wt2);
  k_gemm_xw_mfma<<<gT, 256, 0, stream>>>(x, Wt0, a_src, a_dst, h, esrc, edst);
  k_scatter<<<gE, 256, 0, stream>>>(srcI, dstI, esrc, edst, cursor, sedge);
  k_agg<<<N_NODES / 4, 256, 0, stream>>>(cursor, sedge, h, b_gat, h0);
  k_bnstats<<<(N_NODES + 127) / 128, 256, 0, stream>>>(h0, gsum0, gsq0);
  k_fc12<<<gT, 256, 0, stream>>>(h0, gsum0, gsq0, g0, beta0, Wt1, b1, Wt2, b2, h2,
                                 gsum2, gsq2);
  k_fc3<<<(N_NODES + 7) / 8, 256, 0, stream>>>(h2, gsum2, gsq2, g2, beta2, W3, b3, out);
}

// Round 7
// 281.284 us; speedup vs baseline: 1.2779x; 1.1067x over previous
//
#include <hip/hip_runtime.h>
#include <math.h>

#define N_NODES 50000
#define N_EDGES 800000
#define D_INPUT 256
#define HDIM 128
#define A_DIM 32
#define NEG_SLOPE 0.2f
#define BN_EPS 1e-5f
#define CAP 64        // max degree; Poisson(16): P(deg>=64) ~ 1e-21
#define NB 391        // dst bins of 128 nodes (391*128 = 50048)
#define BIN_SHIFT 7
#define BCAP 2432     // per-bin segment cap; lambda=2046, +8.5 sigma
#define GC_STRIDE 16  // pad bin counters to one per 64B line (R5 lesson)
#define EPB 4096      // edges per k_bin block

typedef short short8 __attribute__((ext_vector_type(8)));
typedef unsigned short ushort8v __attribute__((ext_vector_type(8)));
typedef unsigned short ushort4v __attribute__((ext_vector_type(4)));
typedef float float4v __attribute__((ext_vector_type(4)));

__device__ __forceinline__ unsigned short f2bf(float f) {
  unsigned u = __float_as_uint(f);
  u += 0x7FFFu + ((u >> 16) & 1u);
  return (unsigned short)(u >> 16);
}
__device__ __forceinline__ float bf2f(unsigned short b) {
  return __uint_as_float(((unsigned)b) << 16);
}

__device__ __forceinline__ float waveReduceMax(float v) {
#pragma unroll
  for (int o = 32; o >= 1; o >>= 1) v = fmaxf(v, __shfl_xor(v, o, 64));
  return v;
}
__device__ __forceinline__ float waveReduceSum(float v) {
#pragma unroll
  for (int o = 32; o >= 1; o >>= 1) v += __shfl_xor(v, o, 64);
  return v;
}

// ---------------- prep: W -> Wt (bf16, transposed [n][k]) -------------------
__global__ __launch_bounds__(256) void k_prep(
    const float* __restrict__ W, const float* __restrict__ W1,
    const float* __restrict__ W2, unsigned short* __restrict__ Wt0,
    unsigned short* __restrict__ Wt1, unsigned short* __restrict__ Wt2)
{
  int i = blockIdx.x * 256 + threadIdx.x;
  if (i < HDIM * D_INPUT) {                 // Wt0[n][k], 128 x 256
    int n = i >> 8, k = i & 255;
    Wt0[i] = f2bf(W[(size_t)k * HDIM + n]);
  }
  if (i < HDIM * HDIM) {                    // Wt1/Wt2[n][k], 128 x 128
    int n = i >> 7, k = i & 127;
    Wt1[i] = f2bf(W1[(size_t)k * HDIM + n]);
    Wt2[i] = f2bf(W2[(size_t)k * HDIM + n]);
  }
}

// ---------------- K1: h(bf16) = x @ W, plus esrc/edst (MFMA) ----------------
__global__ __launch_bounds__(256) void k_gemm_xw_mfma(
    const float* __restrict__ x, const unsigned short* __restrict__ Wt0,
    const float* __restrict__ a_src, const float* __restrict__ a_dst,
    unsigned short* __restrict__ hbf, float* __restrict__ esrc, float* __restrict__ edst)
{
  __shared__ short As[64][72];   // [m][k] bf16
  __shared__ short Bs[128][72];  // [n][k] bf16
  __shared__ float esred[64][2], edred[64][2];

  const int t = threadIdx.x;
  const int lane = t & 63;
  const int wv = t >> 6;
  const int rh = wv >> 1;
  const int ch = wv & 1;
  const int quad = (lane >> 4) & 3;
  const int l15 = lane & 15;
  const int row0 = blockIdx.x * 64;

  float4v acc[2][4];
#pragma unroll
  for (int i = 0; i < 2; ++i)
#pragma unroll
    for (int j = 0; j < 4; ++j) acc[i][j] = (float4v){0.f, 0.f, 0.f, 0.f};

  for (int ks = 0; ks < D_INPUT / 64; ++ks) {
    const int kk0 = ks * 64;
#pragma unroll
    for (int it = 0; it < 4; ++it) {
      int idx = it * 256 + t;
      int r = idx >> 4, c4 = idx & 15;
      int rr = row0 + r; if (rr >= N_NODES) rr = N_NODES - 1;
      float4 v = *(const float4*)(x + (size_t)rr * D_INPUT + kk0 + c4 * 4);
      ushort4v b; b.x = f2bf(v.x); b.y = f2bf(v.y); b.z = f2bf(v.z); b.w = f2bf(v.w);
      *(ushort4v*)(&As[r][c4 * 4]) = b;
    }
#pragma unroll
    for (int it = 0; it < 4; ++it) {
      int idx = it * 256 + t;
      int n = idx >> 3, c8 = idx & 7;
      *(ushort8v*)(&Bs[n][c8 * 8]) = *(const ushort8v*)(Wt0 + (size_t)n * D_INPUT + kk0 + c8 * 8);
    }
    __syncthreads();
#pragma unroll
    for (int kc = 0; kc < 2; ++kc) {
      short8 af[2], bfr[4];
#pragma unroll
      for (int rt = 0; rt < 2; ++rt)
        af[rt] = *(const short8*)(&As[rh * 32 + rt * 16 + l15][kc * 32 + quad * 8]);
#pragma unroll
      for (int nt = 0; nt < 4; ++nt)
        bfr[nt] = *(const short8*)(&Bs[ch * 64 + nt * 16 + l15][kc * 32 + quad * 8]);
#pragma unroll
      for (int rt = 0; rt < 2; ++rt)
#pragma unroll
        for (int nt = 0; nt < 4; ++nt)
          acc[rt][nt] = __builtin_amdgcn_mfma_f32_16x16x32_bf16(af[rt], bfr[nt], acc[rt][nt], 0, 0, 0);
    }
    __syncthreads();
  }

  float asv[4], adv[4];
#pragma unroll
  for (int nt = 0; nt < 4; ++nt) {
    int col = ch * 64 + nt * 16 + l15;
    asv[nt] = a_src[col]; adv[nt] = a_dst[col];
  }
#pragma unroll
  for (int rt = 0; rt < 2; ++rt) {
#pragma unroll
    for (int reg = 0; reg < 4; ++reg) {
      int rloc = rh * 32 + rt * 16 + quad * 4 + reg;
      int row = row0 + rloc;
      bool valid = (row < N_NODES);
      float ps = 0.f, pd = 0.f;
#pragma unroll
      for (int nt = 0; nt < 4; ++nt) {
        float v = acc[rt][nt][reg];
        ps += v * asv[nt]; pd += v * adv[nt];
        if (valid) hbf[(size_t)row * HDIM + ch * 64 + nt * 16 + l15] = f2bf(v);
      }
#pragma unroll
      for (int o = 8; o >= 1; o >>= 1) {
        ps += __shfl_xor(ps, o, 64);
        pd += __shfl_xor(pd, o, 64);
      }
      if (l15 == 0) { esred[rloc][ch] = ps; edred[rloc][ch] = pd; }
    }
  }
  __syncthreads();
  if (t < 64) {
    int row = row0 + t;
    if (row < N_NODES) {
      esrc[row] = esred[t][0] + esred[t][1];
      edst[row] = edred[t][0] + edred[t][1];
    }
  }
}

// ---------------- phase 1: bin by dst-range, block-reserved segments --------
// per-edge work: 2 LDS atomics; global atomics only per (block,bin) = 77k,
// counters padded to 1/line. payload 4B: src(16b) | d&127 (7b)
__global__ __launch_bounds__(256) void k_bin(
    const int* __restrict__ srcI, const int* __restrict__ dstI,
    int* __restrict__ gcur, int* __restrict__ bbuf)
{
  __shared__ int hist[NB];
  __shared__ int base[NB];
  const int t = threadIdx.x;
  const int e0 = blockIdx.x * EPB;
  const int e1 = min(e0 + EPB, N_EDGES);
  for (int i = t; i < NB; i += 256) hist[i] = 0;
  __syncthreads();
  for (int e = e0 + t; e < e1; e += 256)
    atomicAdd(&hist[dstI[e] >> BIN_SHIFT], 1);
  __syncthreads();
  for (int i = t; i < NB; i += 256) {
    base[i] = atomicAdd(&gcur[i * GC_STRIDE], hist[i]);
    hist[i] = 0;
  }
  __syncthreads();
  for (int e = e0 + t; e < e1; e += 256) {
    int d = dstI[e];
    int bin = d >> BIN_SHIFT;
    int r = atomicAdd(&hist[bin], 1) + base[bin];
    if (r < BCAP) bbuf[(size_t)bin * BCAP + r] = srcI[e] | ((d & 127) << 16);
  }
}

// ---------------- phase 2: per-bin rank + bucket build in LDS ---------------
// one block per bin; LDS atomics for ranks; coalesced masked write-out
__global__ __launch_bounds__(256) void k_sc2(
    const int* __restrict__ gcur, const int* __restrict__ bbuf,
    const float* __restrict__ esrc, const float* __restrict__ edst,
    int* __restrict__ deg, int2* __restrict__ sedge)
{
  __shared__ int2 bk[128][CAP];   // 64 KB
  __shared__ int lcur[128];
  __shared__ float ledst[128];
  const int t = threadIdx.x;
  const int bin = blockIdx.x;
  const int d0 = bin << BIN_SHIFT;
  if (t < 128) {
    lcur[t] = 0;
    int d = d0 + t;
    ledst[t] = (d < N_NODES) ? edst[d] : 0.f;
  }
  __syncthreads();
  const int cnt = min(gcur[bin * GC_STRIDE], BCAP);
  const int* seg = bbuf + (size_t)bin * BCAP;
  for (int i = t; i < cnt; i += 256) {
    int v = seg[i];
    int s = v & 0xFFFF;
    int dl = (v >> 16) & 127;
    float ev = esrc[s] + ledst[dl];
    ev = (ev > 0.f) ? ev : NEG_SLOPE * ev;
    int r = atomicAdd(&lcur[dl], 1);
    if (r < CAP) {
      int2 e2; e2.x = s; e2.y = __float_as_int(ev);
      bk[dl][r] = e2;
    }
  }
  __syncthreads();
  for (int idx = t; idx < 128 * CAP; idx += 256) {
    int dl = idx >> 6, sl = idx & 63;
    if (sl < lcur[dl])                       // d>=N_NODES has lcur==0
      sedge[(size_t)(d0 + dl) * CAP + sl] = bk[dl][sl];
  }
  if (t < 128) {
    int d = d0 + t;
    if (d < N_NODES) deg[d] = min(lcur[t], CAP);
  }
}

// ---------------- per-dst softmax + aggregation: 1 wave per node ------------
__global__ __launch_bounds__(256) void k_agg(
    const int* __restrict__ degA, const int2* __restrict__ sedge,
    const unsigned short* __restrict__ hbf,
    const float* __restrict__ b_gat, unsigned short* __restrict__ h0)
{
  const int t = threadIdx.x;
  const int lane = t & 63;
  const int node = blockIdx.x * 4 + (t >> 6);
  const int deg = min(degA[node], CAP);

  int2 ev; ev.x = 0; ev.y = 0;
  float val = -INFINITY;
  if (lane < deg) {
    ev = sedge[(size_t)node * CAP + lane];
    val = __int_as_float(ev.y);
  }
  const float m = waveReduceMax(val);
  const float ex = (lane < deg) ? __expf(val - m) : 0.f;
  const float s = waveReduceSum(ex);
  const float al = ex * (1.0f / fmaxf(s, 1e-16f));
  const int sr = ev.x;

  float ax = 0.f, ay = 0.f;
  int j = 0;
  for (; j + 4 <= deg; j += 4) {
    float a0 = __shfl(al, j, 64),   a1 = __shfl(al, j+1, 64);
    float a2 = __shfl(al, j+2, 64), a3 = __shfl(al, j+3, 64);
    int s0 = __shfl(sr, j, 64),   s1 = __shfl(sr, j+1, 64);
    int s2 = __shfl(sr, j+2, 64), s3 = __shfl(sr, j+3, 64);
    unsigned v0 = *(const unsigned*)(hbf + (size_t)s0 * HDIM + lane * 2);
    unsigned v1 = *(const unsigned*)(hbf + (size_t)s1 * HDIM + lane * 2);
    unsigned v2 = *(const unsigned*)(hbf + (size_t)s2 * HDIM + lane * 2);
    unsigned v3 = *(const unsigned*)(hbf + (size_t)s3 * HDIM + lane * 2);
    ax += a0 * bf2f((unsigned short)(v0 & 0xFFFFu))
        + a1 * bf2f((unsigned short)(v1 & 0xFFFFu))
        + a2 * bf2f((unsigned short)(v2 & 0xFFFFu))
        + a3 * bf2f((unsigned short)(v3 & 0xFFFFu));
    ay += a0 * bf2f((unsigned short)(v0 >> 16))
        + a1 * bf2f((unsigned short)(v1 >> 16))
        + a2 * bf2f((unsigned short)(v2 >> 16))
        + a3 * bf2f((unsigned short)(v3 >> 16));
  }
  for (; j < deg; ++j) {
    float a = __shfl(al, j, 64);
    int sj = __shfl(sr, j, 64);
    unsigned v = *(const unsigned*)(hbf + (size_t)sj * HDIM + lane * 2);
    ax += a * bf2f((unsigned short)(v & 0xFFFFu));
    ay += a * bf2f((unsigned short)(v >> 16));
  }
  float vx = fmaxf(ax + b_gat[lane * 2], 0.f);
  float vy = fmaxf(ay + b_gat[lane * 2 + 1], 0.f);
  *(unsigned*)(h0 + (size_t)node * HDIM + lane * 2) =
      (unsigned)f2bf(vx) | ((unsigned)f2bf(vy) << 16);
}

// ---------------- BN column stats, ushort8-vectorized -----------------------
#define BN_ROWS 256
__global__ __launch_bounds__(256) void k_bnstats(
    const unsigned short* __restrict__ src, float* __restrict__ gsum, float* __restrict__ gsq)
{
  __shared__ float red[16][128];
  const int t = threadIdx.x;
  const int cg = t & 15;       // col group: cols cg*8..cg*8+7
  const int rl = t >> 4;       // 16 row lanes
  const int row0 = blockIdx.x * BN_ROWS;
  float s[8], q[8];
#pragma unroll
  for (int j = 0; j < 8; ++j) { s[j] = 0.f; q[j] = 0.f; }
  for (int i = 0; i < BN_ROWS / 16; ++i) {
    int row = row0 + rl + i * 16;
    if (row < N_NODES) {
      ushort8v v = *(const ushort8v*)(src + (size_t)row * HDIM + cg * 8);
#pragma unroll
      for (int j = 0; j < 8; ++j) {
        float f = bf2f(v[j]);
        s[j] += f; q[j] += f * f;
      }
    }
  }
#pragma unroll
  for (int j = 0; j < 8; ++j) red[rl][cg * 8 + j] = s[j];
  __syncthreads();
  if (t < 128) {
    float S = 0.f;
#pragma unroll
    for (int r = 0; r < 16; ++r) S += red[r][t];
    atomicAdd(&gsum[t], S);
  }
  __syncthreads();
#pragma unroll
  for (int j = 0; j < 8; ++j) red[rl][cg * 8 + j] = q[j];
  __syncthreads();
  if (t < 128) {
    float Q = 0.f;
#pragma unroll
    for (int r = 0; r < 16; ++r) Q += red[r][t];
    atomicAdd(&gsq[t], Q);
  }
}

// ---------------- fused FC1+FC2 (MFMA), BN0 inline, BN2 stats out -----------
__global__ __launch_bounds__(256) void k_fc12(
    const unsigned short* __restrict__ in,
    const float* __restrict__ gsumIn, const float* __restrict__ gsqIn,
    const float* __restrict__ gamma, const float* __restrict__ beta,
    const unsigned short* __restrict__ Wt1, const float* __restrict__ b1,
    const unsigned short* __restrict__ Wt2, const float* __restrict__ b2,
    unsigned short* __restrict__ outp,
    float* __restrict__ gsum, float* __restrict__ gsq)
{
  __shared__ short As[64 * 72];
  __shared__ short Bsh[128 * 72];
  __shared__ short H1[64 * 136];
  __shared__ float statS[128][2], statQ[128][2];
  __shared__ float sc[HDIM], shf[HDIM];

  const int t = threadIdx.x;
  const int lane = t & 63;
  const int wv = t >> 6;
  const int rh = wv >> 1;
  const int ch = wv & 1;
  const int quad = (lane >> 4) & 3;
  const int l15 = lane & 15;
  const int row0 = blockIdx.x * 64;

  if (t < HDIM) {
    float mean = gsumIn[t] / (float)N_NODES;
    float var = gsqIn[t] / (float)N_NODES - mean * mean;
    float s = gamma[t] * rsqrtf(var + BN_EPS);
    sc[t] = s; shf[t] = beta[t] - mean * s;
  }
  __syncthreads();

  float4v acc[2][4];
#pragma unroll
  for (int i = 0; i < 2; ++i)
#pragma unroll
    for (int j = 0; j < 4; ++j) acc[i][j] = (float4v){0.f, 0.f, 0.f, 0.f};

  for (int ks = 0; ks < 2; ++ks) {
    const int kk0 = ks * 64;
#pragma unroll
    for (int it = 0; it < 2; ++it) {
      int idx = it * 256 + t;
      int r = idx >> 3, c8 = idx & 7;
      int rr = row0 + r; if (rr >= N_NODES) rr = N_NODES - 1;
      ushort8v v = *(const ushort8v*)(in + (size_t)rr * HDIM + kk0 + c8 * 8);
#pragma unroll
      for (int j = 0; j < 8; ++j) {
        int k = kk0 + c8 * 8 + j;
        v[j] = f2bf(bf2f(v[j]) * sc[k] + shf[k]);
      }
      *(ushort8v*)(&As[r * 72 + c8 * 8]) = v;
    }
#pragma unroll
    for (int it = 0; it < 4; ++it) {
      int idx = it * 256 + t;
      int n = idx >> 3, c8 = idx & 7;
      *(ushort8v*)(&Bsh[n * 72 + c8 * 8]) = *(const ushort8v*)(Wt1 + (size_t)n * HDIM + kk0 + c8 * 8);
    }
    __syncthreads();
#pragma unroll
    for (int kc = 0; kc < 2; ++kc) {
      short8 af[2], bfr[4];
#pragma unroll
      for (int rt = 0; rt < 2; ++rt)
        af[rt] = *(const short8*)(&As[(rh * 32 + rt * 16 + l15) * 72 + kc * 32 + quad * 8]);
#pragma unroll
      for (int nt = 0; nt < 4; ++nt)
        bfr[nt] = *(const short8*)(&Bsh[(ch * 64 + nt * 16 + l15) * 72 + kc * 32 + quad * 8]);
#pragma unroll
      for (int rt = 0; rt < 2; ++rt)
#pragma unroll
        for (int nt = 0; nt < 4; ++nt)
          acc[rt][nt] = __builtin_amdgcn_mfma_f32_16x16x32_bf16(af[rt], bfr[nt], acc[rt][nt], 0, 0, 0);
    }
    __syncthreads();
  }

  {
    float bv[4];
#pragma unroll
    for (int nt = 0; nt < 4; ++nt) bv[nt] = b1[ch * 64 + nt * 16 + l15];
#pragma unroll
    for (int rt = 0; rt < 2; ++rt) {
#pragma unroll
      for (int reg = 0; reg < 4; ++reg) {
        int rloc = rh * 32 + rt * 16 + quad * 4 + reg;
#pragma unroll
        for (int nt = 0; nt < 4; ++nt) {
          float o = fmaxf(acc[rt][nt][reg] + bv[nt], 0.f);
          H1[rloc * 136 + ch * 64 + nt * 16 + l15] = f2bf(o);
        }
      }
    }
  }
  __syncthreads();

#pragma unroll
  for (int i = 0; i < 2; ++i)
#pragma unroll
    for (int j = 0; j < 4; ++j) acc[i][j] = (float4v){0.f, 0.f, 0.f, 0.f};

  for (int ks = 0; ks < 2; ++ks) {
    const int kk0 = ks * 64;
#pragma unroll
    for (int it = 0; it < 4; ++it) {
      int idx = it * 256 + t;
      int n = idx >> 3, c8 = idx & 7;
      *(ushort8v*)(&Bsh[n * 72 + c8 * 8]) = *(const ushort8v*)(Wt2 + (size_t)n * HDIM + kk0 + c8 * 8);
    }
    __syncthreads();
#pragma unroll
    for (int kc = 0; kc < 2; ++kc) {
      short8 af[2], bfr[4];
#pragma unroll
      for (int rt = 0; rt < 2; ++rt)
        af[rt] = *(const short8*)(&H1[(rh * 32 + rt * 16 + l15) * 136 + kk0 + kc * 32 + quad * 8]);
#pragma unroll
      for (int nt = 0; nt < 4; ++nt)
        bfr[nt] = *(const short8*)(&Bsh[(ch * 64 + nt * 16 + l15) * 72 + kc * 32 + quad * 8]);
#pragma unroll
      for (int rt = 0; rt < 2; ++rt)
#pragma unroll
        for (int nt = 0; nt < 4; ++nt)
          acc[rt][nt] = __builtin_amdgcn_mfma_f32_16x16x32_bf16(af[rt], bfr[nt], acc[rt][nt], 0, 0, 0);
    }
    __syncthreads();
  }

  float bv[4];
#pragma unroll
  for (int nt = 0; nt < 4; ++nt) bv[nt] = b2[ch * 64 + nt * 16 + l15];

  float pS[4] = {0.f, 0.f, 0.f, 0.f}, pQ[4] = {0.f, 0.f, 0.f, 0.f};
#pragma unroll
  for (int rt = 0; rt < 2; ++rt) {
#pragma unroll
    for (int reg = 0; reg < 4; ++reg) {
      int row = row0 + rh * 32 + rt * 16 + quad * 4 + reg;
      bool valid = (row < N_NODES);
#pragma unroll
      for (int nt = 0; nt < 4; ++nt) {
        float o = fmaxf(acc[rt][nt][reg] + bv[nt], 0.f);
        if (valid) {
          outp[(size_t)row * HDIM + ch * 64 + nt * 16 + l15] = f2bf(o);
          pS[nt] += o; pQ[nt] += o * o;
        }
      }
    }
  }
#pragma unroll
  for (int nt = 0; nt < 4; ++nt) {
    float s = pS[nt], q = pQ[nt];
    s += __shfl_xor(s, 16, 64); s += __shfl_xor(s, 32, 64);
    q += __shfl_xor(q, 16, 64); q += __shfl_xor(q, 32, 64);
    if (lane < 16) {
      statS[ch * 64 + nt * 16 + lane][rh] = s;
      statQ[ch * 64 + nt * 16 + lane][rh] = q;
    }
  }
  __syncthreads();
  if (t < 128) {
    atomicAdd(&gsum[t], statS[t][0] + statS[t][1]);
    atomicAdd(&gsq[t],  statQ[t][0] + statQ[t][1]);
  }
}

// ---------------- fc3 + row softmax (LDS-staged rows, fp32 math) ------------
__global__ __launch_bounds__(256) void k_fc3(
    const unsigned short* __restrict__ h2,
    const float* __restrict__ gsumIn, const float* __restrict__ gsqIn,
    const float* __restrict__ gamma, const float* __restrict__ beta,
    const float* __restrict__ W3, const float* __restrict__ b3,
    float* __restrict__ out)
{
  __shared__ float w3s[HDIM * A_DIM];
  __shared__ float s2[HDIM], sh2[HDIM];
  __shared__ unsigned short hr[8][HDIM];
  const int t = threadIdx.x;
  for (int l = t; l < HDIM * A_DIM; l += 256) w3s[l] = W3[l];
  if (t < HDIM) {
    float mean = gsumIn[t] / (float)N_NODES;
    float var = gsqIn[t] / (float)N_NODES - mean * mean;
    float s = gamma[t] * rsqrtf(var + BN_EPS);
    s2[t] = s; sh2[t] = beta[t] - mean * s;
  }
  const int rbase = blockIdx.x * 8;
  if (t < 128) {                       // stage 8 rows, ushort8 vector loads
    int rr = t >> 4, cg = t & 15;
    int row = rbase + rr;
    if (row < N_NODES)
      *(ushort8v*)(&hr[rr][cg * 8]) =
          *(const ushort8v*)(h2 + (size_t)row * HDIM + cg * 8);
  }
  __syncthreads();

  const int j = t & 31;
  const int rloc = t >> 5;
  const int row = rbase + rloc;
  if (row >= N_NODES) return;

  float dotv = 0.f;
#pragma unroll 4
  for (int k = 0; k < HDIM; ++k) {
    float hv = bf2f(hr[rloc][k]) * s2[k] + sh2[k];
    dotv += hv * w3s[k * A_DIM + j];
  }
  float logit = dotv + b3[j];
  float mx = logit;
#pragma unroll
  for (int o = 16; o >= 1; o >>= 1) mx = fmaxf(mx, __shfl_xor(mx, o, 32));
  float ex = __expf(logit - mx);
  float sm = ex;
#pragma unroll
  for (int o = 16; o >= 1; o >>= 1) sm += __shfl_xor(sm, o, 32);
  out[(size_t)row * A_DIM + j] = ex / sm;
}

// ---------------------------------------------------------------------------
extern "C" void kernel_launch(void* const* d_in, const int* in_sizes, int n_in,
                              void* d_out, int out_size, void* d_ws, size_t ws_size,
                              hipStream_t stream) {
  const float* x     = (const float*)d_in[0];
  const int*   ei    = (const int*)d_in[1];
  const float* W     = (const float*)d_in[2];
  const float* a_src = (const float*)d_in[3];
  const float* a_dst = (const float*)d_in[4];
  const float* b_gat = (const float*)d_in[5];
  const float* g0    = (const float*)d_in[6];
  const float* beta0 = (const float*)d_in[7];
  const float* W1    = (const float*)d_in[8];
  const float* b1    = (const float*)d_in[9];
  const float* W2    = (const float*)d_in[10];
  const float* b2    = (const float*)d_in[11];
  const float* g2    = (const float*)d_in[12];
  const float* beta2 = (const float*)d_in[13];
  const float* W3    = (const float*)d_in[14];
  const float* b3    = (const float*)d_in[15];
  float* out = (float*)d_out;
  const int* srcI = ei;
  const int* dstI = ei + N_EDGES;

  char* p = (char*)d_ws;
  auto alloc = [&](size_t bytes) -> char* {
    char* q = p; p += (bytes + 255) & ~(size_t)255; return q;
  };
  unsigned short* h   = (unsigned short*)alloc(sizeof(short) * (size_t)N_NODES * HDIM);
  unsigned short* h0  = (unsigned short*)alloc(sizeof(short) * (size_t)N_NODES * HDIM);
  unsigned short* h2  = h;  // h dead after k_agg; reuse for fc12 output
  unsigned short* Wt0 = (unsigned short*)alloc(sizeof(short) * HDIM * D_INPUT);
  unsigned short* Wt1 = (unsigned short*)alloc(sizeof(short) * HDIM * HDIM);
  unsigned short* Wt2 = (unsigned short*)alloc(sizeof(short) * HDIM * HDIM);
  int2*  sedge  = (int2*)alloc(sizeof(int2) * (size_t)N_NODES * CAP);
  int*   bbuf   = (int*)alloc(sizeof(int) * (size_t)NB * BCAP);
  float* esrc   = (float*)alloc(sizeof(float) * N_NODES);
  float* edst   = (float*)alloc(sizeof(float) * N_NODES);
  int*   deg    = (int*)alloc(sizeof(int) * N_NODES);
  // zero-init region: gcur (line-padded) + stats -> one memset
  char*  zbase  = alloc(sizeof(int) * NB * GC_STRIDE + 256 + sizeof(float) * 4 * 128);
  int*   gcur   = (int*)zbase;
  float* stats  = (float*)(zbase + ((sizeof(int) * NB * GC_STRIDE + 255) & ~(size_t)255));
  float* gsum0 = stats;        float* gsq0  = stats + 128;
  float* gsum2 = stats + 256;  float* gsq2  = stats + 384;
  size_t zsize = (size_t)((char*)(stats + 512) - zbase);

  hipMemsetAsync(zbase, 0, zsize, stream);

  const int gT = (N_NODES + 63) / 64;          // 782 MFMA tiles
  const int gB = (N_EDGES + EPB - 1) / EPB;    // 196

  k_prep<<<(HDIM * D_INPUT + 255) / 256, 256, 0, stream>>>(W, W1, W2, Wt0, Wt1, Wt2);
  k_gemm_xw_mfma<<<gT, 256, 0, stream>>>(x, Wt0, a_src, a_dst, h, esrc, edst);
  k_bin<<<gB, 256, 0, stream>>>(srcI, dstI, gcur, bbuf);
  k_sc2<<<NB, 256, 0, stream>>>(gcur, bbuf, esrc, edst, deg, sedge);
  k_agg<<<N_NODES / 4, 256, 0, stream>>>(deg, sedge, h, b_gat, h0);
  k_bnstats<<<(N_NODES + BN_ROWS - 1) / BN_ROWS, 256, 0, stream>>>(h0, gsum0, gsq0);
  k_fc12<<<gT, 256, 0, stream>>>(h0, gsum0, gsq0, g0, beta0, Wt1, b1, Wt2, b2, h2,
                                 gsum2, gsq2);
  k_fc3<<<(N_NODES + 7) / 8, 256, 0, stream>>>(h2, gsum2, gsq2, g2, beta2, W3, b3, out);
}

// Round 8
// 265.934 us; speedup vs baseline: 1.3516x; 1.0577x over previous
//
#include <hip/hip_runtime.h>
#include <math.h>

#define N_NODES 50000
#define N_EDGES 800000
#define D_INPUT 256
#define HDIM 128
#define A_DIM 32
#define NEG_SLOPE 0.2f
#define BN_EPS 1e-5f
#define CAP 64        // max degree; Poisson(16): P(deg>=64) ~ 1e-21
#define NB 391        // dst bins of 128 nodes (391*128 = 50048)
#define BIN_SHIFT 7
#define BCAP 2432     // per-bin segment cap; lambda=2046, +8.5 sigma
#define GC_STRIDE 16  // pad bin counters to one per 64B line (R5 lesson)
#define EPB 4096      // edges per k_bin block
#define FC3_TR 64     // rows per k_fc3 block

typedef short short8 __attribute__((ext_vector_type(8)));
typedef unsigned short ushort8v __attribute__((ext_vector_type(8)));
typedef unsigned short ushort4v __attribute__((ext_vector_type(4)));
typedef float float4v __attribute__((ext_vector_type(4)));

__device__ __forceinline__ unsigned short f2bf(float f) {
  unsigned u = __float_as_uint(f);
  u += 0x7FFFu + ((u >> 16) & 1u);
  return (unsigned short)(u >> 16);
}
__device__ __forceinline__ float bf2f(unsigned short b) {
  return __uint_as_float(((unsigned)b) << 16);
}

__device__ __forceinline__ float waveReduceMax(float v) {
#pragma unroll
  for (int o = 32; o >= 1; o >>= 1) v = fmaxf(v, __shfl_xor(v, o, 64));
  return v;
}
__device__ __forceinline__ float waveReduceSum(float v) {
#pragma unroll
  for (int o = 32; o >= 1; o >>= 1) v += __shfl_xor(v, o, 64);
  return v;
}

// ---------------- K1: h(bf16) = x @ W, plus esrc/edst (MFMA) ----------------
__global__ __launch_bounds__(256) void k_gemm_xw_mfma(
    const float* __restrict__ x, const unsigned short* __restrict__ Wt0,
    const float* __restrict__ a_src, const float* __restrict__ a_dst,
    unsigned short* __restrict__ hbf, float* __restrict__ esrc, float* __restrict__ edst)
{
  __shared__ short As[64][72];   // [m][k] bf16
  __shared__ short Bs[128][72];  // [n][k] bf16
  __shared__ float esred[64][2], edred[64][2];

  const int t = threadIdx.x;
  const int lane = t & 63;
  const int wv = t >> 6;
  const int rh = wv >> 1;
  const int ch = wv & 1;
  const int quad = (lane >> 4) & 3;
  const int l15 = lane & 15;
  const int row0 = blockIdx.x * 64;

  float4v acc[2][4];
#pragma unroll
  for (int i = 0; i < 2; ++i)
#pragma unroll
    for (int j = 0; j < 4; ++j) acc[i][j] = (float4v){0.f, 0.f, 0.f, 0.f};

  for (int ks = 0; ks < D_INPUT / 64; ++ks) {
    const int kk0 = ks * 64;
#pragma unroll
    for (int it = 0; it < 4; ++it) {
      int idx = it * 256 + t;
      int r = idx >> 4, c4 = idx & 15;
      int rr = row0 + r; if (rr >= N_NODES) rr = N_NODES - 1;
      float4 v = *(const float4*)(x + (size_t)rr * D_INPUT + kk0 + c4 * 4);
      ushort4v b; b.x = f2bf(v.x); b.y = f2bf(v.y); b.z = f2bf(v.z); b.w = f2bf(v.w);
      *(ushort4v*)(&As[r][c4 * 4]) = b;
    }
#pragma unroll
    for (int it = 0; it < 4; ++it) {
      int idx = it * 256 + t;
      int n = idx >> 3, c8 = idx & 7;
      *(ushort8v*)(&Bs[n][c8 * 8]) = *(const ushort8v*)(Wt0 + (size_t)n * D_INPUT + kk0 + c8 * 8);
    }
    __syncthreads();
#pragma unroll
    for (int kc = 0; kc < 2; ++kc) {
      short8 af[2], bfr[4];
#pragma unroll
      for (int rt = 0; rt < 2; ++rt)
        af[rt] = *(const short8*)(&As[rh * 32 + rt * 16 + l15][kc * 32 + quad * 8]);
#pragma unroll
      for (int nt = 0; nt < 4; ++nt)
        bfr[nt] = *(const short8*)(&Bs[ch * 64 + nt * 16 + l15][kc * 32 + quad * 8]);
#pragma unroll
      for (int rt = 0; rt < 2; ++rt)
#pragma unroll
        for (int nt = 0; nt < 4; ++nt)
          acc[rt][nt] = __builtin_amdgcn_mfma_f32_16x16x32_bf16(af[rt], bfr[nt], acc[rt][nt], 0, 0, 0);
    }
    __syncthreads();
  }

  float asv[4], adv[4];
#pragma unroll
  for (int nt = 0; nt < 4; ++nt) {
    int col = ch * 64 + nt * 16 + l15;
    asv[nt] = a_src[col]; adv[nt] = a_dst[col];
  }
#pragma unroll
  for (int rt = 0; rt < 2; ++rt) {
#pragma unroll
    for (int reg = 0; reg < 4; ++reg) {
      int rloc = rh * 32 + rt * 16 + quad * 4 + reg;
      int row = row0 + rloc;
      bool valid = (row < N_NODES);
      float ps = 0.f, pd = 0.f;
#pragma unroll
      for (int nt = 0; nt < 4; ++nt) {
        float v = acc[rt][nt][reg];
        ps += v * asv[nt]; pd += v * adv[nt];
        if (valid) hbf[(size_t)row * HDIM + ch * 64 + nt * 16 + l15] = f2bf(v);
      }
#pragma unroll
      for (int o = 8; o >= 1; o >>= 1) {
        ps += __shfl_xor(ps, o, 64);
        pd += __shfl_xor(pd, o, 64);
      }
      if (l15 == 0) { esred[rloc][ch] = ps; edred[rloc][ch] = pd; }
    }
  }
  __syncthreads();
  if (t < 64) {
    int row = row0 + t;
    if (row < N_NODES) {
      esrc[row] = esred[t][0] + esred[t][1];
      edst[row] = edred[t][0] + edred[t][1];
    }
  }
}

// ---------------- phase 1: bin edges (+ merged weight prep blocks) ----------
// bin: per-edge 2 LDS atomics; global atomics only per (block,bin), counters
// line-padded. prep blocks (blockIdx >= gB) transpose W/W1/W2 to bf16 [n][k].
__global__ __launch_bounds__(256) void k_binprep(
    const int* __restrict__ srcI, const int* __restrict__ dstI,
    int* __restrict__ gcur, int* __restrict__ bbuf,
    const float* __restrict__ W, const float* __restrict__ W1,
    const float* __restrict__ W2, unsigned short* __restrict__ Wt0,
    unsigned short* __restrict__ Wt1, unsigned short* __restrict__ Wt2)
{
  const int gB = (N_EDGES + EPB - 1) / EPB;
  if (blockIdx.x >= gB) {           // ---- prep path ----
    int i = (blockIdx.x - gB) * 256 + threadIdx.x;
    if (i < HDIM * D_INPUT) {
      int n = i >> 8, k = i & 255;
      Wt0[i] = f2bf(W[(size_t)k * HDIM + n]);
    }
    if (i < HDIM * HDIM) {
      int n = i >> 7, k = i & 127;
      Wt1[i] = f2bf(W1[(size_t)k * HDIM + n]);
      Wt2[i] = f2bf(W2[(size_t)k * HDIM + n]);
    }
    return;
  }
  // ---- bin path ----
  __shared__ int hist[NB];
  __shared__ int base[NB];
  const int t = threadIdx.x;
  const int e0 = blockIdx.x * EPB;
  const int e1 = min(e0 + EPB, N_EDGES);
  for (int i = t; i < NB; i += 256) hist[i] = 0;
  __syncthreads();
  for (int e = e0 + t; e < e1; e += 256)
    atomicAdd(&hist[dstI[e] >> BIN_SHIFT], 1);
  __syncthreads();
  for (int i = t; i < NB; i += 256) {
    base[i] = atomicAdd(&gcur[i * GC_STRIDE], hist[i]);
    hist[i] = 0;
  }
  __syncthreads();
  for (int e = e0 + t; e < e1; e += 256) {
    int d = dstI[e];
    int bin = d >> BIN_SHIFT;
    int r = atomicAdd(&hist[bin], 1) + base[bin];
    if (r < BCAP) bbuf[(size_t)bin * BCAP + r] = srcI[e] | ((d & 127) << 16);
  }
}

// ---------------- phase 2: per-bin rank + bucket build in LDS ---------------
__global__ __launch_bounds__(256) void k_sc2(
    const int* __restrict__ gcur, const int* __restrict__ bbuf,
    const float* __restrict__ esrc, const float* __restrict__ edst,
    int* __restrict__ deg, int2* __restrict__ sedge)
{
  __shared__ int2 bk[128][CAP];   // 64 KB
  __shared__ int lcur[128];
  __shared__ float ledst[128];
  const int t = threadIdx.x;
  const int bin = blockIdx.x;
  const int d0 = bin << BIN_SHIFT;
  if (t < 128) {
    lcur[t] = 0;
    int d = d0 + t;
    ledst[t] = (d < N_NODES) ? edst[d] : 0.f;
  }
  __syncthreads();
  const int cnt = min(gcur[bin * GC_STRIDE], BCAP);
  const int* seg = bbuf + (size_t)bin * BCAP;
  for (int i = t; i < cnt; i += 256) {
    int v = seg[i];
    int s = v & 0xFFFF;
    int dl = (v >> 16) & 127;
    float ev = esrc[s] + ledst[dl];
    ev = (ev > 0.f) ? ev : NEG_SLOPE * ev;
    int r = atomicAdd(&lcur[dl], 1);
    if (r < CAP) {
      int2 e2; e2.x = s; e2.y = __float_as_int(ev);
      bk[dl][r] = e2;
    }
  }
  __syncthreads();
  for (int idx = t; idx < 128 * CAP; idx += 256) {
    int dl = idx >> 6, sl = idx & 63;
    if (sl < lcur[dl])
      sedge[(size_t)(d0 + dl) * CAP + sl] = bk[dl][sl];
  }
  if (t < 128) {
    int d = d0 + t;
    if (d < N_NODES) deg[d] = min(lcur[t], CAP);
  }
}

// ---------------- per-dst softmax + aggregation: 1 wave per node ------------
__global__ __launch_bounds__(256) void k_agg(
    const int* __restrict__ degA, const int2* __restrict__ sedge,
    const unsigned short* __restrict__ hbf,
    const float* __restrict__ b_gat, unsigned short* __restrict__ h0)
{
  const int t = threadIdx.x;
  const int lane = t & 63;
  const int node = blockIdx.x * 4 + (t >> 6);
  const int deg = min(degA[node], CAP);

  int2 ev; ev.x = 0; ev.y = 0;
  float val = -INFINITY;
  if (lane < deg) {
    ev = sedge[(size_t)node * CAP + lane];
    val = __int_as_float(ev.y);
  }
  const float m = waveReduceMax(val);
  const float ex = (lane < deg) ? __expf(val - m) : 0.f;
  const float s = waveReduceSum(ex);
  const float al = ex * (1.0f / fmaxf(s, 1e-16f));
  const int sr = ev.x;

  float ax = 0.f, ay = 0.f;
  int j = 0;
  for (; j + 4 <= deg; j += 4) {
    float a0 = __shfl(al, j, 64),   a1 = __shfl(al, j+1, 64);
    float a2 = __shfl(al, j+2, 64), a3 = __shfl(al, j+3, 64);
    int s0 = __shfl(sr, j, 64),   s1 = __shfl(sr, j+1, 64);
    int s2 = __shfl(sr, j+2, 64), s3 = __shfl(sr, j+3, 64);
    unsigned v0 = *(const unsigned*)(hbf + (size_t)s0 * HDIM + lane * 2);
    unsigned v1 = *(const unsigned*)(hbf + (size_t)s1 * HDIM + lane * 2);
    unsigned v2 = *(const unsigned*)(hbf + (size_t)s2 * HDIM + lane * 2);
    unsigned v3 = *(const unsigned*)(hbf + (size_t)s3 * HDIM + lane * 2);
    ax += a0 * bf2f((unsigned short)(v0 & 0xFFFFu))
        + a1 * bf2f((unsigned short)(v1 & 0xFFFFu))
        + a2 * bf2f((unsigned short)(v2 & 0xFFFFu))
        + a3 * bf2f((unsigned short)(v3 & 0xFFFFu));
    ay += a0 * bf2f((unsigned short)(v0 >> 16))
        + a1 * bf2f((unsigned short)(v1 >> 16))
        + a2 * bf2f((unsigned short)(v2 >> 16))
        + a3 * bf2f((unsigned short)(v3 >> 16));
  }
  for (; j < deg; ++j) {
    float a = __shfl(al, j, 64);
    int sj = __shfl(sr, j, 64);
    unsigned v = *(const unsigned*)(hbf + (size_t)sj * HDIM + lane * 2);
    ax += a * bf2f((unsigned short)(v & 0xFFFFu));
    ay += a * bf2f((unsigned short)(v >> 16));
  }
  float vx = fmaxf(ax + b_gat[lane * 2], 0.f);
  float vy = fmaxf(ay + b_gat[lane * 2 + 1], 0.f);
  *(unsigned*)(h0 + (size_t)node * HDIM + lane * 2) =
      (unsigned)f2bf(vx) | ((unsigned)f2bf(vy) << 16);
}

// ---------------- BN column stats, ushort8-vectorized -----------------------
#define BN_ROWS 256
__global__ __launch_bounds__(256) void k_bnstats(
    const unsigned short* __restrict__ src, float* __restrict__ gsum, float* __restrict__ gsq)
{
  __shared__ float red[16][128];
  const int t = threadIdx.x;
  const int cg = t & 15;
  const int rl = t >> 4;
  const int row0 = blockIdx.x * BN_ROWS;
  float s[8], q[8];
#pragma unroll
  for (int j = 0; j < 8; ++j) { s[j] = 0.f; q[j] = 0.f; }
  for (int i = 0; i < BN_ROWS / 16; ++i) {
    int row = row0 + rl + i * 16;
    if (row < N_NODES) {
      ushort8v v = *(const ushort8v*)(src + (size_t)row * HDIM + cg * 8);
#pragma unroll
      for (int j = 0; j < 8; ++j) {
        float f = bf2f(v[j]);
        s[j] += f; q[j] += f * f;
      }
    }
  }
#pragma unroll
  for (int j = 0; j < 8; ++j) red[rl][cg * 8 + j] = s[j];
  __syncthreads();
  if (t < 128) {
    float S = 0.f;
#pragma unroll
    for (int r = 0; r < 16; ++r) S += red[r][t];
    atomicAdd(&gsum[t], S);
  }
  __syncthreads();
#pragma unroll
  for (int j = 0; j < 8; ++j) red[rl][cg * 8 + j] = q[j];
  __syncthreads();
  if (t < 128) {
    float Q = 0.f;
#pragma unroll
    for (int r = 0; r < 16; ++r) Q += red[r][t];
    atomicAdd(&gsq[t], Q);
  }
}

// ---------------- fused FC1+FC2 (MFMA), BN0 inline, BN2 stats out -----------
__global__ __launch_bounds__(256) void k_fc12(
    const unsigned short* __restrict__ in,
    const float* __restrict__ gsumIn, const float* __restrict__ gsqIn,
    const float* __restrict__ gamma, const float* __restrict__ beta,
    const unsigned short* __restrict__ Wt1, const float* __restrict__ b1,
    const unsigned short* __restrict__ Wt2, const float* __restrict__ b2,
    unsigned short* __restrict__ outp,
    float* __restrict__ gsum, float* __restrict__ gsq)
{
  __shared__ short As[64 * 72];
  __shared__ short Bsh[128 * 72];
  __shared__ short H1[64 * 136];
  __shared__ float statS[128][2], statQ[128][2];
  __shared__ float sc[HDIM], shf[HDIM];

  const int t = threadIdx.x;
  const int lane = t & 63;
  const int wv = t >> 6;
  const int rh = wv >> 1;
  const int ch = wv & 1;
  const int quad = (lane >> 4) & 3;
  const int l15 = lane & 15;
  const int row0 = blockIdx.x * 64;

  if (t < HDIM) {
    float mean = gsumIn[t] / (float)N_NODES;
    float var = gsqIn[t] / (float)N_NODES - mean * mean;
    float s = gamma[t] * rsqrtf(var + BN_EPS);
    sc[t] = s; shf[t] = beta[t] - mean * s;
  }
  __syncthreads();

  float4v acc[2][4];
#pragma unroll
  for (int i = 0; i < 2; ++i)
#pragma unroll
    for (int j = 0; j < 4; ++j) acc[i][j] = (float4v){0.f, 0.f, 0.f, 0.f};

  for (int ks = 0; ks < 2; ++ks) {
    const int kk0 = ks * 64;
#pragma unroll
    for (int it = 0; it < 2; ++it) {
      int idx = it * 256 + t;
      int r = idx >> 3, c8 = idx & 7;
      int rr = row0 + r; if (rr >= N_NODES) rr = N_NODES - 1;
      ushort8v v = *(const ushort8v*)(in + (size_t)rr * HDIM + kk0 + c8 * 8);
#pragma unroll
      for (int j = 0; j < 8; ++j) {
        int k = kk0 + c8 * 8 + j;
        v[j] = f2bf(bf2f(v[j]) * sc[k] + shf[k]);
      }
      *(ushort8v*)(&As[r * 72 + c8 * 8]) = v;
    }
#pragma unroll
    for (int it = 0; it < 4; ++it) {
      int idx = it * 256 + t;
      int n = idx >> 3, c8 = idx & 7;
      *(ushort8v*)(&Bsh[n * 72 + c8 * 8]) = *(const ushort8v*)(Wt1 + (size_t)n * HDIM + kk0 + c8 * 8);
    }
    __syncthreads();
#pragma unroll
    for (int kc = 0; kc < 2; ++kc) {
      short8 af[2], bfr[4];
#pragma unroll
      for (int rt = 0; rt < 2; ++rt)
        af[rt] = *(const short8*)(&As[(rh * 32 + rt * 16 + l15) * 72 + kc * 32 + quad * 8]);
#pragma unroll
      for (int nt = 0; nt < 4; ++nt)
        bfr[nt] = *(const short8*)(&Bsh[(ch * 64 + nt * 16 + l15) * 72 + kc * 32 + quad * 8]);
#pragma unroll
      for (int rt = 0; rt < 2; ++rt)
#pragma unroll
        for (int nt = 0; nt < 4; ++nt)
          acc[rt][nt] = __builtin_amdgcn_mfma_f32_16x16x32_bf16(af[rt], bfr[nt], acc[rt][nt], 0, 0, 0);
    }
    __syncthreads();
  }

  {
    float bv[4];
#pragma unroll
    for (int nt = 0; nt < 4; ++nt) bv[nt] = b1[ch * 64 + nt * 16 + l15];
#pragma unroll
    for (int rt = 0; rt < 2; ++rt) {
#pragma unroll
      for (int reg = 0; reg < 4; ++reg) {
        int rloc = rh * 32 + rt * 16 + quad * 4 + reg;
#pragma unroll
        for (int nt = 0; nt < 4; ++nt) {
          float o = fmaxf(acc[rt][nt][reg] + bv[nt], 0.f);
          H1[rloc * 136 + ch * 64 + nt * 16 + l15] = f2bf(o);
        }
      }
    }
  }
  __syncthreads();

#pragma unroll
  for (int i = 0; i < 2; ++i)
#pragma unroll
    for (int j = 0; j < 4; ++j) acc[i][j] = (float4v){0.f, 0.f, 0.f, 0.f};

  for (int ks = 0; ks < 2; ++ks) {
    const int kk0 = ks * 64;
#pragma unroll
    for (int it = 0; it < 4; ++it) {
      int idx = it * 256 + t;
      int n = idx >> 3, c8 = idx & 7;
      *(ushort8v*)(&Bsh[n * 72 + c8 * 8]) = *(const ushort8v*)(Wt2 + (size_t)n * HDIM + kk0 + c8 * 8);
    }
    __syncthreads();
#pragma unroll
    for (int kc = 0; kc < 2; ++kc) {
      short8 af[2], bfr[4];
#pragma unroll
      for (int rt = 0; rt < 2; ++rt)
        af[rt] = *(const short8*)(&H1[(rh * 32 + rt * 16 + l15) * 136 + kk0 + kc * 32 + quad * 8]);
#pragma unroll
      for (int nt = 0; nt < 4; ++nt)
        bfr[nt] = *(const short8*)(&Bsh[(ch * 64 + nt * 16 + l15) * 72 + kc * 32 + quad * 8]);
#pragma unroll
      for (int rt = 0; rt < 2; ++rt)
#pragma unroll
        for (int nt = 0; nt < 4; ++nt)
          acc[rt][nt] = __builtin_amdgcn_mfma_f32_16x16x32_bf16(af[rt], bfr[nt], acc[rt][nt], 0, 0, 0);
    }
    __syncthreads();
  }

  float bv[4];
#pragma unroll
  for (int nt = 0; nt < 4; ++nt) bv[nt] = b2[ch * 64 + nt * 16 + l15];

  float pS[4] = {0.f, 0.f, 0.f, 0.f}, pQ[4] = {0.f, 0.f, 0.f, 0.f};
#pragma unroll
  for (int rt = 0; rt < 2; ++rt) {
#pragma unroll
    for (int reg = 0; reg < 4; ++reg) {
      int row = row0 + rh * 32 + rt * 16 + quad * 4 + reg;
      bool valid = (row < N_NODES);
#pragma unroll
      for (int nt = 0; nt < 4; ++nt) {
        float o = fmaxf(acc[rt][nt][reg] + bv[nt], 0.f);
        if (valid) {
          outp[(size_t)row * HDIM + ch * 64 + nt * 16 + l15] = f2bf(o);
          pS[nt] += o; pQ[nt] += o * o;
        }
      }
    }
  }
#pragma unroll
  for (int nt = 0; nt < 4; ++nt) {
    float s = pS[nt], q = pQ[nt];
    s += __shfl_xor(s, 16, 64); s += __shfl_xor(s, 32, 64);
    q += __shfl_xor(q, 16, 64); q += __shfl_xor(q, 32, 64);
    if (lane < 16) {
      statS[ch * 64 + nt * 16 + lane][rh] = s;
      statQ[ch * 64 + nt * 16 + lane][rh] = q;
    }
  }
  __syncthreads();
  if (t < 128) {
    atomicAdd(&gsum[t], statS[t][0] + statS[t][1]);
    atomicAdd(&gsq[t],  statQ[t][0] + statQ[t][1]);
  }
}

// ---------------- fc3 + softmax: BN-folded W3', register-blocked fp32 -------
// logits = h2 @ (s2*W3) + (b3 + sh2 @ W3); thread = 4 rows x 4 cols
__global__ __launch_bounds__(128) void k_fc3(
    const unsigned short* __restrict__ h2,
    const float* __restrict__ gsumIn, const float* __restrict__ gsqIn,
    const float* __restrict__ gamma, const float* __restrict__ beta,
    const float* __restrict__ W3, const float* __restrict__ b3,
    float* __restrict__ out)
{
  __shared__ float w3p[HDIM][A_DIM];      // s2-folded W3, 16 KB
  __shared__ float hs[HDIM][FC3_TR + 2];  // fp32 h tile, transposed [k][r], 33 KB
  __shared__ float s2s[HDIM], sh2s[HDIM];
  __shared__ float bred[4][A_DIM];
  __shared__ float b3p[A_DIM];
  const int t = threadIdx.x;

  {
    float mean = gsumIn[t] / (float)N_NODES;
    float var = gsqIn[t] / (float)N_NODES - mean * mean;
    float s = gamma[t] * rsqrtf(var + BN_EPS);
    s2s[t] = s; sh2s[t] = beta[t] - mean * s;
  }
  __syncthreads();

  for (int i = t; i < HDIM * A_DIM; i += 128) {
    int k = i >> 5;
    w3p[k][i & 31] = s2s[k] * W3[i];
  }
  {
    int j = t & 31, seg = t >> 5;   // 4 segs x 32 k
    float p = 0.f;
    for (int kk = 0; kk < 32; ++kk) {
      int k = seg * 32 + kk;
      p += sh2s[k] * W3[k * A_DIM + j];
    }
    bred[seg][j] = p;
  }
  // stage h tile: 64 rows x 128 k, bf16 -> fp32, transposed into hs[k][r]
  const int row0 = blockIdx.x * FC3_TR;
  for (int i = t; i < FC3_TR * (HDIM / 8); i += 128) {
    int r = i & 63, cg = i >> 6;     // consecutive lanes -> consecutive r
    int row = row0 + r;
    ushort8v v;
    if (row < N_NODES) v = *(const ushort8v*)(h2 + (size_t)row * HDIM + cg * 8);
    else { for (int jj = 0; jj < 8; ++jj) v[jj] = 0; }
#pragma unroll
    for (int jj = 0; jj < 8; ++jj) hs[cg * 8 + jj][r] = bf2f(v[jj]);
  }
  __syncthreads();
  if (t < 32) b3p[t] = b3[t] + bred[0][t] + bred[1][t] + bred[2][t] + bred[3][t];
  __syncthreads();

  const int r0 = (t >> 3) * 4;   // 16 row groups of 4
  const int j0 = (t & 7) * 4;    // 8 col groups of 4
  float4 acc[4];
#pragma unroll
  for (int r = 0; r < 4; ++r) acc[r] = (float4){0.f, 0.f, 0.f, 0.f};

  for (int k = 0; k < HDIM; k += 4) {
    float4 w0 = *(const float4*)&w3p[k + 0][j0];
    float4 w1 = *(const float4*)&w3p[k + 1][j0];
    float4 w2 = *(const float4*)&w3p[k + 2][j0];
    float4 w3v = *(const float4*)&w3p[k + 3][j0];
#pragma unroll
    for (int r = 0; r < 4; ++r) {
      int rr = r0 + r;
      float h0 = hs[k + 0][rr], h1 = hs[k + 1][rr];
      float h2v = hs[k + 2][rr], h3 = hs[k + 3][rr];
      acc[r].x += h0 * w0.x + h1 * w1.x + h2v * w2.x + h3 * w3v.x;
      acc[r].y += h0 * w0.y + h1 * w1.y + h2v * w2.y + h3 * w3v.y;
      acc[r].z += h0 * w0.z + h1 * w1.z + h2v * w2.z + h3 * w3v.z;
      acc[r].w += h0 * w0.w + h1 * w1.w + h2v * w2.w + h3 * w3v.w;
    }
  }

  float4 b4 = *(const float4*)&b3p[j0];
#pragma unroll
  for (int r = 0; r < 4; ++r) {
    float l0 = acc[r].x + b4.x, l1 = acc[r].y + b4.y;
    float l2 = acc[r].z + b4.z, l3 = acc[r].w + b4.w;
    float mx = fmaxf(fmaxf(l0, l1), fmaxf(l2, l3));
#pragma unroll
    for (int o = 1; o <= 4; o <<= 1) mx = fmaxf(mx, __shfl_xor(mx, o, 64));
    float e0 = __expf(l0 - mx), e1 = __expf(l1 - mx);
    float e2 = __expf(l2 - mx), e3 = __expf(l3 - mx);
    float sm = e0 + e1 + e2 + e3;
#pragma unroll
    for (int o = 1; o <= 4; o <<= 1) sm += __shfl_xor(sm, o, 64);
    float inv = 1.0f / sm;
    int row = row0 + r0 + r;
    if (row < N_NODES) {
      float4 o4; o4.x = e0 * inv; o4.y = e1 * inv; o4.z = e2 * inv; o4.w = e3 * inv;
      *(float4*)(out + (size_t)row * A_DIM + j0) = o4;
    }
  }
}

// ---------------------------------------------------------------------------
extern "C" void kernel_launch(void* const* d_in, const int* in_sizes, int n_in,
                              void* d_out, int out_size, void* d_ws, size_t ws_size,
                              hipStream_t stream) {
  const float* x     = (const float*)d_in[0];
  const int*   ei    = (const int*)d_in[1];
  const float* W     = (const float*)d_in[2];
  const float* a_src = (const float*)d_in[3];
  const float* a_dst = (const float*)d_in[4];
  const float* b_gat = (const float*)d_in[5];
  const float* g0    = (const float*)d_in[6];
  const float* beta0 = (const float*)d_in[7];
  const float* W1    = (const float*)d_in[8];
  const float* b1    = (const float*)d_in[9];
  const float* W2    = (const float*)d_in[10];
  const float* b2    = (const float*)d_in[11];
  const float* g2    = (const float*)d_in[12];
  const float* beta2 = (const float*)d_in[13];
  const float* W3    = (const float*)d_in[14];
  const float* b3    = (const float*)d_in[15];
  float* out = (float*)d_out;
  const int* srcI = ei;
  const int* dstI = ei + N_EDGES;

  char* p = (char*)d_ws;
  auto alloc = [&](size_t bytes) -> char* {
    char* q = p; p += (bytes + 255) & ~(size_t)255; return q;
  };
  unsigned short* h   = (unsigned short*)alloc(sizeof(short) * (size_t)N_NODES * HDIM);
  unsigned short* h0  = (unsigned short*)alloc(sizeof(short) * (size_t)N_NODES * HDIM);
  unsigned short* h2  = h;  // h dead after k_agg; reuse for fc12 output
  unsigned short* Wt0 = (unsigned short*)alloc(sizeof(short) * HDIM * D_INPUT);
  unsigned short* Wt1 = (unsigned short*)alloc(sizeof(short) * HDIM * HDIM);
  unsigned short* Wt2 = (unsigned short*)alloc(sizeof(short) * HDIM * HDIM);
  int2*  sedge  = (int2*)alloc(sizeof(int2) * (size_t)N_NODES * CAP);
  int*   bbuf   = (int*)alloc(sizeof(int) * (size_t)NB * BCAP);
  float* esrc   = (float*)alloc(sizeof(float) * N_NODES);
  float* edst   = (float*)alloc(sizeof(float) * N_NODES);
  int*   deg    = (int*)alloc(sizeof(int) * N_NODES);
  // zero-init region: gcur (line-padded) + stats -> one memset
  char*  zbase  = alloc(sizeof(int) * NB * GC_STRIDE + 256 + sizeof(float) * 4 * 128);
  int*   gcur   = (int*)zbase;
  float* stats  = (float*)(zbase + ((sizeof(int) * NB * GC_STRIDE + 255) & ~(size_t)255));
  float* gsum0 = stats;        float* gsq0  = stats + 128;
  float* gsum2 = stats + 256;  float* gsq2  = stats + 384;
  size_t zsize = (size_t)((char*)(stats + 512) - zbase);

  hipMemsetAsync(zbase, 0, zsize, stream);

  const int gT = (N_NODES + 63) / 64;          // 782 MFMA tiles
  const int gB = (N_EDGES + EPB - 1) / EPB;    // 196 bin blocks
  const int gP = (HDIM * D_INPUT + 255) / 256; // 128 prep blocks

  k_binprep<<<gB + gP, 256, 0, stream>>>(srcI, dstI, gcur, bbuf,
                                         W, W1, W2, Wt0, Wt1, Wt2);
  k_gemm_xw_mfma<<<gT, 256, 0, stream>>>(x, Wt0, a_src, a_dst, h, esrc, edst);
  k_sc2<<<NB, 256, 0, stream>>>(gcur, bbuf, esrc, edst, deg, sedge);
  k_agg<<<N_NODES / 4, 256, 0, stream>>>(deg, sedge, h, b_gat, h0);
  k_bnstats<<<(N_NODES + BN_ROWS - 1) / BN_ROWS, 256, 0, stream>>>(h0, gsum0, gsq0);
  k_fc12<<<gT, 256, 0, stream>>>(h0, gsum0, gsq0, g0, beta0, Wt1, b1, Wt2, b2, h2,
                                 gsum2, gsq2);
  k_fc3<<<(N_NODES + FC3_TR - 1) / FC3_TR, 128, 0, stream>>>(
      h2, gsum2, gsq2, g2, beta2, W3, b3, out);
}

// Round 9
// 265.033 us; speedup vs baseline: 1.3562x; 1.0034x over previous
//
#include <hip/hip_runtime.h>
#include <math.h>

#define N_NODES 50000
#define N_EDGES 800000
#define D_INPUT 256
#define HDIM 128
#define A_DIM 32
#define NEG_SLOPE 0.2f
#define BN_EPS 1e-5f
#define CAP 64        // max degree; Poisson(16): P(deg>=64) ~ 1e-21
#define NB 391        // dst bins of 128 nodes (391*128 = 50048)
#define BIN_SHIFT 7
#define BCAP 2432     // per-bin segment cap; lambda=2046, +8.5 sigma
#define GC_STRIDE 16  // pad bin counters to one per 64B line (R5 lesson)
#define EPB 4096      // edges per k_bin block
#define FC3_TR 64     // rows per k_fc3 block
#define SROW 132      // LDS row stride (shorts) for fc12: 66 dwords -> conflict-free

typedef short short8 __attribute__((ext_vector_type(8)));
typedef unsigned short ushort8v __attribute__((ext_vector_type(8)));
typedef unsigned short ushort4v __attribute__((ext_vector_type(4)));
typedef float float4v __attribute__((ext_vector_type(4)));

__device__ __forceinline__ unsigned short f2bf(float f) {
  unsigned u = __float_as_uint(f);
  u += 0x7FFFu + ((u >> 16) & 1u);
  return (unsigned short)(u >> 16);
}
__device__ __forceinline__ float bf2f(unsigned short b) {
  return __uint_as_float(((unsigned)b) << 16);
}

__device__ __forceinline__ float waveReduceMax(float v) {
#pragma unroll
  for (int o = 32; o >= 1; o >>= 1) v = fmaxf(v, __shfl_xor(v, o, 64));
  return v;
}
__device__ __forceinline__ float waveReduceSum(float v) {
#pragma unroll
  for (int o = 32; o >= 1; o >>= 1) v += __shfl_xor(v, o, 64);
  return v;
}

// ---------------- K1: h(bf16) = x @ W, plus esrc/edst (MFMA) ----------------
__global__ __launch_bounds__(256) void k_gemm_xw_mfma(
    const float* __restrict__ x, const unsigned short* __restrict__ Wt0,
    const float* __restrict__ a_src, const float* __restrict__ a_dst,
    unsigned short* __restrict__ hbf, float* __restrict__ esrc, float* __restrict__ edst)
{
  __shared__ short As[64][72];   // [m][k] bf16
  __shared__ short Bs[128][72];  // [n][k] bf16
  __shared__ float esred[64][2], edred[64][2];

  const int t = threadIdx.x;
  const int lane = t & 63;
  const int wv = t >> 6;
  const int rh = wv >> 1;
  const int ch = wv & 1;
  const int quad = (lane >> 4) & 3;
  const int l15 = lane & 15;
  const int row0 = blockIdx.x * 64;

  float4v acc[2][4];
#pragma unroll
  for (int i = 0; i < 2; ++i)
#pragma unroll
    for (int j = 0; j < 4; ++j) acc[i][j] = (float4v){0.f, 0.f, 0.f, 0.f};

  for (int ks = 0; ks < D_INPUT / 64; ++ks) {
    const int kk0 = ks * 64;
#pragma unroll
    for (int it = 0; it < 4; ++it) {
      int idx = it * 256 + t;
      int r = idx >> 4, c4 = idx & 15;
      int rr = row0 + r; if (rr >= N_NODES) rr = N_NODES - 1;
      float4 v = *(const float4*)(x + (size_t)rr * D_INPUT + kk0 + c4 * 4);
      ushort4v b; b.x = f2bf(v.x); b.y = f2bf(v.y); b.z = f2bf(v.z); b.w = f2bf(v.w);
      *(ushort4v*)(&As[r][c4 * 4]) = b;
    }
#pragma unroll
    for (int it = 0; it < 4; ++it) {
      int idx = it * 256 + t;
      int n = idx >> 3, c8 = idx & 7;
      *(ushort8v*)(&Bs[n][c8 * 8]) = *(const ushort8v*)(Wt0 + (size_t)n * D_INPUT + kk0 + c8 * 8);
    }
    __syncthreads();
#pragma unroll
    for (int kc = 0; kc < 2; ++kc) {
      short8 af[2], bfr[4];
#pragma unroll
      for (int rt = 0; rt < 2; ++rt)
        af[rt] = *(const short8*)(&As[rh * 32 + rt * 16 + l15][kc * 32 + quad * 8]);
#pragma unroll
      for (int nt = 0; nt < 4; ++nt)
        bfr[nt] = *(const short8*)(&Bs[ch * 64 + nt * 16 + l15][kc * 32 + quad * 8]);
#pragma unroll
      for (int rt = 0; rt < 2; ++rt)
#pragma unroll
        for (int nt = 0; nt < 4; ++nt)
          acc[rt][nt] = __builtin_amdgcn_mfma_f32_16x16x32_bf16(af[rt], bfr[nt], acc[rt][nt], 0, 0, 0);
    }
    __syncthreads();
  }

  float asv[4], adv[4];
#pragma unroll
  for (int nt = 0; nt < 4; ++nt) {
    int col = ch * 64 + nt * 16 + l15;
    asv[nt] = a_src[col]; adv[nt] = a_dst[col];
  }
#pragma unroll
  for (int rt = 0; rt < 2; ++rt) {
#pragma unroll
    for (int reg = 0; reg < 4; ++reg) {
      int rloc = rh * 32 + rt * 16 + quad * 4 + reg;
      int row = row0 + rloc;
      bool valid = (row < N_NODES);
      float ps = 0.f, pd = 0.f;
#pragma unroll
      for (int nt = 0; nt < 4; ++nt) {
        float v = acc[rt][nt][reg];
        ps += v * asv[nt]; pd += v * adv[nt];
        if (valid) hbf[(size_t)row * HDIM + ch * 64 + nt * 16 + l15] = f2bf(v);
      }
#pragma unroll
      for (int o = 8; o >= 1; o >>= 1) {
        ps += __shfl_xor(ps, o, 64);
        pd += __shfl_xor(pd, o, 64);
      }
      if (l15 == 0) { esred[rloc][ch] = ps; edred[rloc][ch] = pd; }
    }
  }
  __syncthreads();
  if (t < 64) {
    int row = row0 + t;
    if (row < N_NODES) {
      esrc[row] = esred[t][0] + esred[t][1];
      edst[row] = edred[t][0] + edred[t][1];
    }
  }
}

// ---------------- phase 1: bin edges (+ merged weight prep blocks) ----------
__global__ __launch_bounds__(256) void k_binprep(
    const int* __restrict__ srcI, const int* __restrict__ dstI,
    int* __restrict__ gcur, int* __restrict__ bbuf,
    const float* __restrict__ W, const float* __restrict__ W1,
    const float* __restrict__ W2, unsigned short* __restrict__ Wt0,
    unsigned short* __restrict__ Wt1, unsigned short* __restrict__ Wt2)
{
  const int gB = (N_EDGES + EPB - 1) / EPB;
  if (blockIdx.x >= gB) {           // ---- prep path ----
    int i = (blockIdx.x - gB) * 256 + threadIdx.x;
    if (i < HDIM * D_INPUT) {
      int n = i >> 8, k = i & 255;
      Wt0[i] = f2bf(W[(size_t)k * HDIM + n]);
    }
    if (i < HDIM * HDIM) {
      int n = i >> 7, k = i & 127;
      Wt1[i] = f2bf(W1[(size_t)k * HDIM + n]);
      Wt2[i] = f2bf(W2[(size_t)k * HDIM + n]);
    }
    return;
  }
  // ---- bin path ----
  __shared__ int hist[NB];
  __shared__ int base[NB];
  const int t = threadIdx.x;
  const int e0 = blockIdx.x * EPB;
  const int e1 = min(e0 + EPB, N_EDGES);
  for (int i = t; i < NB; i += 256) hist[i] = 0;
  __syncthreads();
  for (int e = e0 + t; e < e1; e += 256)
    atomicAdd(&hist[dstI[e] >> BIN_SHIFT], 1);
  __syncthreads();
  for (int i = t; i < NB; i += 256) {
    base[i] = atomicAdd(&gcur[i * GC_STRIDE], hist[i]);
    hist[i] = 0;
  }
  __syncthreads();
  for (int e = e0 + t; e < e1; e += 256) {
    int d = dstI[e];
    int bin = d >> BIN_SHIFT;
    int r = atomicAdd(&hist[bin], 1) + base[bin];
    if (r < BCAP) bbuf[(size_t)bin * BCAP + r] = srcI[e] | ((d & 127) << 16);
  }
}

// ---------------- phase 2: per-bin rank + bucket build in LDS ---------------
__global__ __launch_bounds__(256) void k_sc2(
    const int* __restrict__ gcur, const int* __restrict__ bbuf,
    const float* __restrict__ esrc, const float* __restrict__ edst,
    int* __restrict__ deg, int2* __restrict__ sedge)
{
  __shared__ int2 bk[128][CAP];   // 64 KB
  __shared__ int lcur[128];
  __shared__ float ledst[128];
  const int t = threadIdx.x;
  const int bin = blockIdx.x;
  const int d0 = bin << BIN_SHIFT;
  if (t < 128) {
    lcur[t] = 0;
    int d = d0 + t;
    ledst[t] = (d < N_NODES) ? edst[d] : 0.f;
  }
  __syncthreads();
  const int cnt = min(gcur[bin * GC_STRIDE], BCAP);
  const int* seg = bbuf + (size_t)bin * BCAP;
  for (int i = t; i < cnt; i += 256) {
    int v = seg[i];
    int s = v & 0xFFFF;
    int dl = (v >> 16) & 127;
    float ev = esrc[s] + ledst[dl];
    ev = (ev > 0.f) ? ev : NEG_SLOPE * ev;
    int r = atomicAdd(&lcur[dl], 1);
    if (r < CAP) {
      int2 e2; e2.x = s; e2.y = __float_as_int(ev);
      bk[dl][r] = e2;
    }
  }
  __syncthreads();
  for (int idx = t; idx < 128 * CAP; idx += 256) {
    int dl = idx >> 6, sl = idx & 63;
    if (sl < lcur[dl])
      sedge[(size_t)(d0 + dl) * CAP + sl] = bk[dl][sl];
  }
  if (t < 128) {
    int d = d0 + t;
    if (d < N_NODES) deg[d] = min(lcur[t], CAP);
  }
}

// ---------------- per-dst softmax + aggregation: 1 wave per node ------------
__global__ __launch_bounds__(256) void k_agg(
    const int* __restrict__ degA, const int2* __restrict__ sedge,
    const unsigned short* __restrict__ hbf,
    const float* __restrict__ b_gat, unsigned short* __restrict__ h0)
{
  const int t = threadIdx.x;
  const int lane = t & 63;
  const int node = blockIdx.x * 4 + (t >> 6);
  const int deg = min(degA[node], CAP);

  int2 ev; ev.x = 0; ev.y = 0;
  float val = -INFINITY;
  if (lane < deg) {
    ev = sedge[(size_t)node * CAP + lane];
    val = __int_as_float(ev.y);
  }
  const float m = waveReduceMax(val);
  const float ex = (lane < deg) ? __expf(val - m) : 0.f;
  const float s = waveReduceSum(ex);
  const float al = ex * (1.0f / fmaxf(s, 1e-16f));
  const int sr = ev.x;

  float ax = 0.f, ay = 0.f;
  int j = 0;
  for (; j + 4 <= deg; j += 4) {
    float a0 = __shfl(al, j, 64),   a1 = __shfl(al, j+1, 64);
    float a2 = __shfl(al, j+2, 64), a3 = __shfl(al, j+3, 64);
    int s0 = __shfl(sr, j, 64),   s1 = __shfl(sr, j+1, 64);
    int s2 = __shfl(sr, j+2, 64), s3 = __shfl(sr, j+3, 64);
    unsigned v0 = *(const unsigned*)(hbf + (size_t)s0 * HDIM + lane * 2);
    unsigned v1 = *(const unsigned*)(hbf + (size_t)s1 * HDIM + lane * 2);
    unsigned v2 = *(const unsigned*)(hbf + (size_t)s2 * HDIM + lane * 2);
    unsigned v3 = *(const unsigned*)(hbf + (size_t)s3 * HDIM + lane * 2);
    ax += a0 * bf2f((unsigned short)(v0 & 0xFFFFu))
        + a1 * bf2f((unsigned short)(v1 & 0xFFFFu))
        + a2 * bf2f((unsigned short)(v2 & 0xFFFFu))
        + a3 * bf2f((unsigned short)(v3 & 0xFFFFu));
    ay += a0 * bf2f((unsigned short)(v0 >> 16))
        + a1 * bf2f((unsigned short)(v1 >> 16))
        + a2 * bf2f((unsigned short)(v2 >> 16))
        + a3 * bf2f((unsigned short)(v3 >> 16));
  }
  for (; j < deg; ++j) {
    float a = __shfl(al, j, 64);
    int sj = __shfl(sr, j, 64);
    unsigned v = *(const unsigned*)(hbf + (size_t)sj * HDIM + lane * 2);
    ax += a * bf2f((unsigned short)(v & 0xFFFFu));
    ay += a * bf2f((unsigned short)(v >> 16));
  }
  float vx = fmaxf(ax + b_gat[lane * 2], 0.f);
  float vy = fmaxf(ay + b_gat[lane * 2 + 1], 0.f);
  *(unsigned*)(h0 + (size_t)node * HDIM + lane * 2) =
      (unsigned)f2bf(vx) | ((unsigned)f2bf(vy) << 16);
}

// ---------------- BN column stats, ushort8-vectorized -----------------------
#define BN_ROWS 256
__global__ __launch_bounds__(256) void k_bnstats(
    const unsigned short* __restrict__ src, float* __restrict__ gsum, float* __restrict__ gsq)
{
  __shared__ float red[16][128];
  const int t = threadIdx.x;
  const int cg = t & 15;
  const int rl = t >> 4;
  const int row0 = blockIdx.x * BN_ROWS;
  float s[8], q[8];
#pragma unroll
  for (int j = 0; j < 8; ++j) { s[j] = 0.f; q[j] = 0.f; }
  for (int i = 0; i < BN_ROWS / 16; ++i) {
    int row = row0 + rl + i * 16;
    if (row < N_NODES) {
      ushort8v v = *(const ushort8v*)(src + (size_t)row * HDIM + cg * 8);
#pragma unroll
      for (int j = 0; j < 8; ++j) {
        float f = bf2f(v[j]);
        s[j] += f; q[j] += f * f;
      }
    }
  }
#pragma unroll
  for (int j = 0; j < 8; ++j) red[rl][cg * 8 + j] = s[j];
  __syncthreads();
  if (t < 128) {
    float S = 0.f;
#pragma unroll
    for (int r = 0; r < 16; ++r) S += red[r][t];
    atomicAdd(&gsum[t], S);
  }
  __syncthreads();
#pragma unroll
  for (int j = 0; j < 8; ++j) red[rl][cg * 8 + j] = q[j];
  __syncthreads();
  if (t < 128) {
    float Q = 0.f;
#pragma unroll
    for (int r = 0; r < 16; ++r) Q += red[r][t];
    atomicAdd(&gsq[t], Q);
  }
}

// ---------------- fused FC1+FC2, full-K staging, 5 barriers -----------------
// stage A(BN)+W1 once -> 16 MFMA fc1 -> H1 overwrites As -> W2 -> 16 MFMA fc2
__global__ __launch_bounds__(256) void k_fc12(
    const unsigned short* __restrict__ in,
    const float* __restrict__ gsumIn, const float* __restrict__ gsqIn,
    const float* __restrict__ gamma, const float* __restrict__ beta,
    const unsigned short* __restrict__ Wt1, const float* __restrict__ b1,
    const unsigned short* __restrict__ Wt2, const float* __restrict__ b2,
    unsigned short* __restrict__ outp,
    float* __restrict__ gsum, float* __restrict__ gsq)
{
  __shared__ short As[64 * SROW];    // input tile, then H1 tile (K=128)
  __shared__ short Bsh[128 * SROW];  // W1, then W2 (full K)
  __shared__ float statS[128][2], statQ[128][2];
  __shared__ float sc[HDIM], shf[HDIM];

  const int t = threadIdx.x;
  const int lane = t & 63;
  const int wv = t >> 6;
  const int rh = wv >> 1;
  const int ch = wv & 1;
  const int quad = (lane >> 4) & 3;
  const int l15 = lane & 15;
  const int row0 = blockIdx.x * 64;

  if (t < HDIM) {
    float mean = gsumIn[t] / (float)N_NODES;
    float var = gsqIn[t] / (float)N_NODES - mean * mean;
    float s = gamma[t] * rsqrtf(var + BN_EPS);
    sc[t] = s; shf[t] = beta[t] - mean * s;
  }
  __syncthreads();                                   // B1

  // stage A (BN applied): 64 rows x 128 k
#pragma unroll
  for (int it = 0; it < 4; ++it) {
    int idx = it * 256 + t;
    int r = idx >> 4, c8 = idx & 15;
    int rr = row0 + r; if (rr >= N_NODES) rr = N_NODES - 1;
    ushort8v v = *(const ushort8v*)(in + (size_t)rr * HDIM + c8 * 8);
#pragma unroll
    for (int j = 0; j < 8; ++j) {
      int k = c8 * 8 + j;
      v[j] = f2bf(bf2f(v[j]) * sc[k] + shf[k]);
    }
    *(ushort8v*)(&As[r * SROW + c8 * 8]) = v;
  }
  // stage W1: 128 n x 128 k
#pragma unroll
  for (int it = 0; it < 8; ++it) {
    int idx = it * 256 + t;
    int n = idx >> 4, c8 = idx & 15;
    *(ushort8v*)(&Bsh[n * SROW + c8 * 8]) = *(const ushort8v*)(Wt1 + (size_t)n * HDIM + c8 * 8);
  }
  __syncthreads();                                   // B2

  float4v acc[2][4];
#pragma unroll
  for (int i = 0; i < 2; ++i)
#pragma unroll
    for (int j = 0; j < 4; ++j) acc[i][j] = (float4v){0.f, 0.f, 0.f, 0.f};

#pragma unroll
  for (int kc = 0; kc < 4; ++kc) {
    short8 af[2], bfr[4];
#pragma unroll
    for (int rt = 0; rt < 2; ++rt)
      af[rt] = *(const short8*)(&As[(rh * 32 + rt * 16 + l15) * SROW + kc * 32 + quad * 8]);
#pragma unroll
    for (int nt = 0; nt < 4; ++nt)
      bfr[nt] = *(const short8*)(&Bsh[(ch * 64 + nt * 16 + l15) * SROW + kc * 32 + quad * 8]);
#pragma unroll
    for (int rt = 0; rt < 2; ++rt)
#pragma unroll
      for (int nt = 0; nt < 4; ++nt)
        acc[rt][nt] = __builtin_amdgcn_mfma_f32_16x16x32_bf16(af[rt], bfr[nt], acc[rt][nt], 0, 0, 0);
  }
  __syncthreads();                                   // B3: all fc1 LDS reads done

  // H1 = relu(acc + b1) -> overwrite As; stage W2 -> Bsh
  {
    float bv[4];
#pragma unroll
    for (int nt = 0; nt < 4; ++nt) bv[nt] = b1[ch * 64 + nt * 16 + l15];
#pragma unroll
    for (int rt = 0; rt < 2; ++rt) {
#pragma unroll
      for (int reg = 0; reg < 4; ++reg) {
        int rloc = rh * 32 + rt * 16 + quad * 4 + reg;
#pragma unroll
        for (int nt = 0; nt < 4; ++nt) {
          float o = fmaxf(acc[rt][nt][reg] + bv[nt], 0.f);
          As[rloc * SROW + ch * 64 + nt * 16 + l15] = f2bf(o);
        }
      }
    }
  }
#pragma unroll
  for (int it = 0; it < 8; ++it) {
    int idx = it * 256 + t;
    int n = idx >> 4, c8 = idx & 15;
    *(ushort8v*)(&Bsh[n * SROW + c8 * 8]) = *(const ushort8v*)(Wt2 + (size_t)n * HDIM + c8 * 8);
  }
  __syncthreads();                                   // B4

#pragma unroll
  for (int i = 0; i < 2; ++i)
#pragma unroll
    for (int j = 0; j < 4; ++j) acc[i][j] = (float4v){0.f, 0.f, 0.f, 0.f};

#pragma unroll
  for (int kc = 0; kc < 4; ++kc) {
    short8 af[2], bfr[4];
#pragma unroll
    for (int rt = 0; rt < 2; ++rt)
      af[rt] = *(const short8*)(&As[(rh * 32 + rt * 16 + l15) * SROW + kc * 32 + quad * 8]);
#pragma unroll
    for (int nt = 0; nt < 4; ++nt)
      bfr[nt] = *(const short8*)(&Bsh[(ch * 64 + nt * 16 + l15) * SROW + kc * 32 + quad * 8]);
#pragma unroll
    for (int rt = 0; rt < 2; ++rt)
#pragma unroll
      for (int nt = 0; nt < 4; ++nt)
        acc[rt][nt] = __builtin_amdgcn_mfma_f32_16x16x32_bf16(af[rt], bfr[nt], acc[rt][nt], 0, 0, 0);
  }

  // epilogue: h2 = relu(acc + b2), store + BN2 stats
  float bv[4];
#pragma unroll
  for (int nt = 0; nt < 4; ++nt) bv[nt] = b2[ch * 64 + nt * 16 + l15];

  float pS[4] = {0.f, 0.f, 0.f, 0.f}, pQ[4] = {0.f, 0.f, 0.f, 0.f};
#pragma unroll
  for (int rt = 0; rt < 2; ++rt) {
#pragma unroll
    for (int reg = 0; reg < 4; ++reg) {
      int row = row0 + rh * 32 + rt * 16 + quad * 4 + reg;
      bool valid = (row < N_NODES);
#pragma unroll
      for (int nt = 0; nt < 4; ++nt) {
        float o = fmaxf(acc[rt][nt][reg] + bv[nt], 0.f);
        if (valid) {
          outp[(size_t)row * HDIM + ch * 64 + nt * 16 + l15] = f2bf(o);
          pS[nt] += o; pQ[nt] += o * o;
        }
      }
    }
  }
#pragma unroll
  for (int nt = 0; nt < 4; ++nt) {
    float s = pS[nt], q = pQ[nt];
    s += __shfl_xor(s, 16, 64); s += __shfl_xor(s, 32, 64);
    q += __shfl_xor(q, 16, 64); q += __shfl_xor(q, 32, 64);
    if (lane < 16) {
      statS[ch * 64 + nt * 16 + lane][rh] = s;
      statQ[ch * 64 + nt * 16 + lane][rh] = q;
    }
  }
  __syncthreads();                                   // B5
  if (t < 128) {
    atomicAdd(&gsum[t], statS[t][0] + statS[t][1]);
    atomicAdd(&gsq[t],  statQ[t][0] + statQ[t][1]);
  }
}

// ---------------- fc3 + softmax: BN-folded W3', register-blocked fp32 -------
__global__ __launch_bounds__(128) void k_fc3(
    const unsigned short* __restrict__ h2,
    const float* __restrict__ gsumIn, const float* __restrict__ gsqIn,
    const float* __restrict__ gamma, const float* __restrict__ beta,
    const float* __restrict__ W3, const float* __restrict__ b3,
    float* __restrict__ out)
{
  __shared__ float w3p[HDIM][A_DIM];      // s2-folded W3, 16 KB
  __shared__ float hs[HDIM][FC3_TR + 2];  // fp32 h tile, transposed [k][r]
  __shared__ float s2s[HDIM], sh2s[HDIM];
  __shared__ float bred[4][A_DIM];
  __shared__ float b3p[A_DIM];
  const int t = threadIdx.x;

  {
    float mean = gsumIn[t] / (float)N_NODES;
    float var = gsqIn[t] / (float)N_NODES - mean * mean;
    float s = gamma[t] * rsqrtf(var + BN_EPS);
    s2s[t] = s; sh2s[t] = beta[t] - mean * s;
  }
  __syncthreads();

  for (int i = t; i < HDIM * A_DIM; i += 128) {
    int k = i >> 5;
    w3p[k][i & 31] = s2s[k] * W3[i];
  }
  {
    int j = t & 31, seg = t >> 5;
    float p = 0.f;
    for (int kk = 0; kk < 32; ++kk) {
      int k = seg * 32 + kk;
      p += sh2s[k] * W3[k * A_DIM + j];
    }
    bred[seg][j] = p;
  }
  const int row0 = blockIdx.x * FC3_TR;
  for (int i = t; i < FC3_TR * (HDIM / 8); i += 128) {
    int r = i & 63, cg = i >> 6;
    int row = row0 + r;
    ushort8v v;
    if (row < N_NODES) v = *(const ushort8v*)(h2 + (size_t)row * HDIM + cg * 8);
    else { for (int jj = 0; jj < 8; ++jj) v[jj] = 0; }
#pragma unroll
    for (int jj = 0; jj < 8; ++jj) hs[cg * 8 + jj][r] = bf2f(v[jj]);
  }
  __syncthreads();
  if (t < 32) b3p[t] = b3[t] + bred[0][t] + bred[1][t] + bred[2][t] + bred[3][t];
  __syncthreads();

  const int r0 = (t >> 3) * 4;
  const int j0 = (t & 7) * 4;
  float4 acc[4];
#pragma unroll
  for (int r = 0; r < 4; ++r) acc[r] = (float4){0.f, 0.f, 0.f, 0.f};

  for (int k = 0; k < HDIM; k += 4) {
    float4 w0 = *(const float4*)&w3p[k + 0][j0];
    float4 w1 = *(const float4*)&w3p[k + 1][j0];
    float4 w2 = *(const float4*)&w3p[k + 2][j0];
    float4 w3v = *(const float4*)&w3p[k + 3][j0];
#pragma unroll
    for (int r = 0; r < 4; ++r) {
      int rr = r0 + r;
      float h0 = hs[k + 0][rr], h1 = hs[k + 1][rr];
      float h2v = hs[k + 2][rr], h3 = hs[k + 3][rr];
      acc[r].x += h0 * w0.x + h1 * w1.x + h2v * w2.x + h3 * w3v.x;
      acc[r].y += h0 * w0.y + h1 * w1.y + h2v * w2.y + h3 * w3v.y;
      acc[r].z += h0 * w0.z + h1 * w1.z + h2v * w2.z + h3 * w3v.z;
      acc[r].w += h0 * w0.w + h1 * w1.w + h2v * w2.w + h3 * w3v.w;
    }
  }

  float4 b4 = *(const float4*)&b3p[j0];
#pragma unroll
  for (int r = 0; r < 4; ++r) {
    float l0 = acc[r].x + b4.x, l1 = acc[r].y + b4.y;
    float l2 = acc[r].z + b4.z, l3 = acc[r].w + b4.w;
    float mx = fmaxf(fmaxf(l0, l1), fmaxf(l2, l3));
#pragma unroll
    for (int o = 1; o <= 4; o <<= 1) mx = fmaxf(mx, __shfl_xor(mx, o, 64));
    float e0 = __expf(l0 - mx), e1 = __expf(l1 - mx);
    float e2 = __expf(l2 - mx), e3 = __expf(l3 - mx);
    float sm = e0 + e1 + e2 + e3;
#pragma unroll
    for (int o = 1; o <= 4; o <<= 1) sm += __shfl_xor(sm, o, 64);
    float inv = 1.0f / sm;
    int row = row0 + r0 + r;
    if (row < N_NODES) {
      float4 o4; o4.x = e0 * inv; o4.y = e1 * inv; o4.z = e2 * inv; o4.w = e3 * inv;
      *(float4*)(out + (size_t)row * A_DIM + j0) = o4;
    }
  }
}

// ---------------------------------------------------------------------------
extern "C" void kernel_launch(void* const* d_in, const int* in_sizes, int n_in,
                              void* d_out, int out_size, void* d_ws, size_t ws_size,
                              hipStream_t stream) {
  const float* x     = (const float*)d_in[0];
  const int*   ei    = (const int*)d_in[1];
  const float* W     = (const float*)d_in[2];
  const float* a_src = (const float*)d_in[3];
  const float* a_dst = (const float*)d_in[4];
  const float* b_gat = (const float*)d_in[5];
  const float* g0    = (const float*)d_in[6];
  const float* beta0 = (const float*)d_in[7];
  const float* W1    = (const float*)d_in[8];
  const float* b1    = (const float*)d_in[9];
  const float* W2    = (const float*)d_in[10];
  const float* b2    = (const float*)d_in[11];
  const float* g2    = (const float*)d_in[12];
  const float* beta2 = (const float*)d_in[13];
  const float* W3    = (const float*)d_in[14];
  const float* b3    = (const float*)d_in[15];
  float* out = (float*)d_out;
  const int* srcI = ei;
  const int* dstI = ei + N_EDGES;

  char* p = (char*)d_ws;
  auto alloc = [&](size_t bytes) -> char* {
    char* q = p; p += (bytes + 255) & ~(size_t)255; return q;
  };
  unsigned short* h   = (unsigned short*)alloc(sizeof(short) * (size_t)N_NODES * HDIM);
  unsigned short* h0  = (unsigned short*)alloc(sizeof(short) * (size_t)N_NODES * HDIM);
  unsigned short* h2  = h;  // h dead after k_agg; reuse for fc12 output
  unsigned short* Wt0 = (unsigned short*)alloc(sizeof(short) * HDIM * D_INPUT);
  unsigned short* Wt1 = (unsigned short*)alloc(sizeof(short) * HDIM * HDIM);
  unsigned short* Wt2 = (unsigned short*)alloc(sizeof(short) * HDIM * HDIM);
  int2*  sedge  = (int2*)alloc(sizeof(int2) * (size_t)N_NODES * CAP);
  int*   bbuf   = (int*)alloc(sizeof(int) * (size_t)NB * BCAP);
  float* esrc   = (float*)alloc(sizeof(float) * N_NODES);
  float* edst   = (float*)alloc(sizeof(float) * N_NODES);
  int*   deg    = (int*)alloc(sizeof(int) * N_NODES);
  // zero-init region: gcur (line-padded) + stats -> one memset
  char*  zbase  = alloc(sizeof(int) * NB * GC_STRIDE + 256 + sizeof(float) * 4 * 128);
  int*   gcur   = (int*)zbase;
  float* stats  = (float*)(zbase + ((sizeof(int) * NB * GC_STRIDE + 255) & ~(size_t)255));
  float* gsum0 = stats;        float* gsq0  = stats + 128;
  float* gsum2 = stats + 256;  float* gsq2  = stats + 384;
  size_t zsize = (size_t)((char*)(stats + 512) - zbase);

  hipMemsetAsync(zbase, 0, zsize, stream);

  const int gT = (N_NODES + 63) / 64;          // 782 MFMA tiles
  const int gB = (N_EDGES + EPB - 1) / EPB;    // 196 bin blocks
  const int gP = (HDIM * D_INPUT + 255) / 256; // 128 prep blocks

  k_binprep<<<gB + gP, 256, 0, stream>>>(srcI, dstI, gcur, bbuf,
                                         W, W1, W2, Wt0, Wt1, Wt2);
  k_gemm_xw_mfma<<<gT, 256, 0, stream>>>(x, Wt0, a_src, a_dst, h, esrc, edst);
  k_sc2<<<NB, 256, 0, stream>>>(gcur, bbuf, esrc, edst, deg, sedge);
  k_agg<<<N_NODES / 4, 256, 0, stream>>>(deg, sedge, h, b_gat, h0);
  k_bnstats<<<(N_NODES + BN_ROWS - 1) / BN_ROWS, 256, 0, stream>>>(h0, gsum0, gsq0);
  k_fc12<<<gT, 256, 0, stream>>>(h0, gsum0, gsq0, g0, beta0, Wt1, b1, Wt2, b2, h2,
                                 gsum2, gsq2);
  k_fc3<<<(N_NODES + FC3_TR - 1) / FC3_TR, 128, 0, stream>>>(
      h2, gsum2, gsq2, g2, beta2, W3, b3, out);
}

// Round 10
// 248.420 us; speedup vs baseline: 1.4469x; 1.0669x over previous
//
#include <hip/hip_runtime.h>
#include <math.h>

#define N_NODES 50000
#define N_EDGES 800000
#define D_INPUT 256
#define HDIM 128
#define A_DIM 32
#define NEG_SLOPE 0.2f
#define BN_EPS 1e-5f
#define CAP 64        // max degree; Poisson(16): P(deg>=64) ~ 1e-21
#define NB 391        // dst bins of 128 nodes (391*128 = 50048)
#define BIN_SHIFT 7
#define BCAP 2432     // per-bin segment cap; lambda=2046, +8.5 sigma
#define GC_STRIDE 16  // pad bin counters to one per 64B line (R5 lesson)
#define EPB 4096      // edges per bin block
#define FC3_TR 64     // rows per k_fc3 block
#define SROW 132      // LDS row stride (shorts) for fc12: 66 dwords -> conflict-free

typedef short short8 __attribute__((ext_vector_type(8)));
typedef unsigned short ushort8v __attribute__((ext_vector_type(8)));
typedef unsigned short ushort4v __attribute__((ext_vector_type(4)));
typedef float float4v __attribute__((ext_vector_type(4)));

__device__ __forceinline__ unsigned short f2bf(float f) {
  unsigned u = __float_as_uint(f);
  u += 0x7FFFu + ((u >> 16) & 1u);
  return (unsigned short)(u >> 16);
}
__device__ __forceinline__ float bf2f(unsigned short b) {
  return __uint_as_float(((unsigned)b) << 16);
}

__device__ __forceinline__ float waveReduceMax(float v) {
#pragma unroll
  for (int o = 32; o >= 1; o >>= 1) v = fmaxf(v, __shfl_xor(v, o, 64));
  return v;
}
__device__ __forceinline__ float waveReduceSum(float v) {
#pragma unroll
  for (int o = 32; o >= 1; o >>= 1) v += __shfl_xor(v, o, 64);
  return v;
}

// ---------------- prep: W->Wt (bf16 [n][k]) + zero gcur/stats ---------------
__global__ __launch_bounds__(256) void k_prep(
    const float* __restrict__ W, const float* __restrict__ W1,
    const float* __restrict__ W2, unsigned short* __restrict__ Wt0,
    unsigned short* __restrict__ Wt1, unsigned short* __restrict__ Wt2,
    int* __restrict__ gcur, float* __restrict__ stats)
{
  int i = blockIdx.x * 256 + threadIdx.x;
  if (i < HDIM * D_INPUT) {                 // Wt0[n][k], 128 x 256
    int n = i >> 8, k = i & 255;
    Wt0[i] = f2bf(W[(size_t)k * HDIM + n]);
  }
  if (i < HDIM * HDIM) {                    // Wt1/Wt2[n][k], 128 x 128
    int n = i >> 7, k = i & 127;
    Wt1[i] = f2bf(W1[(size_t)k * HDIM + n]);
    Wt2[i] = f2bf(W2[(size_t)k * HDIM + n]);
  }
  if (i < NB * GC_STRIDE) gcur[i] = 0;      // replaces hipMemsetAsync
  if (i < 512) stats[i] = 0.f;
}

// ---------------- merged: MFMA gemm blocks + edge-bin blocks ----------------
// blocks [0, gT): h = x@W + esrc/edst.  blocks [gT, gT+gB): dst-bin edges.
// bin waves are latency-bound (atomics), gemm waves MFMA-bound -> co-schedule.
__global__ __launch_bounds__(256) void k_gemmbin(
    const float* __restrict__ x, const unsigned short* __restrict__ Wt0,
    const float* __restrict__ a_src, const float* __restrict__ a_dst,
    unsigned short* __restrict__ hbf, float* __restrict__ esrc, float* __restrict__ edst,
    const int* __restrict__ srcI, const int* __restrict__ dstI,
    int* __restrict__ gcur, int* __restrict__ bbuf)
{
  const int gT = (N_NODES + 63) / 64;
  __shared__ short As[64][72];
  __shared__ short Bs[128][72];
  __shared__ float esred[64][2], edred[64][2];
  __shared__ int hist[NB];
  __shared__ int base[NB];

  const int t = threadIdx.x;

  if (blockIdx.x >= gT) {
    // ---- bin path ----
    const int e0 = (blockIdx.x - gT) * EPB;
    const int e1 = min(e0 + EPB, N_EDGES);
    for (int i = t; i < NB; i += 256) hist[i] = 0;
    __syncthreads();
    for (int e = e0 + t; e < e1; e += 256)
      atomicAdd(&hist[dstI[e] >> BIN_SHIFT], 1);
    __syncthreads();
    for (int i = t; i < NB; i += 256) {
      base[i] = atomicAdd(&gcur[i * GC_STRIDE], hist[i]);
      hist[i] = 0;
    }
    __syncthreads();
    for (int e = e0 + t; e < e1; e += 256) {
      int d = dstI[e];
      int bin = d >> BIN_SHIFT;
      int r = atomicAdd(&hist[bin], 1) + base[bin];
      if (r < BCAP) bbuf[(size_t)bin * BCAP + r] = srcI[e] | ((d & 127) << 16);
    }
    return;
  }

  // ---- gemm path ----
  const int lane = t & 63;
  const int wv = t >> 6;
  const int rh = wv >> 1;
  const int ch = wv & 1;
  const int quad = (lane >> 4) & 3;
  const int l15 = lane & 15;
  const int row0 = blockIdx.x * 64;

  float4v acc[2][4];
#pragma unroll
  for (int i = 0; i < 2; ++i)
#pragma unroll
    for (int j = 0; j < 4; ++j) acc[i][j] = (float4v){0.f, 0.f, 0.f, 0.f};

  for (int ks = 0; ks < D_INPUT / 64; ++ks) {
    const int kk0 = ks * 64;
#pragma unroll
    for (int it = 0; it < 4; ++it) {
      int idx = it * 256 + t;
      int r = idx >> 4, c4 = idx & 15;
      int rr = row0 + r; if (rr >= N_NODES) rr = N_NODES - 1;
      float4 v = *(const float4*)(x + (size_t)rr * D_INPUT + kk0 + c4 * 4);
      ushort4v b; b.x = f2bf(v.x); b.y = f2bf(v.y); b.z = f2bf(v.z); b.w = f2bf(v.w);
      *(ushort4v*)(&As[r][c4 * 4]) = b;
    }
#pragma unroll
    for (int it = 0; it < 4; ++it) {
      int idx = it * 256 + t;
      int n = idx >> 3, c8 = idx & 7;
      *(ushort8v*)(&Bs[n][c8 * 8]) = *(const ushort8v*)(Wt0 + (size_t)n * D_INPUT + kk0 + c8 * 8);
    }
    __syncthreads();
#pragma unroll
    for (int kc = 0; kc < 2; ++kc) {
      short8 af[2], bfr[4];
#pragma unroll
      for (int rt = 0; rt < 2; ++rt)
        af[rt] = *(const short8*)(&As[rh * 32 + rt * 16 + l15][kc * 32 + quad * 8]);
#pragma unroll
      for (int nt = 0; nt < 4; ++nt)
        bfr[nt] = *(const short8*)(&Bs[ch * 64 + nt * 16 + l15][kc * 32 + quad * 8]);
#pragma unroll
      for (int rt = 0; rt < 2; ++rt)
#pragma unroll
        for (int nt = 0; nt < 4; ++nt)
          acc[rt][nt] = __builtin_amdgcn_mfma_f32_16x16x32_bf16(af[rt], bfr[nt], acc[rt][nt], 0, 0, 0);
    }
    __syncthreads();
  }

  float asv[4], adv[4];
#pragma unroll
  for (int nt = 0; nt < 4; ++nt) {
    int col = ch * 64 + nt * 16 + l15;
    asv[nt] = a_src[col]; adv[nt] = a_dst[col];
  }
#pragma unroll
  for (int rt = 0; rt < 2; ++rt) {
#pragma unroll
    for (int reg = 0; reg < 4; ++reg) {
      int rloc = rh * 32 + rt * 16 + quad * 4 + reg;
      int row = row0 + rloc;
      bool valid = (row < N_NODES);
      float ps = 0.f, pd = 0.f;
#pragma unroll
      for (int nt = 0; nt < 4; ++nt) {
        float v = acc[rt][nt][reg];
        ps += v * asv[nt]; pd += v * adv[nt];
        if (valid) hbf[(size_t)row * HDIM + ch * 64 + nt * 16 + l15] = f2bf(v);
      }
#pragma unroll
      for (int o = 8; o >= 1; o >>= 1) {
        ps += __shfl_xor(ps, o, 64);
        pd += __shfl_xor(pd, o, 64);
      }
      if (l15 == 0) { esred[rloc][ch] = ps; edred[rloc][ch] = pd; }
    }
  }
  __syncthreads();
  if (t < 64) {
    int row = row0 + t;
    if (row < N_NODES) {
      esrc[row] = esred[t][0] + esred[t][1];
      edst[row] = edred[t][0] + edred[t][1];
    }
  }
}

// ---------------- phase 2: per-bin rank + bucket build in LDS ---------------
__global__ __launch_bounds__(256) void k_sc2(
    const int* __restrict__ gcur, const int* __restrict__ bbuf,
    const float* __restrict__ esrc, const float* __restrict__ edst,
    int* __restrict__ deg, int2* __restrict__ sedge)
{
  __shared__ int2 bk[128][CAP];   // 64 KB
  __shared__ int lcur[128];
  __shared__ float ledst[128];
  const int t = threadIdx.x;
  const int bin = blockIdx.x;
  const int d0 = bin << BIN_SHIFT;
  if (t < 128) {
    lcur[t] = 0;
    int d = d0 + t;
    ledst[t] = (d < N_NODES) ? edst[d] : 0.f;
  }
  __syncthreads();
  const int cnt = min(gcur[bin * GC_STRIDE], BCAP);
  const int* seg = bbuf + (size_t)bin * BCAP;
  for (int i = t; i < cnt; i += 256) {
    int v = seg[i];
    int s = v & 0xFFFF;
    int dl = (v >> 16) & 127;
    float ev = esrc[s] + ledst[dl];
    ev = (ev > 0.f) ? ev : NEG_SLOPE * ev;
    int r = atomicAdd(&lcur[dl], 1);
    if (r < CAP) {
      int2 e2; e2.x = s; e2.y = __float_as_int(ev);
      bk[dl][r] = e2;
    }
  }
  __syncthreads();
  for (int idx = t; idx < 128 * CAP; idx += 256) {
    int dl = idx >> 6, sl = idx & 63;
    if (sl < lcur[dl])
      sedge[(size_t)(d0 + dl) * CAP + sl] = bk[dl][sl];
  }
  if (t < 128) {
    int d = d0 + t;
    if (d < N_NODES) deg[d] = min(lcur[t], CAP);
  }
}

// ---------------- per-dst softmax + aggregation: 1 wave per node ------------
__global__ __launch_bounds__(256) void k_agg(
    const int* __restrict__ degA, const int2* __restrict__ sedge,
    const unsigned short* __restrict__ hbf,
    const float* __restrict__ b_gat, unsigned short* __restrict__ h0)
{
  const int t = threadIdx.x;
  const int lane = t & 63;
  const int node = blockIdx.x * 4 + (t >> 6);
  const int deg = min(degA[node], CAP);

  int2 ev; ev.x = 0; ev.y = 0;
  float val = -INFINITY;
  if (lane < deg) {
    ev = sedge[(size_t)node * CAP + lane];
    val = __int_as_float(ev.y);
  }
  const float m = waveReduceMax(val);
  const float ex = (lane < deg) ? __expf(val - m) : 0.f;
  const float s = waveReduceSum(ex);
  const float al = ex * (1.0f / fmaxf(s, 1e-16f));
  const int sr = ev.x;

  float ax = 0.f, ay = 0.f;
  int j = 0;
  for (; j + 4 <= deg; j += 4) {
    float a0 = __shfl(al, j, 64),   a1 = __shfl(al, j+1, 64);
    float a2 = __shfl(al, j+2, 64), a3 = __shfl(al, j+3, 64);
    int s0 = __shfl(sr, j, 64),   s1 = __shfl(sr, j+1, 64);
    int s2 = __shfl(sr, j+2, 64), s3 = __shfl(sr, j+3, 64);
    unsigned v0 = *(const unsigned*)(hbf + (size_t)s0 * HDIM + lane * 2);
    unsigned v1 = *(const unsigned*)(hbf + (size_t)s1 * HDIM + lane * 2);
    unsigned v2 = *(const unsigned*)(hbf + (size_t)s2 * HDIM + lane * 2);
    unsigned v3 = *(const unsigned*)(hbf + (size_t)s3 * HDIM + lane * 2);
    ax += a0 * bf2f((unsigned short)(v0 & 0xFFFFu))
        + a1 * bf2f((unsigned short)(v1 & 0xFFFFu))
        + a2 * bf2f((unsigned short)(v2 & 0xFFFFu))
        + a3 * bf2f((unsigned short)(v3 & 0xFFFFu));
    ay += a0 * bf2f((unsigned short)(v0 >> 16))
        + a1 * bf2f((unsigned short)(v1 >> 16))
        + a2 * bf2f((unsigned short)(v2 >> 16))
        + a3 * bf2f((unsigned short)(v3 >> 16));
  }
  for (; j < deg; ++j) {
    float a = __shfl(al, j, 64);
    int sj = __shfl(sr, j, 64);
    unsigned v = *(const unsigned*)(hbf + (size_t)sj * HDIM + lane * 2);
    ax += a * bf2f((unsigned short)(v & 0xFFFFu));
    ay += a * bf2f((unsigned short)(v >> 16));
  }
  float vx = fmaxf(ax + b_gat[lane * 2], 0.f);
  float vy = fmaxf(ay + b_gat[lane * 2 + 1], 0.f);
  *(unsigned*)(h0 + (size_t)node * HDIM + lane * 2) =
      (unsigned)f2bf(vx) | ((unsigned)f2bf(vy) << 16);
}

// ---------------- BN column stats, ushort8-vectorized -----------------------
#define BN_ROWS 256
__global__ __launch_bounds__(256) void k_bnstats(
    const unsigned short* __restrict__ src, float* __restrict__ gsum, float* __restrict__ gsq)
{
  __shared__ float red[16][128];
  const int t = threadIdx.x;
  const int cg = t & 15;
  const int rl = t >> 4;
  const int row0 = blockIdx.x * BN_ROWS;
  float s[8], q[8];
#pragma unroll
  for (int j = 0; j < 8; ++j) { s[j] = 0.f; q[j] = 0.f; }
  for (int i = 0; i < BN_ROWS / 16; ++i) {
    int row = row0 + rl + i * 16;
    if (row < N_NODES) {
      ushort8v v = *(const ushort8v*)(src + (size_t)row * HDIM + cg * 8);
#pragma unroll
      for (int j = 0; j < 8; ++j) {
        float f = bf2f(v[j]);
        s[j] += f; q[j] += f * f;
      }
    }
  }
#pragma unroll
  for (int j = 0; j < 8; ++j) red[rl][cg * 8 + j] = s[j];
  __syncthreads();
  if (t < 128) {
    float S = 0.f;
#pragma unroll
    for (int r = 0; r < 16; ++r) S += red[r][t];
    atomicAdd(&gsum[t], S);
  }
  __syncthreads();
#pragma unroll
  for (int j = 0; j < 8; ++j) red[rl][cg * 8 + j] = q[j];
  __syncthreads();
  if (t < 128) {
    float Q = 0.f;
#pragma unroll
    for (int r = 0; r < 16; ++r) Q += red[r][t];
    atomicAdd(&gsq[t], Q);
  }
}

// ---------------- fused FC1+FC2, full-K staging, 5 barriers -----------------
__global__ __launch_bounds__(256) void k_fc12(
    const unsigned short* __restrict__ in,
    const float* __restrict__ gsumIn, const float* __restrict__ gsqIn,
    const float* __restrict__ gamma, const float* __restrict__ beta,
    const unsigned short* __restrict__ Wt1, const float* __restrict__ b1,
    const unsigned short* __restrict__ Wt2, const float* __restrict__ b2,
    unsigned short* __restrict__ outp,
    float* __restrict__ gsum, float* __restrict__ gsq)
{
  __shared__ short As[64 * SROW];    // input tile, then H1 tile (K=128)
  __shared__ short Bsh[128 * SROW];  // W1, then W2 (full K)
  __shared__ float statS[128][2], statQ[128][2];
  __shared__ float sc[HDIM], shf[HDIM];

  const int t = threadIdx.x;
  const int lane = t & 63;
  const int wv = t >> 6;
  const int rh = wv >> 1;
  const int ch = wv & 1;
  const int quad = (lane >> 4) & 3;
  const int l15 = lane & 15;
  const int row0 = blockIdx.x * 64;

  if (t < HDIM) {
    float mean = gsumIn[t] / (float)N_NODES;
    float var = gsqIn[t] / (float)N_NODES - mean * mean;
    float s = gamma[t] * rsqrtf(var + BN_EPS);
    sc[t] = s; shf[t] = beta[t] - mean * s;
  }
  __syncthreads();                                   // B1

#pragma unroll
  for (int it = 0; it < 4; ++it) {
    int idx = it * 256 + t;
    int r = idx >> 4, c8 = idx & 15;
    int rr = row0 + r; if (rr >= N_NODES) rr = N_NODES - 1;
    ushort8v v = *(const ushort8v*)(in + (size_t)rr * HDIM + c8 * 8);
#pragma unroll
    for (int j = 0; j < 8; ++j) {
      int k = c8 * 8 + j;
      v[j] = f2bf(bf2f(v[j]) * sc[k] + shf[k]);
    }
    *(ushort8v*)(&As[r * SROW + c8 * 8]) = v;
  }
#pragma unroll
  for (int it = 0; it < 8; ++it) {
    int idx = it * 256 + t;
    int n = idx >> 4, c8 = idx & 15;
    *(ushort8v*)(&Bsh[n * SROW + c8 * 8]) = *(const ushort8v*)(Wt1 + (size_t)n * HDIM + c8 * 8);
  }
  __syncthreads();                                   // B2

  float4v acc[2][4];
#pragma unroll
  for (int i = 0; i < 2; ++i)
#pragma unroll
    for (int j = 0; j < 4; ++j) acc[i][j] = (float4v){0.f, 0.f, 0.f, 0.f};

#pragma unroll
  for (int kc = 0; kc < 4; ++kc) {
    short8 af[2], bfr[4];
#pragma unroll
    for (int rt = 0; rt < 2; ++rt)
      af[rt] = *(const short8*)(&As[(rh * 32 + rt * 16 + l15) * SROW + kc * 32 + quad * 8]);
#pragma unroll
    for (int nt = 0; nt < 4; ++nt)
      bfr[nt] = *(const short8*)(&Bsh[(ch * 64 + nt * 16 + l15) * SROW + kc * 32 + quad * 8]);
#pragma unroll
    for (int rt = 0; rt < 2; ++rt)
#pragma unroll
      for (int nt = 0; nt < 4; ++nt)
        acc[rt][nt] = __builtin_amdgcn_mfma_f32_16x16x32_bf16(af[rt], bfr[nt], acc[rt][nt], 0, 0, 0);
  }
  __syncthreads();                                   // B3

  {
    float bv[4];
#pragma unroll
    for (int nt = 0; nt < 4; ++nt) bv[nt] = b1[ch * 64 + nt * 16 + l15];
#pragma unroll
    for (int rt = 0; rt < 2; ++rt) {
#pragma unroll
      for (int reg = 0; reg < 4; ++reg) {
        int rloc = rh * 32 + rt * 16 + quad * 4 + reg;
#pragma unroll
        for (int nt = 0; nt < 4; ++nt) {
          float o = fmaxf(acc[rt][nt][reg] + bv[nt], 0.f);
          As[rloc * SROW + ch * 64 + nt * 16 + l15] = f2bf(o);
        }
      }
    }
  }
#pragma unroll
  for (int it = 0; it < 8; ++it) {
    int idx = it * 256 + t;
    int n = idx >> 4, c8 = idx & 15;
    *(ushort8v*)(&Bsh[n * SROW + c8 * 8]) = *(const ushort8v*)(Wt2 + (size_t)n * HDIM + c8 * 8);
  }
  __syncthreads();                                   // B4

#pragma unroll
  for (int i = 0; i < 2; ++i)
#pragma unroll
    for (int j = 0; j < 4; ++j) acc[i][j] = (float4v){0.f, 0.f, 0.f, 0.f};

#pragma unroll
  for (int kc = 0; kc < 4; ++kc) {
    short8 af[2], bfr[4];
#pragma unroll
    for (int rt = 0; rt < 2; ++rt)
      af[rt] = *(const short8*)(&As[(rh * 32 + rt * 16 + l15) * SROW + kc * 32 + quad * 8]);
#pragma unroll
    for (int nt = 0; nt < 4; ++nt)
      bfr[nt] = *(const short8*)(&Bsh[(ch * 64 + nt * 16 + l15) * SROW + kc * 32 + quad * 8]);
#pragma unroll
    for (int rt = 0; rt < 2; ++rt)
#pragma unroll
      for (int nt = 0; nt < 4; ++nt)
        acc[rt][nt] = __builtin_amdgcn_mfma_f32_16x16x32_bf16(af[rt], bfr[nt], acc[rt][nt], 0, 0, 0);
  }

  float bv[4];
#pragma unroll
  for (int nt = 0; nt < 4; ++nt) bv[nt] = b2[ch * 64 + nt * 16 + l15];

  float pS[4] = {0.f, 0.f, 0.f, 0.f}, pQ[4] = {0.f, 0.f, 0.f, 0.f};
#pragma unroll
  for (int rt = 0; rt < 2; ++rt) {
#pragma unroll
    for (int reg = 0; reg < 4; ++reg) {
      int row = row0 + rh * 32 + rt * 16 + quad * 4 + reg;
      bool valid = (row < N_NODES);
#pragma unroll
      for (int nt = 0; nt < 4; ++nt) {
        float o = fmaxf(acc[rt][nt][reg] + bv[nt], 0.f);
        if (valid) {
          outp[(size_t)row * HDIM + ch * 64 + nt * 16 + l15] = f2bf(o);
          pS[nt] += o; pQ[nt] += o * o;
        }
      }
    }
  }
#pragma unroll
  for (int nt = 0; nt < 4; ++nt) {
    float s = pS[nt], q = pQ[nt];
    s += __shfl_xor(s, 16, 64); s += __shfl_xor(s, 32, 64);
    q += __shfl_xor(q, 16, 64); q += __shfl_xor(q, 32, 64);
    if (lane < 16) {
      statS[ch * 64 + nt * 16 + lane][rh] = s;
      statQ[ch * 64 + nt * 16 + lane][rh] = q;
    }
  }
  __syncthreads();                                   // B5
  if (t < 128) {
    atomicAdd(&gsum[t], statS[t][0] + statS[t][1]);
    atomicAdd(&gsq[t],  statQ[t][0] + statQ[t][1]);
  }
}

// ---------------- fc3 + softmax: BN-folded W3', register-blocked fp32 -------
__global__ __launch_bounds__(128) void k_fc3(
    const unsigned short* __restrict__ h2,
    const float* __restrict__ gsumIn, const float* __restrict__ gsqIn,
    const float* __restrict__ gamma, const float* __restrict__ beta,
    const float* __restrict__ W3, const float* __restrict__ b3,
    float* __restrict__ out)
{
  __shared__ float w3p[HDIM][A_DIM];      // s2-folded W3
  __shared__ float hs[HDIM][FC3_TR + 2];  // fp32 h tile, transposed [k][r]
  __shared__ float s2s[HDIM], sh2s[HDIM];
  __shared__ float bred[4][A_DIM];
  __shared__ float b3p[A_DIM];
  const int t = threadIdx.x;

  {
    float mean = gsumIn[t] / (float)N_NODES;
    float var = gsqIn[t] / (float)N_NODES - mean * mean;
    float s = gamma[t] * rsqrtf(var + BN_EPS);
    s2s[t] = s; sh2s[t] = beta[t] - mean * s;
  }
  __syncthreads();

  for (int i = t; i < HDIM * A_DIM; i += 128) {
    int k = i >> 5;
    w3p[k][i & 31] = s2s[k] * W3[i];
  }
  {
    int j = t & 31, seg = t >> 5;
    float p = 0.f;
    for (int kk = 0; kk < 32; ++kk) {
      int k = seg * 32 + kk;
      p += sh2s[k] * W3[k * A_DIM + j];
    }
    bred[seg][j] = p;
  }
  const int row0 = blockIdx.x * FC3_TR;
  for (int i = t; i < FC3_TR * (HDIM / 8); i += 128) {
    int r = i & 63, cg = i >> 6;
    int row = row0 + r;
    ushort8v v;
    if (row < N_NODES) v = *(const ushort8v*)(h2 + (size_t)row * HDIM + cg * 8);
    else { for (int jj = 0; jj < 8; ++jj) v[jj] = 0; }
#pragma unroll
    for (int jj = 0; jj < 8; ++jj) hs[cg * 8 + jj][r] = bf2f(v[jj]);
  }
  __syncthreads();
  if (t < 32) b3p[t] = b3[t] + bred[0][t] + bred[1][t] + bred[2][t] + bred[3][t];
  __syncthreads();

  const int r0 = (t >> 3) * 4;
  const int j0 = (t & 7) * 4;
  float4 acc[4];
#pragma unroll
  for (int r = 0; r < 4; ++r) acc[r] = (float4){0.f, 0.f, 0.f, 0.f};

  for (int k = 0; k < HDIM; k += 4) {
    float4 w0 = *(const float4*)&w3p[k + 0][j0];
    float4 w1 = *(const float4*)&w3p[k + 1][j0];
    float4 w2 = *(const float4*)&w3p[k + 2][j0];
    float4 w3v = *(const float4*)&w3p[k + 3][j0];
#pragma unroll
    for (int r = 0; r < 4; ++r) {
      int rr = r0 + r;
      float h0 = hs[k + 0][rr], h1 = hs[k + 1][rr];
      float h2v = hs[k + 2][rr], h3 = hs[k + 3][rr];
      acc[r].x += h0 * w0.x + h1 * w1.x + h2v * w2.x + h3 * w3v.x;
      acc[r].y += h0 * w0.y + h1 * w1.y + h2v * w2.y + h3 * w3v.y;
      acc[r].z += h0 * w0.z + h1 * w1.z + h2v * w2.z + h3 * w3v.z;
      acc[r].w += h0 * w0.w + h1 * w1.w + h2v * w2.w + h3 * w3v.w;
    }
  }

  float4 b4 = *(const float4*)&b3p[j0];
#pragma unroll
  for (int r = 0; r < 4; ++r) {
    float l0 = acc[r].x + b4.x, l1 = acc[r].y + b4.y;
    float l2 = acc[r].z + b4.z, l3 = acc[r].w + b4.w;
    float mx = fmaxf(fmaxf(l0, l1), fmaxf(l2, l3));
#pragma unroll
    for (int o = 1; o <= 4; o <<= 1) mx = fmaxf(mx, __shfl_xor(mx, o, 64));
    float e0 = __expf(l0 - mx), e1 = __expf(l1 - mx);
    float e2 = __expf(l2 - mx), e3 = __expf(l3 - mx);
    float sm = e0 + e1 + e2 + e3;
#pragma unroll
    for (int o = 1; o <= 4; o <<= 1) sm += __shfl_xor(sm, o, 64);
    float inv = 1.0f / sm;
    int row = row0 + r0 + r;
    if (row < N_NODES) {
      float4 o4; o4.x = e0 * inv; o4.y = e1 * inv; o4.z = e2 * inv; o4.w = e3 * inv;
      *(float4*)(out + (size_t)row * A_DIM + j0) = o4;
    }
  }
}

// ---------------------------------------------------------------------------
extern "C" void kernel_launch(void* const* d_in, const int* in_sizes, int n_in,
                              void* d_out, int out_size, void* d_ws, size_t ws_size,
                              hipStream_t stream) {
  const float* x     = (const float*)d_in[0];
  const int*   ei    = (const int*)d_in[1];
  const float* W     = (const float*)d_in[2];
  const float* a_src = (const float*)d_in[3];
  const float* a_dst = (const float*)d_in[4];
  const float* b_gat = (const float*)d_in[5];
  const float* g0    = (const float*)d_in[6];
  const float* beta0 = (const float*)d_in[7];
  const float* W1    = (const float*)d_in[8];
  const float* b1    = (const float*)d_in[9];
  const float* W2    = (const float*)d_in[10];
  const float* b2    = (const float*)d_in[11];
  const float* g2    = (const float*)d_in[12];
  const float* beta2 = (const float*)d_in[13];
  const float* W3    = (const float*)d_in[14];
  const float* b3    = (const float*)d_in[15];
  float* out = (float*)d_out;
  const int* srcI = ei;
  const int* dstI = ei + N_EDGES;

  char* p = (char*)d_ws;
  auto alloc = [&](size_t bytes) -> char* {
    char* q = p; p += (bytes + 255) & ~(size_t)255; return q;
  };
  unsigned short* h   = (unsigned short*)alloc(sizeof(short) * (size_t)N_NODES * HDIM);
  unsigned short* h0  = (unsigned short*)alloc(sizeof(short) * (size_t)N_NODES * HDIM);
  unsigned short* h2  = h;  // h dead after k_agg; reuse for fc12 output
  unsigned short* Wt0 = (unsigned short*)alloc(sizeof(short) * HDIM * D_INPUT);
  unsigned short* Wt1 = (unsigned short*)alloc(sizeof(short) * HDIM * HDIM);
  unsigned short* Wt2 = (unsigned short*)alloc(sizeof(short) * HDIM * HDIM);
  int2*  sedge  = (int2*)alloc(sizeof(int2) * (size_t)N_NODES * CAP);
  int*   bbuf   = (int*)alloc(sizeof(int) * (size_t)NB * BCAP);
  float* esrc   = (float*)alloc(sizeof(float) * N_NODES);
  float* edst   = (float*)alloc(sizeof(float) * N_NODES);
  int*   deg    = (int*)alloc(sizeof(int) * N_NODES);
  int*   gcur   = (int*)alloc(sizeof(int) * NB * GC_STRIDE);
  float* stats  = (float*)alloc(sizeof(float) * 4 * 128);
  float* gsum0 = stats;        float* gsq0  = stats + 128;
  float* gsum2 = stats + 256;  float* gsq2  = stats + 384;

  const int gT = (N_NODES + 63) / 64;          // 782 MFMA tiles
  const int gB = (N_EDGES + EPB - 1) / EPB;    // 196 bin blocks
  const int gP = (HDIM * D_INPUT + 255) / 256; // 128 prep blocks

  k_prep<<<gP, 256, 0, stream>>>(W, W1, W2, Wt0, Wt1, Wt2, gcur, stats);
  k_gemmbin<<<gT + gB, 256, 0, stream>>>(x, Wt0, a_src, a_dst, h, esrc, edst,
                                         srcI, dstI, gcur, bbuf);
  k_sc2<<<NB, 256, 0, stream>>>(gcur, bbuf, esrc, edst, deg, sedge);
  k_agg<<<N_NODES / 4, 256, 0, stream>>>(deg, sedge, h, b_gat, h0);
  k_bnstats<<<(N_NODES + BN_ROWS - 1) / BN_ROWS, 256, 0, stream>>>(h0, gsum0, gsq0);
  k_fc12<<<gT, 256, 0, stream>>>(h0, gsum0, gsq0, g0, beta0, Wt1, b1, Wt2, b2, h2,
                                 gsum2, gsq2);
  k_fc3<<<(N_NODES + FC3_TR - 1) / FC3_TR, 128, 0, stream>>>(
      h2, gsum2, gsq2, g2, beta2, W3, b3, out);
}

// Round 11
// 247.897 us; speedup vs baseline: 1.4500x; 1.0021x over previous
//
#include <hip/hip_runtime.h>
#include <math.h>

#define N_NODES 50000
#define N_EDGES 800000
#define D_INPUT 256
#define HDIM 128
#define A_DIM 32
#define NEG_SLOPE 0.2f
#define BN_EPS 1e-5f
#define CAP 64        // max degree; Poisson(16): P(deg>=64) ~ 1e-21
#define NB 391        // dst bins of 128 nodes (391*128 = 50048)
#define BIN_SHIFT 7
#define BCAP 2432     // per-bin segment cap; lambda=2046, +8.5 sigma
#define GC_STRIDE 16  // pad bin counters to one per 64B line (R5 lesson)
#define EPB 4096      // edges per bin block
#define FC3_TR 64     // rows per k_fc3 block
#define SROW 132      // LDS row stride (shorts) for fc12: 66 dwords -> conflict-free

typedef short short8 __attribute__((ext_vector_type(8)));
typedef unsigned short ushort8v __attribute__((ext_vector_type(8)));
typedef unsigned short ushort4v __attribute__((ext_vector_type(4)));
typedef float float4v __attribute__((ext_vector_type(4)));

__device__ __forceinline__ unsigned short f2bf(float f) {
  unsigned u = __float_as_uint(f);
  u += 0x7FFFu + ((u >> 16) & 1u);
  return (unsigned short)(u >> 16);
}
__device__ __forceinline__ float bf2f(unsigned short b) {
  return __uint_as_float(((unsigned)b) << 16);
}

__device__ __forceinline__ float waveReduceMax(float v) {
#pragma unroll
  for (int o = 32; o >= 1; o >>= 1) v = fmaxf(v, __shfl_xor(v, o, 64));
  return v;
}
__device__ __forceinline__ float waveReduceSum(float v) {
#pragma unroll
  for (int o = 32; o >= 1; o >>= 1) v += __shfl_xor(v, o, 64);
  return v;
}

// ---------------- prep: W->Wt (bf16 [n][k]) + zero gcur/stats ---------------
__global__ __launch_bounds__(256) void k_prep(
    const float* __restrict__ W, const float* __restrict__ W1,
    const float* __restrict__ W2, unsigned short* __restrict__ Wt0,
    unsigned short* __restrict__ Wt1, unsigned short* __restrict__ Wt2,
    int* __restrict__ gcur, float* __restrict__ stats)
{
  int i = blockIdx.x * 256 + threadIdx.x;
  if (i < HDIM * D_INPUT) {                 // Wt0[n][k], 128 x 256
    int n = i >> 8, k = i & 255;
    Wt0[i] = f2bf(W[(size_t)k * HDIM + n]);
  }
  if (i < HDIM * HDIM) {                    // Wt1/Wt2[n][k], 128 x 128
    int n = i >> 7, k = i & 127;
    Wt1[i] = f2bf(W1[(size_t)k * HDIM + n]);
    Wt2[i] = f2bf(W2[(size_t)k * HDIM + n]);
  }
  if (i < NB * GC_STRIDE) gcur[i] = 0;      // replaces hipMemsetAsync
  if (i < 512) stats[i] = 0.f;
}

// ---------------- merged: MFMA gemm blocks + edge-bin blocks ----------------
__global__ __launch_bounds__(256) void k_gemmbin(
    const float* __restrict__ x, const unsigned short* __restrict__ Wt0,
    const float* __restrict__ a_src, const float* __restrict__ a_dst,
    unsigned short* __restrict__ hbf, float* __restrict__ esrc, float* __restrict__ edst,
    const int* __restrict__ srcI, const int* __restrict__ dstI,
    int* __restrict__ gcur, int* __restrict__ bbuf)
{
  const int gT = (N_NODES + 63) / 64;
  __shared__ short As[64][72];
  __shared__ short Bs[128][72];
  __shared__ float esred[64][2], edred[64][2];
  __shared__ int hist[NB];
  __shared__ int base[NB];

  const int t = threadIdx.x;

  if (blockIdx.x >= gT) {
    // ---- bin path ----
    const int e0 = (blockIdx.x - gT) * EPB;
    const int e1 = min(e0 + EPB, N_EDGES);
    for (int i = t; i < NB; i += 256) hist[i] = 0;
    __syncthreads();
    for (int e = e0 + t; e < e1; e += 256)
      atomicAdd(&hist[dstI[e] >> BIN_SHIFT], 1);
    __syncthreads();
    for (int i = t; i < NB; i += 256) {
      base[i] = atomicAdd(&gcur[i * GC_STRIDE], hist[i]);
      hist[i] = 0;
    }
    __syncthreads();
    for (int e = e0 + t; e < e1; e += 256) {
      int d = dstI[e];
      int bin = d >> BIN_SHIFT;
      int r = atomicAdd(&hist[bin], 1) + base[bin];
      if (r < BCAP) bbuf[(size_t)bin * BCAP + r] = srcI[e] | ((d & 127) << 16);
    }
    return;
  }

  // ---- gemm path ----
  const int lane = t & 63;
  const int wv = t >> 6;
  const int rh = wv >> 1;
  const int ch = wv & 1;
  const int quad = (lane >> 4) & 3;
  const int l15 = lane & 15;
  const int row0 = blockIdx.x * 64;

  float4v acc[2][4];
#pragma unroll
  for (int i = 0; i < 2; ++i)
#pragma unroll
    for (int j = 0; j < 4; ++j) acc[i][j] = (float4v){0.f, 0.f, 0.f, 0.f};

  for (int ks = 0; ks < D_INPUT / 64; ++ks) {
    const int kk0 = ks * 64;
#pragma unroll
    for (int it = 0; it < 4; ++it) {
      int idx = it * 256 + t;
      int r = idx >> 4, c4 = idx & 15;
      int rr = row0 + r; if (rr >= N_NODES) rr = N_NODES - 1;
      float4 v = *(const float4*)(x + (size_t)rr * D_INPUT + kk0 + c4 * 4);
      ushort4v b; b.x = f2bf(v.x); b.y = f2bf(v.y); b.z = f2bf(v.z); b.w = f2bf(v.w);
      *(ushort4v*)(&As[r][c4 * 4]) = b;
    }
#pragma unroll
    for (int it = 0; it < 4; ++it) {
      int idx = it * 256 + t;
      int n = idx >> 3, c8 = idx & 7;
      *(ushort8v*)(&Bs[n][c8 * 8]) = *(const ushort8v*)(Wt0 + (size_t)n * D_INPUT + kk0 + c8 * 8);
    }
    __syncthreads();
#pragma unroll
    for (int kc = 0; kc < 2; ++kc) {
      short8 af[2], bfr[4];
#pragma unroll
      for (int rt = 0; rt < 2; ++rt)
        af[rt] = *(const short8*)(&As[rh * 32 + rt * 16 + l15][kc * 32 + quad * 8]);
#pragma unroll
      for (int nt = 0; nt < 4; ++nt)
        bfr[nt] = *(const short8*)(&Bs[ch * 64 + nt * 16 + l15][kc * 32 + quad * 8]);
#pragma unroll
      for (int rt = 0; rt < 2; ++rt)
#pragma unroll
        for (int nt = 0; nt < 4; ++nt)
          acc[rt][nt] = __builtin_amdgcn_mfma_f32_16x16x32_bf16(af[rt], bfr[nt], acc[rt][nt], 0, 0, 0);
    }
    __syncthreads();
  }

  float asv[4], adv[4];
#pragma unroll
  for (int nt = 0; nt < 4; ++nt) {
    int col = ch * 64 + nt * 16 + l15;
    asv[nt] = a_src[col]; adv[nt] = a_dst[col];
  }
#pragma unroll
  for (int rt = 0; rt < 2; ++rt) {
#pragma unroll
    for (int reg = 0; reg < 4; ++reg) {
      int rloc = rh * 32 + rt * 16 + quad * 4 + reg;
      int row = row0 + rloc;
      bool valid = (row < N_NODES);
      float ps = 0.f, pd = 0.f;
#pragma unroll
      for (int nt = 0; nt < 4; ++nt) {
        float v = acc[rt][nt][reg];
        ps += v * asv[nt]; pd += v * adv[nt];
        if (valid) hbf[(size_t)row * HDIM + ch * 64 + nt * 16 + l15] = f2bf(v);
      }
#pragma unroll
      for (int o = 8; o >= 1; o >>= 1) {
        ps += __shfl_xor(ps, o, 64);
        pd += __shfl_xor(pd, o, 64);
      }
      if (l15 == 0) { esred[rloc][ch] = ps; edred[rloc][ch] = pd; }
    }
  }
  __syncthreads();
  if (t < 64) {
    int row = row0 + t;
    if (row < N_NODES) {
      esrc[row] = esred[t][0] + esred[t][1];
      edst[row] = edred[t][0] + edred[t][1];
    }
  }
}

// ---------------- fused: per-bin bucket build + softmax-agg + BN0 stats -----
// one block per bin; buckets live only in LDS; 8 waves x 16 nodes each
__global__ __launch_bounds__(512) void k_scagg(
    const int* __restrict__ gcur, const int* __restrict__ bbuf,
    const float* __restrict__ esrc, const float* __restrict__ edst,
    const unsigned short* __restrict__ hbf, const float* __restrict__ b_gat,
    unsigned short* __restrict__ h0,
    float* __restrict__ gsum, float* __restrict__ gsq)
{
  __shared__ int2 bk[128][CAP];   // 64 KB
  __shared__ int lcur[128];
  __shared__ float ledst[128];
  __shared__ float redS[8][128];
  __shared__ float redQ[8][128];
  const int t = threadIdx.x;
  const int bin = blockIdx.x;
  const int d0 = bin << BIN_SHIFT;

  if (t < 128) {
    lcur[t] = 0;
    int d = d0 + t;
    ledst[t] = (d < N_NODES) ? edst[d] : 0.f;
  }
  __syncthreads();
  // ---- build buckets in LDS ----
  const int cnt = min(gcur[bin * GC_STRIDE], BCAP);
  const int* seg = bbuf + (size_t)bin * BCAP;
  for (int i = t; i < cnt; i += 512) {
    int v = seg[i];
    int s = v & 0xFFFF;
    int dl = (v >> 16) & 127;
    float evv = esrc[s] + ledst[dl];
    evv = (evv > 0.f) ? evv : NEG_SLOPE * evv;
    int r = atomicAdd(&lcur[dl], 1);
    if (r < CAP) {
      int2 e2; e2.x = s; e2.y = __float_as_int(evv);
      bk[dl][r] = e2;
    }
  }
  __syncthreads();

  // ---- per-node softmax + gather-aggregate (wave per node, 16 nodes/wave) --
  const int lane = t & 63;
  const int wv = t >> 6;   // 0..7
  const float bgx = b_gat[lane * 2], bgy = b_gat[lane * 2 + 1];
  float sx = 0.f, sy = 0.f, qx = 0.f, qy = 0.f;

  for (int i = 0; i < 16; ++i) {
    const int dl = wv * 16 + i;
    const int node = d0 + dl;
    const int deg = min(lcur[dl], CAP);

    int2 ev; ev.x = 0; ev.y = 0;
    float val = -INFINITY;
    if (lane < deg) {
      ev = bk[dl][lane];
      val = __int_as_float(ev.y);
    }
    const float m = waveReduceMax(val);
    const float ex = (lane < deg) ? __expf(val - m) : 0.f;
    const float s = waveReduceSum(ex);
    const float al = ex * (1.0f / fmaxf(s, 1e-16f));
    const int sr = ev.x;

    float ax = 0.f, ay = 0.f;
    int j = 0;
    for (; j + 4 <= deg; j += 4) {
      float a0 = __shfl(al, j, 64),   a1 = __shfl(al, j+1, 64);
      float a2 = __shfl(al, j+2, 64), a3 = __shfl(al, j+3, 64);
      int s0 = __shfl(sr, j, 64),   s1 = __shfl(sr, j+1, 64);
      int s2 = __shfl(sr, j+2, 64), s3 = __shfl(sr, j+3, 64);
      unsigned v0 = *(const unsigned*)(hbf + (size_t)s0 * HDIM + lane * 2);
      unsigned v1 = *(const unsigned*)(hbf + (size_t)s1 * HDIM + lane * 2);
      unsigned v2 = *(const unsigned*)(hbf + (size_t)s2 * HDIM + lane * 2);
      unsigned v3 = *(const unsigned*)(hbf + (size_t)s3 * HDIM + lane * 2);
      ax += a0 * bf2f((unsigned short)(v0 & 0xFFFFu))
          + a1 * bf2f((unsigned short)(v1 & 0xFFFFu))
          + a2 * bf2f((unsigned short)(v2 & 0xFFFFu))
          + a3 * bf2f((unsigned short)(v3 & 0xFFFFu));
      ay += a0 * bf2f((unsigned short)(v0 >> 16))
          + a1 * bf2f((unsigned short)(v1 >> 16))
          + a2 * bf2f((unsigned short)(v2 >> 16))
          + a3 * bf2f((unsigned short)(v3 >> 16));
    }
    for (; j < deg; ++j) {
      float a = __shfl(al, j, 64);
      int sj = __shfl(sr, j, 64);
      unsigned v = *(const unsigned*)(hbf + (size_t)sj * HDIM + lane * 2);
      ax += a * bf2f((unsigned short)(v & 0xFFFFu));
      ay += a * bf2f((unsigned short)(v >> 16));
    }
    float vx = fmaxf(ax + bgx, 0.f);
    float vy = fmaxf(ay + bgy, 0.f);
    if (node < N_NODES) {
      *(unsigned*)(h0 + (size_t)node * HDIM + lane * 2) =
          (unsigned)f2bf(vx) | ((unsigned)f2bf(vy) << 16);
      sx += vx; qx += vx * vx;
      sy += vy; qy += vy * vy;
    }
  }

  // ---- BN0 stats: block reduce + 1 atomic per column ----
  redS[wv][lane * 2] = sx; redS[wv][lane * 2 + 1] = sy;
  redQ[wv][lane * 2] = qx; redQ[wv][lane * 2 + 1] = qy;
  __syncthreads();
  if (t < 128) {
    float S = 0.f, Q = 0.f;
#pragma unroll
    for (int w = 0; w < 8; ++w) { S += redS[w][t]; Q += redQ[w][t]; }
    atomicAdd(&gsum[t], S);
    atomicAdd(&gsq[t], Q);
  }
}

// ---------------- fused FC1+FC2, full-K staging, 5 barriers -----------------
__global__ __launch_bounds__(256) void k_fc12(
    const unsigned short* __restrict__ in,
    const float* __restrict__ gsumIn, const float* __restrict__ gsqIn,
    const float* __restrict__ gamma, const float* __restrict__ beta,
    const unsigned short* __restrict__ Wt1, const float* __restrict__ b1,
    const unsigned short* __restrict__ Wt2, const float* __restrict__ b2,
    unsigned short* __restrict__ outp,
    float* __restrict__ gsum, float* __restrict__ gsq)
{
  __shared__ short As[64 * SROW];    // input tile, then H1 tile (K=128)
  __shared__ short Bsh[128 * SROW];  // W1, then W2 (full K)
  __shared__ float statS[128][2], statQ[128][2];
  __shared__ float sc[HDIM], shf[HDIM];

  const int t = threadIdx.x;
  const int lane = t & 63;
  const int wv = t >> 6;
  const int rh = wv >> 1;
  const int ch = wv & 1;
  const int quad = (lane >> 4) & 3;
  const int l15 = lane & 15;
  const int row0 = blockIdx.x * 64;

  if (t < HDIM) {
    float mean = gsumIn[t] / (float)N_NODES;
    float var = gsqIn[t] / (float)N_NODES - mean * mean;
    float s = gamma[t] * rsqrtf(var + BN_EPS);
    sc[t] = s; shf[t] = beta[t] - mean * s;
  }
  __syncthreads();                                   // B1

#pragma unroll
  for (int it = 0; it < 4; ++it) {
    int idx = it * 256 + t;
    int r = idx >> 4, c8 = idx & 15;
    int rr = row0 + r; if (rr >= N_NODES) rr = N_NODES - 1;
    ushort8v v = *(const ushort8v*)(in + (size_t)rr * HDIM + c8 * 8);
#pragma unroll
    for (int j = 0; j < 8; ++j) {
      int k = c8 * 8 + j;
      v[j] = f2bf(bf2f(v[j]) * sc[k] + shf[k]);
    }
    *(ushort8v*)(&As[r * SROW + c8 * 8]) = v;
  }
#pragma unroll
  for (int it = 0; it < 8; ++it) {
    int idx = it * 256 + t;
    int n = idx >> 4, c8 = idx & 15;
    *(ushort8v*)(&Bsh[n * SROW + c8 * 8]) = *(const ushort8v*)(Wt1 + (size_t)n * HDIM + c8 * 8);
  }
  __syncthreads();                                   // B2

  float4v acc[2][4];
#pragma unroll
  for (int i = 0; i < 2; ++i)
#pragma unroll
    for (int j = 0; j < 4; ++j) acc[i][j] = (float4v){0.f, 0.f, 0.f, 0.f};

#pragma unroll
  for (int kc = 0; kc < 4; ++kc) {
    short8 af[2], bfr[4];
#pragma unroll
    for (int rt = 0; rt < 2; ++rt)
      af[rt] = *(const short8*)(&As[(rh * 32 + rt * 16 + l15) * SROW + kc * 32 + quad * 8]);
#pragma unroll
    for (int nt = 0; nt < 4; ++nt)
      bfr[nt] = *(const short8*)(&Bsh[(ch * 64 + nt * 16 + l15) * SROW + kc * 32 + quad * 8]);
#pragma unroll
    for (int rt = 0; rt < 2; ++rt)
#pragma unroll
      for (int nt = 0; nt < 4; ++nt)
        acc[rt][nt] = __builtin_amdgcn_mfma_f32_16x16x32_bf16(af[rt], bfr[nt], acc[rt][nt], 0, 0, 0);
  }
  __syncthreads();                                   // B3

  {
    float bv[4];
#pragma unroll
    for (int nt = 0; nt < 4; ++nt) bv[nt] = b1[ch * 64 + nt * 16 + l15];
#pragma unroll
    for (int rt = 0; rt < 2; ++rt) {
#pragma unroll
      for (int reg = 0; reg < 4; ++reg) {
        int rloc = rh * 32 + rt * 16 + quad * 4 + reg;
#pragma unroll
        for (int nt = 0; nt < 4; ++nt) {
          float o = fmaxf(acc[rt][nt][reg] + bv[nt], 0.f);
          As[rloc * SROW + ch * 64 + nt * 16 + l15] = f2bf(o);
        }
      }
    }
  }
#pragma unroll
  for (int it = 0; it < 8; ++it) {
    int idx = it * 256 + t;
    int n = idx >> 4, c8 = idx & 15;
    *(ushort8v*)(&Bsh[n * SROW + c8 * 8]) = *(const ushort8v*)(Wt2 + (size_t)n * HDIM + c8 * 8);
  }
  __syncthreads();                                   // B4

#pragma unroll
  for (int i = 0; i < 2; ++i)
#pragma unroll
    for (int j = 0; j < 4; ++j) acc[i][j] = (float4v){0.f, 0.f, 0.f, 0.f};

#pragma unroll
  for (int kc = 0; kc < 4; ++kc) {
    short8 af[2], bfr[4];
#pragma unroll
    for (int rt = 0; rt < 2; ++rt)
      af[rt] = *(const short8*)(&As[(rh * 32 + rt * 16 + l15) * SROW + kc * 32 + quad * 8]);
#pragma unroll
    for (int nt = 0; nt < 4; ++nt)
      bfr[nt] = *(const short8*)(&Bsh[(ch * 64 + nt * 16 + l15) * SROW + kc * 32 + quad * 8]);
#pragma unroll
    for (int rt = 0; rt < 2; ++rt)
#pragma unroll
      for (int nt = 0; nt < 4; ++nt)
        acc[rt][nt] = __builtin_amdgcn_mfma_f32_16x16x32_bf16(af[rt], bfr[nt], acc[rt][nt], 0, 0, 0);
  }

  float bv[4];
#pragma unroll
  for (int nt = 0; nt < 4; ++nt) bv[nt] = b2[ch * 64 + nt * 16 + l15];

  float pS[4] = {0.f, 0.f, 0.f, 0.f}, pQ[4] = {0.f, 0.f, 0.f, 0.f};
#pragma unroll
  for (int rt = 0; rt < 2; ++rt) {
#pragma unroll
    for (int reg = 0; reg < 4; ++reg) {
      int row = row0 + rh * 32 + rt * 16 + quad * 4 + reg;
      bool valid = (row < N_NODES);
#pragma unroll
      for (int nt = 0; nt < 4; ++nt) {
        float o = fmaxf(acc[rt][nt][reg] + bv[nt], 0.f);
        if (valid) {
          outp[(size_t)row * HDIM + ch * 64 + nt * 16 + l15] = f2bf(o);
          pS[nt] += o; pQ[nt] += o * o;
        }
      }
    }
  }
#pragma unroll
  for (int nt = 0; nt < 4; ++nt) {
    float s = pS[nt], q = pQ[nt];
    s += __shfl_xor(s, 16, 64); s += __shfl_xor(s, 32, 64);
    q += __shfl_xor(q, 16, 64); q += __shfl_xor(q, 32, 64);
    if (lane < 16) {
      statS[ch * 64 + nt * 16 + lane][rh] = s;
      statQ[ch * 64 + nt * 16 + lane][rh] = q;
    }
  }
  __syncthreads();                                   // B5
  if (t < 128) {
    atomicAdd(&gsum[t], statS[t][0] + statS[t][1]);
    atomicAdd(&gsq[t],  statQ[t][0] + statQ[t][1]);
  }
}

// ---------------- fc3 + softmax: BN-folded W3', register-blocked fp32 -------
__global__ __launch_bounds__(128) void k_fc3(
    const unsigned short* __restrict__ h2,
    const float* __restrict__ gsumIn, const float* __restrict__ gsqIn,
    const float* __restrict__ gamma, const float* __restrict__ beta,
    const float* __restrict__ W3, const float* __restrict__ b3,
    float* __restrict__ out)
{
  __shared__ float w3p[HDIM][A_DIM];      // s2-folded W3
  __shared__ float hs[HDIM][FC3_TR + 2];  // fp32 h tile, transposed [k][r]
  __shared__ float s2s[HDIM], sh2s[HDIM];
  __shared__ float bred[4][A_DIM];
  __shared__ float b3p[A_DIM];
  const int t = threadIdx.x;

  {
    float mean = gsumIn[t] / (float)N_NODES;
    float var = gsqIn[t] / (float)N_NODES - mean * mean;
    float s = gamma[t] * rsqrtf(var + BN_EPS);
    s2s[t] = s; sh2s[t] = beta[t] - mean * s;
  }
  __syncthreads();

  for (int i = t; i < HDIM * A_DIM; i += 128) {
    int k = i >> 5;
    w3p[k][i & 31] = s2s[k] * W3[i];
  }
  {
    int j = t & 31, seg = t >> 5;
    float p = 0.f;
    for (int kk = 0; kk < 32; ++kk) {
      int k = seg * 32 + kk;
      p += sh2s[k] * W3[k * A_DIM + j];
    }
    bred[seg][j] = p;
  }
  const int row0 = blockIdx.x * FC3_TR;
  for (int i = t; i < FC3_TR * (HDIM / 8); i += 128) {
    int r = i & 63, cg = i >> 6;
    int row = row0 + r;
    ushort8v v;
    if (row < N_NODES) v = *(const ushort8v*)(h2 + (size_t)row * HDIM + cg * 8);
    else { for (int jj = 0; jj < 8; ++jj) v[jj] = 0; }
#pragma unroll
    for (int jj = 0; jj < 8; ++jj) hs[cg * 8 + jj][r] = bf2f(v[jj]);
  }
  __syncthreads();
  if (t < 32) b3p[t] = b3[t] + bred[0][t] + bred[1][t] + bred[2][t] + bred[3][t];
  __syncthreads();

  const int r0 = (t >> 3) * 4;
  const int j0 = (t & 7) * 4;
  float4 acc[4];
#pragma unroll
  for (int r = 0; r < 4; ++r) acc[r] = (float4){0.f, 0.f, 0.f, 0.f};

  for (int k = 0; k < HDIM; k += 4) {
    float4 w0 = *(const float4*)&w3p[k + 0][j0];
    float4 w1 = *(const float4*)&w3p[k + 1][j0];
    float4 w2 = *(const float4*)&w3p[k + 2][j0];
    float4 w3v = *(const float4*)&w3p[k + 3][j0];
#pragma unroll
    for (int r = 0; r < 4; ++r) {
      int rr = r0 + r;
      float h0 = hs[k + 0][rr], h1 = hs[k + 1][rr];
      float h2v = hs[k + 2][rr], h3 = hs[k + 3][rr];
      acc[r].x += h0 * w0.x + h1 * w1.x + h2v * w2.x + h3 * w3v.x;
      acc[r].y += h0 * w0.y + h1 * w1.y + h2v * w2.y + h3 * w3v.y;
      acc[r].z += h0 * w0.z + h1 * w1.z + h2v * w2.z + h3 * w3v.z;
      acc[r].w += h0 * w0.w + h1 * w1.w + h2v * w2.w + h3 * w3v.w;
    }
  }

  float4 b4 = *(const float4*)&b3p[j0];
#pragma unroll
  for (int r = 0; r < 4; ++r) {
    float l0 = acc[r].x + b4.x, l1 = acc[r].y + b4.y;
    float l2 = acc[r].z + b4.z, l3 = acc[r].w + b4.w;
    float mx = fmaxf(fmaxf(l0, l1), fmaxf(l2, l3));
#pragma unroll
    for (int o = 1; o <= 4; o <<= 1) mx = fmaxf(mx, __shfl_xor(mx, o, 64));
    float e0 = __expf(l0 - mx), e1 = __expf(l1 - mx);
    float e2 = __expf(l2 - mx), e3 = __expf(l3 - mx);
    float sm = e0 + e1 + e2 + e3;
#pragma unroll
    for (int o = 1; o <= 4; o <<= 1) sm += __shfl_xor(sm, o, 64);
    float inv = 1.0f / sm;
    int row = row0 + r0 + r;
    if (row < N_NODES) {
      float4 o4; o4.x = e0 * inv; o4.y = e1 * inv; o4.z = e2 * inv; o4.w = e3 * inv;
      *(float4*)(out + (size_t)row * A_DIM + j0) = o4;
    }
  }
}

// ---------------------------------------------------------------------------
extern "C" void kernel_launch(void* const* d_in, const int* in_sizes, int n_in,
                              void* d_out, int out_size, void* d_ws, size_t ws_size,
                              hipStream_t stream) {
  const float* x     = (const float*)d_in[0];
  const int*   ei    = (const int*)d_in[1];
  const float* W     = (const float*)d_in[2];
  const float* a_src = (const float*)d_in[3];
  const float* a_dst = (const float*)d_in[4];
  const float* b_gat = (const float*)d_in[5];
  const float* g0    = (const float*)d_in[6];
  const float* beta0 = (const float*)d_in[7];
  const float* W1    = (const float*)d_in[8];
  const float* b1    = (const float*)d_in[9];
  const float* W2    = (const float*)d_in[10];
  const float* b2    = (const float*)d_in[11];
  const float* g2    = (const float*)d_in[12];
  const float* beta2 = (const float*)d_in[13];
  const float* W3    = (const float*)d_in[14];
  const float* b3    = (const float*)d_in[15];
  float* out = (float*)d_out;
  const int* srcI = ei;
  const int* dstI = ei + N_EDGES;

  char* p = (char*)d_ws;
  auto alloc = [&](size_t bytes) -> char* {
    char* q = p; p += (bytes + 255) & ~(size_t)255; return q;
  };
  unsigned short* h   = (unsigned short*)alloc(sizeof(short) * (size_t)N_NODES * HDIM);
  unsigned short* h0  = (unsigned short*)alloc(sizeof(short) * (size_t)N_NODES * HDIM);
  unsigned short* h2  = h;  // h dead after k_scagg; reuse for fc12 output
  unsigned short* Wt0 = (unsigned short*)alloc(sizeof(short) * HDIM * D_INPUT);
  unsigned short* Wt1 = (unsigned short*)alloc(sizeof(short) * HDIM * HDIM);
  unsigned short* Wt2 = (unsigned short*)alloc(sizeof(short) * HDIM * HDIM);
  int*   bbuf   = (int*)alloc(sizeof(int) * (size_t)NB * BCAP);
  float* esrc   = (float*)alloc(sizeof(float) * N_NODES);
  float* edst   = (float*)alloc(sizeof(float) * N_NODES);
  int*   gcur   = (int*)alloc(sizeof(int) * NB * GC_STRIDE);
  float* stats  = (float*)alloc(sizeof(float) * 4 * 128);
  float* gsum0 = stats;        float* gsq0  = stats + 128;
  float* gsum2 = stats + 256;  float* gsq2  = stats + 384;

  const int gT = (N_NODES + 63) / 64;          // 782 MFMA tiles
  const int gB = (N_EDGES + EPB - 1) / EPB;    // 196 bin blocks
  const int gP = (HDIM * D_INPUT + 255) / 256; // 128 prep blocks

  k_prep<<<gP, 256, 0, stream>>>(W, W1, W2, Wt0, Wt1, Wt2, gcur, stats);
  k_gemmbin<<<gT + gB, 256, 0, stream>>>(x, Wt0, a_src, a_dst, h, esrc, edst,
                                         srcI, dstI, gcur, bbuf);
  k_scagg<<<NB, 512, 0, stream>>>(gcur, bbuf, esrc, edst, h, b_gat, h0,
                                  gsum0, gsq0);
  k_fc12<<<gT, 256, 0, stream>>>(h0, gsum0, gsq0, g0, beta0, Wt1, b1, Wt2, b2, h2,
                                 gsum2, gsq2);
  k_fc3<<<(N_NODES + FC3_TR - 1) / FC3_TR, 128, 0, stream>>>(
      h2, gsum2, gsq2, g2, beta2, W3, b3, out);
}